// Round 5
// baseline (1348.852 us; speedup 1.0000x reference)
//
#include <hip/hip_runtime.h>
#include <cstdint>

typedef unsigned short ushort_t;
typedef short bf16x8 __attribute__((ext_vector_type(8)));
typedef unsigned short u16x8 __attribute__((ext_vector_type(8)));
typedef float f32x4 __attribute__((ext_vector_type(4)));

#define NPTS 65536
#define WS_NEED 65536   // expmap bytes

__device__ __forceinline__ float bf2f(ushort_t u) {
  union { unsigned u; float f; } c; c.u = ((unsigned)u) << 16; return c.f;
}
__device__ __forceinline__ ushort_t f2bf(float f) {
  union { float f; unsigned u; } c; c.f = f;
  unsigned u = c.u + 0x7fffu + ((c.u >> 16) & 1u);
  return (ushort_t)(u >> 16);
}
__device__ __forceinline__ float rbf(float v) { return bf2f(f2bf(v)); }  // round f32 -> bf16 value
__device__ __forceinline__ bool nan_bits(float v) {
  union { float f; unsigned u; } c; c.f = v;
  return ((c.u >> 23) & 0xFFu) == 0xFFu && (c.u & 0x7FFFFFu) != 0u;
}

__global__ void k_prep(float* out) {
  if (threadIdx.x == 0) out[NPTS * 3] = 18.125f;  // KL(uniform||one-hot), bf16-rounded: data-independent
}

__global__ void k_sentinel(float* out) {
  if (threadIdx.x == 0) out[0] = 1.0e30f;  // ws_size-too-small marker
}

// ---------------- gate: L1 + L2 (bf16 MFMA, K=448) + L3 + argmax -> expmap byte ----------------
// Emulates the np bf16 pipeline: every op result rounded to bf16 (RNE), fp32 accumulation.
__global__ __launch_bounds__(256) void k_gate(
    const float* __restrict__ x,
    const float* __restrict__ mW1, const float* __restrict__ mb1,
    const float* __restrict__ mW2, const float* __restrict__ mb2,
    const float* __restrict__ mW3, const float* __restrict__ mb3,
    unsigned char* __restrict__ expmap)
{
  extern __shared__ char smem[];
  ushort_t* At  = (ushort_t*)smem;             // [64][40] bf16 A-tile (g1 slice)
  ushort_t* Bt  = (ushort_t*)(smem + 5120);    // [448][40] bf16 B-tile (transposed W2)
  float*    W1c = (float*)(smem + 40960);      // [4][448]: W1 rows 0..2 + b1 (bf16-rounded)
  ushort_t* g2  = (ushort_t*)smem;             // [64][456] bf16 (post-loop union over At/Bt/W1c)
  float*    b2c = (float*)(smem + 58368);      // [448]
  float*    xl  = (float*)(smem + 60160);      // [64*3]
  float*    lg  = (float*)(smem + 60928);      // [64][8]

  int tid = threadIdx.x;
  int blk = blockIdx.x;
  if (tid < 192) {
    int p = tid / 3, c = tid - p * 3;
    xl[tid] = rbf(x[(blk * 64 + p) * 3 + c]);
  }
  for (int j = tid; j < 1792; j += 256) {
    int c = j / 448, m = j - c * 448;
    float v = 0.f;
    if (m < 441) v = (c < 3) ? rbf(mW1[c * 441 + m]) : rbf(mb1[m]);
    W1c[j] = v;
  }
  for (int j = tid; j < 448; j += 256) b2c[j] = (j < 441) ? rbf(mb2[j]) : 0.f;

  int w = tid >> 6;
  int lane = tid & 63;
  int l15 = lane & 15, quad = lane >> 4;

  f32x4 acc[4][7];
  #pragma unroll
  for (int a = 0; a < 4; ++a)
    #pragma unroll
    for (int b = 0; b < 7; ++b)
      acc[a][b] = (f32x4){0.f, 0.f, 0.f, 0.f};

  int am = tid >> 2, ak = (tid & 3) * 8;

  for (int kt = 0; kt < 14; ++kt) {
    int kk0 = kt * 32;
    __syncthreads();  // prior MFMA reads of At/Bt done (and initial LDS fills on kt==0)
    // stage A: g1 = relu(bf16(bf16(x@W1) + b1)) for this k-slice (3 FMAs/elem)
    {
      float x0 = xl[am * 3], x1 = xl[am * 3 + 1], x2 = xl[am * 3 + 2];
      u16x8 tmp;
      #pragma unroll
      for (int u = 0; u < 8; ++u) {
        int j = kk0 + ak + u;
        ushort_t h = 0;
        if (j < 441) {
          float t = x0 * W1c[j];
          t = fmaf(x1, W1c[448 + j], t);
          t = fmaf(x2, W1c[896 + j], t);
          t = rbf(t);                    // matmul op -> bf16
          t = rbf(t + W1c[1344 + j]);    // +b1 -> bf16
          t = fmaxf(t, 0.f);             // relu (exact)
          h = f2bf(t);
        }
        tmp[u] = h;
      }
      *(u16x8*)(At + am * 40 + ak) = tmp;
    }
    // stage B: transpose W2[kk0:kk0+32][0:441] -> Bt[n][kr], f32 -> bf16 (exact op in ref)
    {
      int kr = tid >> 3, nc = tid & 7;
      int kk = kk0 + kr;
      int n0 = nc * 56;
      if (kk < 441) {
        const float* src = mW2 + kk * 441;
        #pragma unroll 8
        for (int i = 0; i < 56; ++i) {
          int n = n0 + i;
          Bt[n * 40 + kr] = (n < 441) ? f2bf(src[n]) : (ushort_t)0;
        }
      } else {
        #pragma unroll 8
        for (int i = 0; i < 56; ++i) Bt[(n0 + i) * 40 + kr] = 0;
      }
    }
    __syncthreads();
    bf16x8 bfr[7];
    #pragma unroll
    for (int j = 0; j < 7; ++j) {
      int nt = w + 4 * j;
      bfr[j] = *(const bf16x8*)(Bt + (nt * 16 + l15) * 40 + quad * 8);
    }
    #pragma unroll
    for (int mt = 0; mt < 4; ++mt) {
      bf16x8 a = *(const bf16x8*)(At + (mt * 16 + l15) * 40 + quad * 8);
      #pragma unroll
      for (int j = 0; j < 7; ++j)
        acc[mt][j] = __builtin_amdgcn_mfma_f32_16x16x32_bf16(a, bfr[j], acc[mt][j], 0, 0, 0);
    }
  }
  __syncthreads();
  // g2 = relu(bf16(bf16(acc) + b2)) -> bf16 LDS (C/D layout: col=lane&15, row=quad*4+r)
  #pragma unroll
  for (int mt = 0; mt < 4; ++mt) {
    #pragma unroll
    for (int j = 0; j < 7; ++j) {
      int c = (w + 4 * j) * 16 + l15;
      float bv = b2c[c];
      #pragma unroll
      for (int r = 0; r < 4; ++r) {
        int m = mt * 16 + quad * 4 + r;
        float v = rbf(acc[mt][j][r]);
        v = rbf(v + bv);
        v = fmaxf(v, 0.f);
        g2[m * 456 + c] = f2bf(v);
      }
    }
  }
  __syncthreads();
  // L3 logits: bf16(bf16(g2@W3) + b3), fp32 sequential accumulation
  {
    int m3 = tid >> 2, eg = tid & 3;
    float s0 = 0.f, s1 = 0.f;
    const ushort_t* row = g2 + m3 * 456;
    for (int j = 0; j < 441; ++j) {
      float gv = bf2f(row[j]);
      s0 = fmaf(gv, rbf(mW3[j * 8 + 2 * eg]), s0);
      s1 = fmaf(gv, rbf(mW3[j * 8 + 2 * eg + 1]), s1);
    }
    s0 = rbf(rbf(s0) + rbf(mb3[2 * eg]));
    s1 = rbf(rbf(s1) + rbf(mb3[2 * eg + 1]));
    lg[m3 * 8 + 2 * eg] = s0;
    lg[m3 * 8 + 2 * eg + 1] = s1;
  }
  __syncthreads();
  if (tid < 64) {
    float best = lg[tid * 8];
    int bi = 0;
    #pragma unroll
    for (int e = 1; e < 8; ++e) {
      float v = lg[tid * 8 + e];
      if (v > best) { best = v; bi = e; }   // strict > : first-index tie-break = np.argmax
    }
    expmap[blk * 64 + tid] = (unsigned char)bi;
  }
}

// ---------------- SIREN expert + decoder: bf16 MFMA, per-op bf16 rounding ----------------
__global__ __launch_bounds__(256) void k_sdec(
    const float* __restrict__ x,
    const float* __restrict__ sW1, const float* __restrict__ sb1,
    const float* __restrict__ sWh, const float* __restrict__ sbh,
    const float* __restrict__ sWo, const float* __restrict__ sbo,
    const float* __restrict__ dW1, const float* __restrict__ db1,
    const float* __restrict__ dW2, const float* __restrict__ db2,
    const unsigned char* __restrict__ expmap,
    float* __restrict__ out)
{
  __shared__ ushort_t bufA[32][264];
  __shared__ ushort_t bufB[32][264];
  __shared__ ushort_t wb[16][264];
  __shared__ int idxl[32];
  __shared__ float xl[32][3];
  __shared__ float wc[944];
  __shared__ int npS;

  int e = blockIdx.y;
  int base = blockIdx.x * 32;
  int tid = threadIdx.x;

  if (tid == 0) {   // serial compaction
    int np_ = 0;
    for (int i = 0; i < 32; ++i) {
      int pt = base + i;
      if ((int)expmap[pt] == e) { idxl[np_] = pt; np_++; }
    }
    int first = (np_ > 0) ? idxl[0] : 0;
    for (int i = np_; i < 32; ++i) idxl[i] = first;  // padding rows duplicate a real point
    npS = np_;
  }
  __syncthreads();
  int np = npS;
  if (np == 0) return;

  if (tid < 96) {
    int p = tid / 3, c = tid - p * 3;
    xl[p][c] = rbf(x[idxl[p] * 3 + c]);
  }
  for (int j = tid; j < 944; j += 256)
    wc[j] = (j < 708) ? rbf(sW1[e * 708 + j]) : rbf(sb1[e * 236 + (j - 708)]);
  // zero K-pad cols [236,264) of both buffers once; layers only write cols<236
  for (int t = tid; t < 32 * 28 * 2; t += 256) {
    int b = t / 896, r = t - b * 896;
    int p = r / 28, cc = 236 + (r - p * 28);
    if (b) bufB[p][cc] = 0; else bufA[p][cc] = 0;
  }
  __syncthreads();
  // L1: h = bf16(sin(bf16(30*bf16(bf16(x@W1)+b1))))
  for (int t = tid; t < 32 * 236; t += 256) {
    int p = t / 236, f = t - p * 236;
    float v = xl[p][0] * wc[f];
    v = fmaf(xl[p][1], wc[236 + f], v);
    v = fmaf(xl[p][2], wc[472 + f], v);
    v = rbf(v);                 // einsum -> bf16
    v = rbf(v + wc[708 + f]);   // +b1 -> bf16
    v = rbf(30.f * v);          // *w0 -> bf16
    bufA[p][f] = f2bf(sinf(v)); // sin -> bf16
  }

  int w = tid >> 6, lane = tid & 63;
  int l15 = lane & 15, quad = lane >> 4;
  ushort_t (*src)[264] = bufA;
  ushort_t (*dst)[264] = bufB;

  for (int l = 0; l < 5; ++l) {
    const float* W; const float* bias; int act;
    if (l < 3)       { W = sWh + (l * 8 + e) * 55696; bias = sbh + (l * 8 + e) * 236; act = 0; }
    else if (l == 3) { W = sWo + e * 55696;           bias = sbo + e * 236;           act = 1; }
    else             { W = dW1 + e * 55696;           bias = db1;                     act = 2; }
    __syncthreads();  // src fully written

    for (int t = 0; t < 15; ++t) {
      // stage wb[j][k] = bf16(W[k][t*16+j]); zero j beyond 236 and K-pad rows [236,256)
      {
        int k = tid;
        if (k < 236) {
          const float* srcW = W + k * 236 + t * 16;
          int jmax = 236 - t * 16; if (jmax > 16) jmax = 16;
          #pragma unroll
          for (int j = 0; j < 16; ++j)
            wb[j][k] = (j < jmax) ? f2bf(srcW[j]) : (ushort_t)0;
        } else if (k < 256) {
          #pragma unroll
          for (int j = 0; j < 16; ++j) wb[j][k] = 0;
        }
      }
      __syncthreads();  // wb staged
      if (w < 2) {      // waves 0,1 compute the two 16-row blocks
        f32x4 acc = (f32x4){0.f, 0.f, 0.f, 0.f};
        #pragma unroll
        for (int kt = 0; kt < 8; ++kt) {
          bf16x8 a = *(const bf16x8*)(&src[w * 16 + l15][kt * 32 + quad * 8]);
          bf16x8 b = *(const bf16x8*)(&wb[l15][kt * 32 + quad * 8]);
          acc = __builtin_amdgcn_mfma_f32_16x16x32_bf16(a, b, acc, 0, 0, 0);
        }
        int n = t * 16 + l15;
        if (n < 236) {
          float bv = rbf(bias[n]);
          #pragma unroll
          for (int r = 0; r < 4; ++r) {
            int m = w * 16 + quad * 4 + r;
            float v = rbf(acc[r]);        // einsum -> bf16
            v = rbf(v + bv);              // +bias -> bf16
            if (act == 0) { v = rbf(30.f * v); v = sinf(v); }
            else if (act == 2) v = fmaxf(v, 0.f);
            dst[m][n] = f2bf(v);
          }
        }
      }
      __syncthreads();
    }
    ushort_t (*tp)[264] = src; src = dst; dst = tp;
  }

  // dec2: out = bf16(bf16(h@dW2) + db2), float32 store
  for (int j = tid; j < 711; j += 256)
    wc[j] = (j < 708) ? rbf(dW2[j]) : rbf(db2[j - 708]);
  __syncthreads();
  if (tid < 96) {
    int p = tid / 3, o = tid - p * 3;
    if (p < np) {
      float s = 0.f;
      for (int k = 0; k < 236; ++k)
        s = fmaf(bf2f(src[p][k]), wc[k * 3 + o], s);
      s = rbf(s);
      s = rbf(s + wc[708 + o]);
      float val;
      if (nan_bits(s)) val = 16.0f;                       // NaN tripwire (fast-math-proof)
      else             val = fminf(fmaxf(s, -4.f), 4.f);  // overflow tripwire (legit |s| <= ~0.6)
      out[idxl[p] * 3 + o] = val;
    }
  }
}

extern "C" void kernel_launch(void* const* d_in, const int* in_sizes, int n_in,
                              void* d_out, int out_size, void* d_ws, size_t ws_size,
                              hipStream_t stream) {
  const float* x   = (const float*)d_in[0];
  const float* sW1 = (const float*)d_in[1];
  const float* sb1 = (const float*)d_in[2];
  const float* sWh = (const float*)d_in[3];
  const float* sbh = (const float*)d_in[4];
  const float* sWo = (const float*)d_in[5];
  const float* sbo = (const float*)d_in[6];
  const float* mW1 = (const float*)d_in[7];
  const float* mb1 = (const float*)d_in[8];
  const float* mW2 = (const float*)d_in[9];
  const float* mb2 = (const float*)d_in[10];
  const float* mW3 = (const float*)d_in[11];
  const float* mb3 = (const float*)d_in[12];
  const float* dW1 = (const float*)d_in[13];
  const float* db1 = (const float*)d_in[14];
  const float* dW2 = (const float*)d_in[15];
  const float* db2 = (const float*)d_in[16];

  float* outp = (float*)d_out;
  if (ws_size < (size_t)WS_NEED) {
    k_sentinel<<<dim3(1), dim3(64), 0, stream>>>(outp);
    return;
  }
  unsigned char* expmap = (unsigned char*)d_ws;

  k_prep<<<dim3(1), dim3(64), 0, stream>>>(outp);
  k_gate<<<dim3(1024), dim3(256), 62976, stream>>>(x, mW1, mb1, mW2, mb2, mW3, mb3, expmap);
  k_sdec<<<dim3(2048, 8), dim3(256), 0, stream>>>(x, sW1, sb1, sWh, sbh, sWo, sbo,
                                                  dW1, db1, dW2, db2, expmap, outp);
}

// Round 6
// 950.094 us; speedup vs baseline: 1.4197x; 1.4197x over previous
//
#include <hip/hip_runtime.h>
#include <cstdint>

typedef unsigned short ushort_t;
typedef short bf16x8 __attribute__((ext_vector_type(8)));
typedef unsigned short u16x8 __attribute__((ext_vector_type(8)));
typedef float f32x4 __attribute__((ext_vector_type(4)));

#define NPTS 65536
// ws layout: counts @0 (8 int), bucket @64 (8 x 65536 ushort) = 1,048,640 B (proven <= ws_size)
#define WS_CNT 0
#define WS_BKT 64
#define WS_NEED (64 + 8 * NPTS * 2)

__device__ __forceinline__ float bf2f(ushort_t u) {
  union { unsigned u; float f; } c; c.u = ((unsigned)u) << 16; return c.f;
}
__device__ __forceinline__ ushort_t f2bf(float f) {
  union { float f; unsigned u; } c; c.f = f;
  unsigned u = c.u + 0x7fffu + ((c.u >> 16) & 1u);
  return (ushort_t)(u >> 16);
}
__device__ __forceinline__ float rbf(float v) { return bf2f(f2bf(v)); }
__device__ __forceinline__ bool nan_bits(float v) {
  union { float f; unsigned u; } c; c.f = v;
  return ((c.u >> 23) & 0xFFu) == 0xFFu && (c.u & 0x7FFFFFu) != 0u;
}

__global__ void k_prep(int* counts, float* out) {
  int t = threadIdx.x;
  if (t < 8) counts[t] = 0;
  if (t == 8) out[NPTS * 3] = 18.125f;  // KL(uniform||one-hot), bf16-rounded: data-independent
}

__global__ void k_sentinel(float* out) {
  if (threadIdx.x == 0) out[0] = 1.0e30f;  // ws_size-too-small marker
}

// ---------------- gate: L1 + L2 (bf16 MFMA, K=448) + L3 + argmax -> bucket scatter ----------------
__global__ __launch_bounds__(256) void k_gate(
    const float* __restrict__ x,
    const float* __restrict__ mW1, const float* __restrict__ mb1,
    const float* __restrict__ mW2, const float* __restrict__ mb2,
    const float* __restrict__ mW3, const float* __restrict__ mb3,
    int* __restrict__ counts, ushort_t* __restrict__ bucket)
{
  extern __shared__ char smem[];
  ushort_t* At  = (ushort_t*)smem;             // [64][40] bf16 A-tile (g1 slice)
  ushort_t* Bt  = (ushort_t*)(smem + 5120);    // [448][40] bf16 B-tile (transposed W2)
  float*    W1c = (float*)(smem + 40960);      // [4][448]: W1 rows 0..2 + b1 (bf16-rounded)
  ushort_t* g2  = (ushort_t*)smem;             // [64][456] bf16 (post-loop union over At/Bt/W1c)
  float*    b2c = (float*)(smem + 58368);      // [448]
  float*    xl  = (float*)(smem + 60160);      // [64*3]
  float*    lg  = (float*)(smem + 60928);      // [64][8]

  int tid = threadIdx.x;
  int blk = blockIdx.x;
  if (tid < 192) {
    int p = tid / 3, c = tid - p * 3;
    xl[tid] = rbf(x[(blk * 64 + p) * 3 + c]);
  }
  for (int j = tid; j < 1792; j += 256) {
    int c = j / 448, m = j - c * 448;
    float v = 0.f;
    if (m < 441) v = (c < 3) ? rbf(mW1[c * 441 + m]) : rbf(mb1[m]);
    W1c[j] = v;
  }
  for (int j = tid; j < 448; j += 256) b2c[j] = (j < 441) ? rbf(mb2[j]) : 0.f;

  int w = tid >> 6;
  int lane = tid & 63;
  int l15 = lane & 15, quad = lane >> 4;

  f32x4 acc[4][7];
  #pragma unroll
  for (int a = 0; a < 4; ++a)
    #pragma unroll
    for (int b = 0; b < 7; ++b)
      acc[a][b] = (f32x4){0.f, 0.f, 0.f, 0.f};

  int am = tid >> 2, ak = (tid & 3) * 8;

  for (int kt = 0; kt < 14; ++kt) {
    int kk0 = kt * 32;
    __syncthreads();  // prior MFMA reads of At/Bt done
    // stage A: g1 = relu(bf16(bf16(x@W1) + b1)) for this k-slice
    {
      float x0 = xl[am * 3], x1 = xl[am * 3 + 1], x2 = xl[am * 3 + 2];
      u16x8 tmp;
      #pragma unroll
      for (int u = 0; u < 8; ++u) {
        int j = kk0 + ak + u;
        ushort_t h = 0;
        if (j < 441) {
          float t = x0 * W1c[j];
          t = fmaf(x1, W1c[448 + j], t);
          t = fmaf(x2, W1c[896 + j], t);
          t = rbf(t);                    // matmul -> bf16
          t = rbf(t + W1c[1344 + j]);    // +b1 -> bf16
          t = fmaxf(t, 0.f);
          h = f2bf(t);
        }
        tmp[u] = h;
      }
      *(u16x8*)(At + am * 40 + ak) = tmp;
    }
    // stage B (coalesced): lane reads column n=tid (and n+256) over kr=0..31, writes u16x8 rows.
    // Global: lanes consecutive in n -> full coalescing. LDS: start banks 20n mod 32 tile all
    // 32 banks per 8 lanes -> conflict-free b128 stores.
    {
      int n1 = tid;
      #pragma unroll
      for (int q = 0; q < 4; ++q) {
        u16x8 tv;
        #pragma unroll
        for (int u = 0; u < 8; ++u) {
          int kk = kk0 + q * 8 + u;
          tv[u] = (kk < 441 && n1 < 441) ? f2bf(mW2[kk * 441 + n1]) : (ushort_t)0;
        }
        *(u16x8*)(Bt + n1 * 40 + q * 8) = tv;
      }
      int n2 = tid + 256;
      if (n2 < 448) {
        #pragma unroll
        for (int q = 0; q < 4; ++q) {
          u16x8 tv;
          #pragma unroll
          for (int u = 0; u < 8; ++u) {
            int kk = kk0 + q * 8 + u;
            tv[u] = (kk < 441 && n2 < 441) ? f2bf(mW2[kk * 441 + n2]) : (ushort_t)0;
          }
          *(u16x8*)(Bt + n2 * 40 + q * 8) = tv;
        }
      }
    }
    __syncthreads();
    bf16x8 bfr[7];
    #pragma unroll
    for (int j = 0; j < 7; ++j) {
      int nt = w + 4 * j;
      bfr[j] = *(const bf16x8*)(Bt + (nt * 16 + l15) * 40 + quad * 8);
    }
    #pragma unroll
    for (int mt = 0; mt < 4; ++mt) {
      bf16x8 a = *(const bf16x8*)(At + (mt * 16 + l15) * 40 + quad * 8);
      #pragma unroll
      for (int j = 0; j < 7; ++j)
        acc[mt][j] = __builtin_amdgcn_mfma_f32_16x16x32_bf16(a, bfr[j], acc[mt][j], 0, 0, 0);
    }
  }
  __syncthreads();
  // g2 = relu(bf16(bf16(acc) + b2)) -> bf16 LDS (C/D: col=lane&15, row=quad*4+r)
  #pragma unroll
  for (int mt = 0; mt < 4; ++mt) {
    #pragma unroll
    for (int j = 0; j < 7; ++j) {
      int c = (w + 4 * j) * 16 + l15;
      float bv = b2c[c];
      #pragma unroll
      for (int r = 0; r < 4; ++r) {
        int m = mt * 16 + quad * 4 + r;
        float v = rbf(acc[mt][j][r]);
        v = rbf(v + bv);
        v = fmaxf(v, 0.f);
        g2[m * 456 + c] = f2bf(v);
      }
    }
  }
  __syncthreads();
  // L3 logits: bf16(bf16(g2@W3) + b3), fp32 sequential accumulation
  {
    int m3 = tid >> 2, eg = tid & 3;
    float s0 = 0.f, s1 = 0.f;
    const ushort_t* row = g2 + m3 * 456;
    for (int j = 0; j < 441; ++j) {
      float gv = bf2f(row[j]);
      s0 = fmaf(gv, rbf(mW3[j * 8 + 2 * eg]), s0);
      s1 = fmaf(gv, rbf(mW3[j * 8 + 2 * eg + 1]), s1);
    }
    s0 = rbf(rbf(s0) + rbf(mb3[2 * eg]));
    s1 = rbf(rbf(s1) + rbf(mb3[2 * eg + 1]));
    lg[m3 * 8 + 2 * eg] = s0;
    lg[m3 * 8 + 2 * eg + 1] = s1;
  }
  __syncthreads();
  if (tid < 64) {  // wave 0: argmax + wave-aggregated bucket scatter (8 atomics/block)
    float best = lg[tid * 8];
    int bi = 0;
    #pragma unroll
    for (int e = 1; e < 8; ++e) {
      float v = lg[tid * 8 + e];
      if (v > best) { best = v; bi = e; }   // strict > : first-index tie-break = np.argmax
    }
    int slot = 0;
    #pragma unroll
    for (int e = 0; e < 8; ++e) {
      unsigned long long msk = __ballot(bi == e);
      if (bi == e) {
        int leader = (int)__builtin_ctzll(msk);
        int rank = __popcll(msk & ((1ull << tid) - 1ull));
        int basep = 0;
        if (tid == leader) basep = atomicAdd(&counts[e], __popcll(msk));
        basep = __shfl(basep, leader);
        slot = basep + rank;
      }
    }
    bucket[bi * NPTS + slot] = (ushort_t)(blk * 64 + tid);
  }
}

// ---------------- bucketed SIREN expert + decoder: 64 pts/block, reg A-cache, wb dbuf ----------------
__global__ __launch_bounds__(256) void k_sdec(
    const float* __restrict__ x,
    const float* __restrict__ sW1, const float* __restrict__ sb1,
    const float* __restrict__ sWh, const float* __restrict__ sbh,
    const float* __restrict__ sWo, const float* __restrict__ sbo,
    const float* __restrict__ dW1, const float* __restrict__ db1,
    const float* __restrict__ dW2, const float* __restrict__ db2,
    const int* __restrict__ counts, const ushort_t* __restrict__ bucket,
    float* __restrict__ out)
{
  __shared__ ushort_t hA[64][264];      // activations (bf16 bits)
  __shared__ ushort_t wb[2][16][264];   // weight tile double-buffer
  __shared__ int idxl[64];
  __shared__ float xl[64][3];
  __shared__ float wc[944];

  int e = blockIdx.y;
  int base = blockIdx.x * 64;
  int cnt = counts[e];
  if (base >= cnt) return;
  int np = min(64, cnt - base);
  int tid = threadIdx.x;

  if (tid < 64) {
    int s = base + (tid < np ? tid : 0);   // pad rows duplicate a real point
    idxl[tid] = (int)bucket[e * NPTS + s];
  }
  __syncthreads();
  if (tid < 192) {
    int p = tid / 3, c = tid - p * 3;
    xl[p][c] = rbf(x[idxl[p] * 3 + c]);
  }
  for (int j = tid; j < 944; j += 256)
    wc[j] = (j < 708) ? rbf(sW1[e * 708 + j]) : rbf(sb1[e * 236 + (j - 708)]);
  for (int t = tid; t < 64 * 28; t += 256) {   // zero K-pad cols [236,264)
    int p = t / 28, cc = 236 + (t - p * 28);
    hA[p][cc] = 0;
  }
  __syncthreads();
  // L1: h = bf16(sin(bf16(30*bf16(bf16(x@W1)+b1))))
  for (int t = tid; t < 64 * 236; t += 256) {
    int p = t / 236, f = t - p * 236;
    float v = xl[p][0] * wc[f];
    v = fmaf(xl[p][1], wc[236 + f], v);
    v = fmaf(xl[p][2], wc[472 + f], v);
    v = rbf(v);
    v = rbf(v + wc[708 + f]);
    v = rbf(30.f * v);
    hA[p][f] = f2bf(sinf(v));
  }

  int w = tid >> 6, lane = tid & 63;
  int l15 = lane & 15, quad = lane >> 4;

  auto stage = [&](const float* W, int t, ushort_t (*buf)[264]) {
    int k = tid;
    if (k < 236) {
      const float* srcW = W + k * 236 + t * 16;
      int jmax = 236 - t * 16; if (jmax > 16) jmax = 16;
      float tv[16];
      if (jmax == 16) {
        *(f32x4*)(tv)      = *(const f32x4*)(srcW);
        *(f32x4*)(tv + 4)  = *(const f32x4*)(srcW + 4);
        *(f32x4*)(tv + 8)  = *(const f32x4*)(srcW + 8);
        *(f32x4*)(tv + 12) = *(const f32x4*)(srcW + 12);
      } else {  // t==14: only 12 valid, don't read past matrix end
        *(f32x4*)(tv)      = *(const f32x4*)(srcW);
        *(f32x4*)(tv + 4)  = *(const f32x4*)(srcW + 4);
        *(f32x4*)(tv + 8)  = *(const f32x4*)(srcW + 8);
        tv[12] = tv[13] = tv[14] = tv[15] = 0.f;
      }
      #pragma unroll
      for (int j = 0; j < 16; ++j)
        buf[j][k] = (j < jmax) ? f2bf(tv[j]) : (ushort_t)0;
    } else {
      #pragma unroll
      for (int j = 0; j < 16; ++j) buf[j][k] = 0;
    }
  };

  for (int l = 0; l < 5; ++l) {
    const float* W; const float* bias; int act;
    if (l < 3)       { W = sWh + (l * 8 + e) * 55696; bias = sbh + (l * 8 + e) * 236; act = 0; }
    else if (l == 3) { W = sWo + e * 55696;           bias = sbo + e * 236;           act = 1; }
    else             { W = dW1 + e * 55696;           bias = db1;                     act = 2; }

    __syncthreads();  // hA writes from previous layer complete
    bf16x8 afr[4][8];  // reg-cache all A-fragments; enables in-place hA update
    #pragma unroll
    for (int mt = 0; mt < 4; ++mt)
      #pragma unroll
      for (int kt = 0; kt < 8; ++kt)
        afr[mt][kt] = *(const bf16x8*)(&hA[mt * 16 + l15][kt * 32 + quad * 8]);
    stage(W, 0, wb[0]);
    __syncthreads();  // afr loads (all waves) + wb[0] staged

    for (int t = 0; t < 15; ++t) {
      if (t < 14) stage(W, t + 1, wb[(t + 1) & 1]);
      if ((t & 3) == w) {  // wave-per-n-tile
        f32x4 acc[4];
        #pragma unroll
        for (int mt = 0; mt < 4; ++mt) acc[mt] = (f32x4){0.f, 0.f, 0.f, 0.f};
        #pragma unroll
        for (int kt = 0; kt < 8; ++kt) {
          bf16x8 b = *(const bf16x8*)(&wb[t & 1][l15][kt * 32 + quad * 8]);
          #pragma unroll
          for (int mt = 0; mt < 4; ++mt)
            acc[mt] = __builtin_amdgcn_mfma_f32_16x16x32_bf16(afr[mt][kt], b, acc[mt], 0, 0, 0);
        }
        int n = t * 16 + l15;
        if (n < 236) {
          float bv = rbf(bias[n]);
          #pragma unroll
          for (int mt = 0; mt < 4; ++mt) {
            #pragma unroll
            for (int r = 0; r < 4; ++r) {
              int m = mt * 16 + quad * 4 + r;
              float v = rbf(acc[mt][r]);      // einsum -> bf16
              v = rbf(v + bv);                // +bias -> bf16
              if (act == 0) { v = rbf(30.f * v); v = sinf(v); }
              else if (act == 2) v = fmaxf(v, 0.f);
              hA[m][n] = f2bf(v);             // in-place ok: afr reg-cached
            }
          }
        }
      }
      __syncthreads();
    }
  }

  // dec2: out = bf16(bf16(h@dW2) + db2), float32 store
  for (int j = tid; j < 711; j += 256)
    wc[j] = (j < 708) ? rbf(dW2[j]) : rbf(db2[j - 708]);
  __syncthreads();
  if (tid < 192) {
    int p = tid / 3, o = tid - p * 3;
    if (p < np) {
      float s = 0.f;
      for (int k = 0; k < 236; ++k)
        s = fmaf(bf2f(hA[p][k]), wc[k * 3 + o], s);
      s = rbf(s);
      s = rbf(s + wc[708 + o]);
      float val;
      if (nan_bits(s)) val = 16.0f;                       // NaN tripwire
      else             val = fminf(fmaxf(s, -4.f), 4.f);  // overflow tripwire (legit |s| <= ~0.6)
      out[idxl[p] * 3 + o] = val;
    }
  }
}

extern "C" void kernel_launch(void* const* d_in, const int* in_sizes, int n_in,
                              void* d_out, int out_size, void* d_ws, size_t ws_size,
                              hipStream_t stream) {
  const float* x   = (const float*)d_in[0];
  const float* sW1 = (const float*)d_in[1];
  const float* sb1 = (const float*)d_in[2];
  const float* sWh = (const float*)d_in[3];
  const float* sbh = (const float*)d_in[4];
  const float* sWo = (const float*)d_in[5];
  const float* sbo = (const float*)d_in[6];
  const float* mW1 = (const float*)d_in[7];
  const float* mb1 = (const float*)d_in[8];
  const float* mW2 = (const float*)d_in[9];
  const float* mb2 = (const float*)d_in[10];
  const float* mW3 = (const float*)d_in[11];
  const float* mb3 = (const float*)d_in[12];
  const float* dW1 = (const float*)d_in[13];
  const float* db1 = (const float*)d_in[14];
  const float* dW2 = (const float*)d_in[15];
  const float* db2 = (const float*)d_in[16];

  float* outp = (float*)d_out;
  if (ws_size < (size_t)WS_NEED) {
    k_sentinel<<<dim3(1), dim3(64), 0, stream>>>(outp);
    return;
  }
  char* ws = (char*)d_ws;
  int* counts      = (int*)(ws + WS_CNT);
  ushort_t* bucket = (ushort_t*)(ws + WS_BKT);

  k_prep<<<dim3(1), dim3(64), 0, stream>>>(counts, outp);
  k_gate<<<dim3(1024), dim3(256), 62976, stream>>>(x, mW1, mb1, mW2, mb2, mW3, mb3, counts, bucket);
  k_sdec<<<dim3(1024, 8), dim3(256), 0, stream>>>(x, sW1, sb1, sWh, sbh, sWo, sbo,
                                                  dW1, db1, dW2, db2, counts, bucket, outp);
}

// Round 7
// 590.968 us; speedup vs baseline: 2.2824x; 1.6077x over previous
//
#include <hip/hip_runtime.h>
#include <cstdint>

typedef unsigned short ushort_t;
typedef short bf16x8 __attribute__((ext_vector_type(8)));
typedef unsigned short u16x8 __attribute__((ext_vector_type(8)));
typedef float f32x4 __attribute__((ext_vector_type(4)));

#define NPTS 65536
// ws layout (fast): counts@0 | bucket@64 (1,048,576) | W2S@1,048,640 (401,408)
//                 | w3T@1,450,048 (14,592) | swt@1,464,640 (5,068,800) => 6,533,440
#define WS_CNT 0
#define WS_BKT 64
#define OFF_W2S 1048640
#define OFF_W3T 1450048
#define OFF_SWT 1464640
#define WS_FAST 6533440u
#define WS_SLOW (64 + 8 * NPTS * 2)

__device__ __forceinline__ float bf2f(ushort_t u) {
  union { unsigned u; float f; } c; c.u = ((unsigned)u) << 16; return c.f;
}
__device__ __forceinline__ ushort_t f2bf(float f) {
  union { float f; unsigned u; } c; c.f = f;
  unsigned u = c.u + 0x7fffu + ((c.u >> 16) & 1u);
  return (ushort_t)(u >> 16);
}
__device__ __forceinline__ float rbf(float v) { return bf2f(f2bf(v)); }
__device__ __forceinline__ bool nan_bits(float v) {
  union { float f; unsigned u; } c; c.f = v;
  return ((c.u >> 23) & 0xFFu) == 0xFFu && (c.u & 0x7FFFFFu) != 0u;
}

__global__ void k_sentinel(float* out) {
  if (threadIdx.x == 0) out[0] = 1.0e30f;  // ws_size-too-small marker
}

// ==================== FAST PATH ====================

// prep: all weight transpose/bf16-convert hoisted here (runs once per launch).
__global__ __launch_bounds__(256) void k_prep_fast(
    const float* __restrict__ sWh, const float* __restrict__ sWo,
    const float* __restrict__ dW1, const float* __restrict__ mW2,
    const float* __restrict__ mW3,
    int* __restrict__ counts, ushort_t* __restrict__ W2S,
    ushort_t* __restrict__ w3T, ushort_t* __restrict__ swt, float* __restrict__ out)
{
  long gid = (long)blockIdx.x * 256 + threadIdx.x;
  long gs = (long)gridDim.x * 256;
  // swt: 40 mats x [240 n][264 k]; swt[mat][n][k] = bf16(W[k*236+n]); zero-padded
  for (long i = gid; i < 40L * 63360; i += gs) {
    int mat = (int)(i / 63360);
    int r = (int)(i - (long)mat * 63360);
    int n = r / 264, k = r - n * 264;
    ushort_t v = 0;
    if (n < 236 && k < 236) {
      const float* W = (mat < 24) ? (sWh + (long)mat * 55696)
                     : (mat < 32) ? (sWo + (long)(mat - 24) * 55696)
                                  : (dW1 + (long)(mat - 32) * 55696);
      v = f2bf(W[k * 236 + n]);
    }
    swt[i] = v;
  }
  // W2S: pre-swizzled B-fragments [kt 14][nt 28][lane 64][u 8]
  for (long i = gid; i < 25088; i += gs) {
    int kt = (int)(i / (28 * 64));
    int rem = (int)(i - (long)kt * 28 * 64);
    int nt = rem / 64, lane = rem - nt * 64;
    int l15 = lane & 15, quad = lane >> 4;
    int n = nt * 16 + l15;
    u16x8 tv;
    #pragma unroll
    for (int u = 0; u < 8; ++u) {
      int k = kt * 32 + quad * 8 + u;
      tv[u] = (k < 441 && n < 441) ? f2bf(mW2[(long)k * 441 + n]) : (ushort_t)0;
    }
    *(u16x8*)(W2S + i * 8) = tv;
  }
  // w3T: [16 e][456 c] (zero-padded) for L3 B-fragments
  for (long i = gid; i < 7296; i += gs) {
    int e = (int)(i / 456), c = (int)(i - (long)e * 456);
    w3T[i] = (e < 8 && c < 441) ? f2bf(mW3[(long)c * 8 + e]) : (ushort_t)0;
  }
  if (gid < 8) counts[gid] = 0;
  if (gid == 8) out[NPTS * 3] = 18.125f;  // KL(uniform||one-hot): data-independent
}

// gate: L1 recompute + L2 bf16-MFMA (B direct from W2S, coalesced) + L3 via chunked MFMA
__global__ __launch_bounds__(256) void k_gate_fast(
    const float* __restrict__ x,
    const float* __restrict__ mW1, const float* __restrict__ mb1,
    const float* __restrict__ mb2, const float* __restrict__ mb3,
    const ushort_t* __restrict__ W2S, const ushort_t* __restrict__ w3Tg,
    int* __restrict__ counts, ushort_t* __restrict__ bucket)
{
  __shared__ ushort_t At[64][40];       // 5120
  __shared__ float W1c[1792];           // 7168
  __shared__ float xl[192];             // 768
  __shared__ ushort_t chunkC[64][72];   // 9216 (pad 72: 2-way banks on b128 reads)
  __shared__ ushort_t w3T[16][456];     // 14592 (stride 912B -> 2-way banks)
  __shared__ float b2c[448];            // 1792
  __shared__ unsigned char bexp[64];

  int tid = threadIdx.x;
  int blk = blockIdx.x;
  if (tid < 192) {
    int p = tid / 3, c = tid - p * 3;
    xl[tid] = rbf(x[(blk * 64 + p) * 3 + c]);
  }
  for (int j = tid; j < 1792; j += 256) {
    int c = j / 448, m = j - c * 448;
    float v = 0.f;
    if (m < 441) v = (c < 3) ? rbf(mW1[c * 441 + m]) : rbf(mb1[m]);
    W1c[j] = v;
  }
  for (int j = tid; j < 448; j += 256) b2c[j] = (j < 441) ? rbf(mb2[j]) : 0.f;
  for (int ch = tid; ch < 912; ch += 256)
    *(u16x8*)(&w3T[0][0] + ch * 8) = *(const u16x8*)(w3Tg + ch * 8);

  int w = tid >> 6, lane = tid & 63;
  int l15 = lane & 15, quad = lane >> 4;

  f32x4 acc[4][7];
  #pragma unroll
  for (int a = 0; a < 4; ++a)
    #pragma unroll
    for (int b = 0; b < 7; ++b)
      acc[a][b] = (f32x4){0.f, 0.f, 0.f, 0.f};

  int am = tid >> 2, ak = (tid & 3) * 8;

  for (int kt = 0; kt < 14; ++kt) {
    int kk0 = kt * 32;
    __syncthreads();  // prior At reads done (covers preload fills on kt==0)
    // stage A: g1 = relu(bf16(bf16(x@W1) + b1)) for this k-slice
    {
      float x0 = xl[am * 3], x1 = xl[am * 3 + 1], x2 = xl[am * 3 + 2];
      u16x8 tmp;
      #pragma unroll
      for (int u = 0; u < 8; ++u) {
        int j = kk0 + ak + u;
        ushort_t h = 0;
        if (j < 441) {
          float t = x0 * W1c[j];
          t = fmaf(x1, W1c[448 + j], t);
          t = fmaf(x2, W1c[896 + j], t);
          t = rbf(t);                    // matmul -> bf16
          t = rbf(t + W1c[1344 + j]);    // +b1 -> bf16
          t = fmaxf(t, 0.f);
          h = f2bf(t);
        }
        tmp[u] = h;
      }
      *(u16x8*)(At[am] + ak) = tmp;
    }
    __syncthreads();
    bf16x8 bfr[7];
    #pragma unroll
    for (int j = 0; j < 7; ++j)  // coalesced: lanes consecutive 16B chunks
      bfr[j] = *(const bf16x8*)(W2S + ((kt * 28 + (w + 4 * j)) * 64 + lane) * 8);
    #pragma unroll
    for (int mt = 0; mt < 4; ++mt) {
      bf16x8 a = *(const bf16x8*)(&At[mt * 16 + l15][quad * 8]);
      #pragma unroll
      for (int j = 0; j < 7; ++j)
        acc[mt][j] = __builtin_amdgcn_mfma_f32_16x16x32_bf16(a, bfr[j], acc[mt][j], 0, 0, 0);
    }
  }

  // L3 via MFMA over 7 column-chunks of g2 (64 c each); g2 chunk from live acc regs.
  f32x4 acc3[4];
  #pragma unroll
  for (int mt = 0; mt < 4; ++mt) acc3[mt] = (f32x4){0.f, 0.f, 0.f, 0.f};
  for (int j = 0; j < 7; ++j) {
    __syncthreads();  // previous chunk reads (or kt-loop At reads) done
    #pragma unroll
    for (int mt = 0; mt < 4; ++mt) {
      #pragma unroll
      for (int r = 0; r < 4; ++r) {
        int cg = j * 64 + w * 16 + l15;        // global col
        int m = mt * 16 + quad * 4 + r;
        float v = rbf(acc[mt][j][r]);          // einsum -> bf16
        v = rbf(v + b2c[cg]);                  // +b2 -> bf16
        v = fmaxf(v, 0.f);                     // relu
        chunkC[m][w * 16 + l15] = f2bf(v);
      }
    }
    __syncthreads();
    bf16x8 b0 = *(const bf16x8*)(&w3T[l15][j * 64 + quad * 8]);
    bf16x8 b1 = *(const bf16x8*)(&w3T[l15][j * 64 + 32 + quad * 8]);
    #pragma unroll
    for (int mt = 0; mt < 4; ++mt) {
      bf16x8 a0 = *(const bf16x8*)(&chunkC[mt * 16 + l15][quad * 8]);
      bf16x8 a1 = *(const bf16x8*)(&chunkC[mt * 16 + l15][32 + quad * 8]);
      acc3[mt] = __builtin_amdgcn_mfma_f32_16x16x32_bf16(a0, b0, acc3[mt], 0, 0, 0);
      acc3[mt] = __builtin_amdgcn_mfma_f32_16x16x32_bf16(a1, b1, acc3[mt], 0, 0, 0);
    }
  }
  // logits in C-layout: e = l15, m = mt*16+quad*4+r. Argmax via 8-lane butterfly.
  float b3v = (l15 < 8) ? rbf(mb3[l15]) : 0.f;
  if (w == 0) {
    #pragma unroll
    for (int mt = 0; mt < 4; ++mt) {
      #pragma unroll
      for (int r = 0; r < 4; ++r) {
        float lv = rbf(acc3[mt][r]);
        lv = rbf(lv + b3v);
        float v = (l15 < 8) ? lv : -1.0e30f;
        int ii = l15;
        #pragma unroll
        for (int mk = 1; mk < 8; mk <<= 1) {
          float ov = __shfl_xor(v, mk);
          int oi = __shfl_xor(ii, mk);
          if (ov > v || (ov == v && oi < ii)) { v = ov; ii = oi; }  // first-max = np.argmax
        }
        if (l15 == 0) bexp[mt * 16 + quad * 4 + r] = (unsigned char)ii;
      }
    }
  }
  __syncthreads();
  if (tid < 64) {  // wave 0: wave-aggregated bucket scatter (<=8 atomics/block)
    int bi = (int)bexp[tid];
    int slot = 0;
    #pragma unroll
    for (int ee = 0; ee < 8; ++ee) {
      unsigned long long msk = __ballot(bi == ee);
      if (bi == ee) {
        int leader = (int)__builtin_ctzll(msk);
        int rank = __popcll(msk & ((1ull << tid) - 1ull));
        int basep = 0;
        if (tid == leader) basep = atomicAdd(&counts[ee], __popcll(msk));
        basep = __shfl(basep, leader);
        slot = basep + rank;
      }
    }
    bucket[bi * NPTS + slot] = (ushort_t)(blk * 64 + tid);
  }
}

// sdec: bucketed, wave-per-mt MFMA, weights pre-staged bf16 in swt (copy-only staging)
__global__ __launch_bounds__(256) void k_sdec_fast(
    const float* __restrict__ x,
    const float* __restrict__ sW1, const float* __restrict__ sb1,
    const float* __restrict__ sbh, const float* __restrict__ sbo,
    const float* __restrict__ db1, const float* __restrict__ dW2,
    const float* __restrict__ db2,
    const ushort_t* __restrict__ swt,
    const int* __restrict__ counts, const ushort_t* __restrict__ bucket,
    float* __restrict__ out)
{
  __shared__ ushort_t hA[64][264];        // 33792
  __shared__ ushort_t wbuf[2][16][264];   // 16896 (wc overlays: only used outside layer loop)
  __shared__ int idxl[64];
  __shared__ float xl[64][3];
  float* wc = (float*)&wbuf[0][0][0];     // 944 f32 = 3776 B

  int e = blockIdx.y;
  int base = blockIdx.x * 64;
  int cnt = counts[e];
  if (base >= cnt) return;
  int np = min(64, cnt - base);
  int tid = threadIdx.x;

  if (tid < 64) {
    int s = base + (tid < np ? tid : 0);   // pad rows duplicate a real point
    idxl[tid] = (int)bucket[e * NPTS + s];
  }
  __syncthreads();
  if (tid < 192) {
    int p = tid / 3, c = tid - p * 3;
    xl[p][c] = rbf(x[idxl[p] * 3 + c]);
  }
  for (int j = tid; j < 944; j += 256)
    wc[j] = (j < 708) ? rbf(sW1[e * 708 + j]) : rbf(sb1[e * 236 + (j - 708)]);
  for (int t = tid; t < 64 * 28; t += 256) {   // zero K-pad cols [236,264) once
    int p = t / 28, cc = 236 + (t - p * 28);
    hA[p][cc] = 0;
  }
  __syncthreads();
  // L1: h = bf16(sin(bf16(30*bf16(bf16(x@W1)+b1))))
  for (int t = tid; t < 64 * 236; t += 256) {
    int p = t / 236, f = t - p * 236;
    float v = xl[p][0] * wc[f];
    v = fmaf(xl[p][1], wc[236 + f], v);
    v = fmaf(xl[p][2], wc[472 + f], v);
    v = rbf(v);
    v = rbf(v + wc[708 + f]);
    v = rbf(30.f * v);
    hA[p][f] = f2bf(sinf(v));
  }

  int w = tid >> 6, lane = tid & 63;
  int l15 = lane & 15, quad = lane >> 4;

  for (int l = 0; l < 5; ++l) {
    const ushort_t* Wt; const float* bias; int act;
    if (l < 3)       { Wt = swt + (l * 8 + e) * 63360; bias = sbh + (l * 8 + e) * 236; act = 0; }
    else if (l == 3) { Wt = swt + (24 + e) * 63360;    bias = sbo + e * 236;           act = 1; }
    else             { Wt = swt + (32 + e) * 63360;    bias = db1;                     act = 2; }

    __syncthreads();  // hA complete; wbuf free (covers L1/wc phase on l==0)
    bf16x8 afr[8];    // wave w caches only its own 16 rows -> in-place hA update safe
    #pragma unroll
    for (int kt = 0; kt < 8; ++kt)
      afr[kt] = *(const bf16x8*)(&hA[w * 16 + l15][kt * 32 + quad * 8]);
    {  // stage tile 0 (pure 16B copies; tile = contiguous 8448 B, zero-padded in prep)
      const ushort_t* src = Wt;
      ushort_t* dst = &wbuf[0][0][0];
      *(u16x8*)(dst + tid * 8)         = *(const u16x8*)(src + tid * 8);
      *(u16x8*)(dst + (tid + 256) * 8) = *(const u16x8*)(src + (tid + 256) * 8);
      if (tid < 16)
        *(u16x8*)(dst + (tid + 512) * 8) = *(const u16x8*)(src + (tid + 512) * 8);
    }
    __syncthreads();

    for (int t = 0; t < 15; ++t) {
      if (t < 14) {  // prefetch next tile into other buffer
        const ushort_t* src = Wt + (t + 1) * 4224;
        ushort_t* dst = &wbuf[(t + 1) & 1][0][0];
        *(u16x8*)(dst + tid * 8)         = *(const u16x8*)(src + tid * 8);
        *(u16x8*)(dst + (tid + 256) * 8) = *(const u16x8*)(src + (tid + 256) * 8);
        if (tid < 16)
          *(u16x8*)(dst + (tid + 512) * 8) = *(const u16x8*)(src + (tid + 512) * 8);
      }
      f32x4 acc = (f32x4){0.f, 0.f, 0.f, 0.f};
      #pragma unroll
      for (int kt = 0; kt < 8; ++kt) {
        bf16x8 b = *(const bf16x8*)(&wbuf[t & 1][l15][kt * 32 + quad * 8]);
        acc = __builtin_amdgcn_mfma_f32_16x16x32_bf16(afr[kt], b, acc, 0, 0, 0);
      }
      int n = t * 16 + l15;
      if (n < 236) {
        float bv = rbf(bias[n]);
        #pragma unroll
        for (int r = 0; r < 4; ++r) {
          int m = w * 16 + quad * 4 + r;
          float v = rbf(acc[r]);      // einsum -> bf16
          v = rbf(v + bv);            // +bias -> bf16
          if (act == 0) { v = rbf(30.f * v); v = sinf(v); }
          else if (act == 2) v = fmaxf(v, 0.f);
          hA[m][n] = f2bf(v);         // wave w writes only its own rows
        }
      }
      __syncthreads();
    }
  }

  // dec2: out = bf16(bf16(h@dW2) + db2), float32 store
  for (int j = tid; j < 711; j += 256)
    wc[j] = (j < 708) ? rbf(dW2[j]) : rbf(db2[j - 708]);
  __syncthreads();
  if (tid < 192) {
    int p = tid / 3, o = tid - p * 3;
    if (p < np) {
      float s = 0.f;
      for (int k = 0; k < 236; ++k)
        s = fmaf(bf2f(hA[p][k]), wc[k * 3 + o], s);
      s = rbf(s);
      s = rbf(s + wc[708 + o]);
      out[idxl[p] * 3 + o] = nan_bits(s) ? 16.0f : fminf(fmaxf(s, -4.f), 4.f);
    }
  }
}

// ==================== SLOW PATH (round-6, proven; used when ws too small) ====================

__global__ void k_prep_slow(int* counts, float* out) {
  int t = threadIdx.x;
  if (t < 8) counts[t] = 0;
  if (t == 8) out[NPTS * 3] = 18.125f;
}

__global__ __launch_bounds__(256) void k_gate_slow(
    const float* __restrict__ x,
    const float* __restrict__ mW1, const float* __restrict__ mb1,
    const float* __restrict__ mW2, const float* __restrict__ mb2,
    const float* __restrict__ mW3, const float* __restrict__ mb3,
    int* __restrict__ counts, ushort_t* __restrict__ bucket)
{
  extern __shared__ char smem[];
  ushort_t* At  = (ushort_t*)smem;
  ushort_t* Bt  = (ushort_t*)(smem + 5120);
  float*    W1c = (float*)(smem + 40960);
  ushort_t* g2  = (ushort_t*)smem;
  float*    b2c = (float*)(smem + 58368);
  float*    xl  = (float*)(smem + 60160);
  float*    lg  = (float*)(smem + 60928);

  int tid = threadIdx.x;
  int blk = blockIdx.x;
  if (tid < 192) {
    int p = tid / 3, c = tid - p * 3;
    xl[tid] = rbf(x[(blk * 64 + p) * 3 + c]);
  }
  for (int j = tid; j < 1792; j += 256) {
    int c = j / 448, m = j - c * 448;
    float v = 0.f;
    if (m < 441) v = (c < 3) ? rbf(mW1[c * 441 + m]) : rbf(mb1[m]);
    W1c[j] = v;
  }
  for (int j = tid; j < 448; j += 256) b2c[j] = (j < 441) ? rbf(mb2[j]) : 0.f;

  int w = tid >> 6, lane = tid & 63;
  int l15 = lane & 15, quad = lane >> 4;

  f32x4 acc[4][7];
  #pragma unroll
  for (int a = 0; a < 4; ++a)
    #pragma unroll
    for (int b = 0; b < 7; ++b)
      acc[a][b] = (f32x4){0.f, 0.f, 0.f, 0.f};

  int am = tid >> 2, ak = (tid & 3) * 8;

  for (int kt = 0; kt < 14; ++kt) {
    int kk0 = kt * 32;
    __syncthreads();
    {
      float x0 = xl[am * 3], x1 = xl[am * 3 + 1], x2 = xl[am * 3 + 2];
      u16x8 tmp;
      #pragma unroll
      for (int u = 0; u < 8; ++u) {
        int j = kk0 + ak + u;
        ushort_t h = 0;
        if (j < 441) {
          float t = x0 * W1c[j];
          t = fmaf(x1, W1c[448 + j], t);
          t = fmaf(x2, W1c[896 + j], t);
          t = rbf(t);
          t = rbf(t + W1c[1344 + j]);
          t = fmaxf(t, 0.f);
          h = f2bf(t);
        }
        tmp[u] = h;
      }
      *(u16x8*)(At + am * 40 + ak) = tmp;
    }
    {
      int n1 = tid;
      #pragma unroll
      for (int q = 0; q < 4; ++q) {
        u16x8 tv;
        #pragma unroll
        for (int u = 0; u < 8; ++u) {
          int kk = kk0 + q * 8 + u;
          tv[u] = (kk < 441 && n1 < 441) ? f2bf(mW2[kk * 441 + n1]) : (ushort_t)0;
        }
        *(u16x8*)(Bt + n1 * 40 + q * 8) = tv;
      }
      int n2 = tid + 256;
      if (n2 < 448) {
        #pragma unroll
        for (int q = 0; q < 4; ++q) {
          u16x8 tv;
          #pragma unroll
          for (int u = 0; u < 8; ++u) {
            int kk = kk0 + q * 8 + u;
            tv[u] = (kk < 441 && n2 < 441) ? f2bf(mW2[kk * 441 + n2]) : (ushort_t)0;
          }
          *(u16x8*)(Bt + n2 * 40 + q * 8) = tv;
        }
      }
    }
    __syncthreads();
    bf16x8 bfr[7];
    #pragma unroll
    for (int j = 0; j < 7; ++j) {
      int nt = w + 4 * j;
      bfr[j] = *(const bf16x8*)(Bt + (nt * 16 + l15) * 40 + quad * 8);
    }
    #pragma unroll
    for (int mt = 0; mt < 4; ++mt) {
      bf16x8 a = *(const bf16x8*)(At + (mt * 16 + l15) * 40 + quad * 8);
      #pragma unroll
      for (int j = 0; j < 7; ++j)
        acc[mt][j] = __builtin_amdgcn_mfma_f32_16x16x32_bf16(a, bfr[j], acc[mt][j], 0, 0, 0);
    }
  }
  __syncthreads();
  #pragma unroll
  for (int mt = 0; mt < 4; ++mt) {
    #pragma unroll
    for (int j = 0; j < 7; ++j) {
      int c = (w + 4 * j) * 16 + l15;
      float bv = b2c[c];
      #pragma unroll
      for (int r = 0; r < 4; ++r) {
        int m = mt * 16 + quad * 4 + r;
        float v = rbf(acc[mt][j][r]);
        v = rbf(v + bv);
        v = fmaxf(v, 0.f);
        g2[m * 456 + c] = f2bf(v);
      }
    }
  }
  __syncthreads();
  {
    int m3 = tid >> 2, eg = tid & 3;
    float s0 = 0.f, s1 = 0.f;
    const ushort_t* row = g2 + m3 * 456;
    for (int j = 0; j < 441; ++j) {
      float gv = bf2f(row[j]);
      s0 = fmaf(gv, rbf(mW3[j * 8 + 2 * eg]), s0);
      s1 = fmaf(gv, rbf(mW3[j * 8 + 2 * eg + 1]), s1);
    }
    s0 = rbf(rbf(s0) + rbf(mb3[2 * eg]));
    s1 = rbf(rbf(s1) + rbf(mb3[2 * eg + 1]));
    lg[m3 * 8 + 2 * eg] = s0;
    lg[m3 * 8 + 2 * eg + 1] = s1;
  }
  __syncthreads();
  if (tid < 64) {
    float best = lg[tid * 8];
    int bi = 0;
    #pragma unroll
    for (int e = 1; e < 8; ++e) {
      float v = lg[tid * 8 + e];
      if (v > best) { best = v; bi = e; }
    }
    int slot = 0;
    #pragma unroll
    for (int e = 0; e < 8; ++e) {
      unsigned long long msk = __ballot(bi == e);
      if (bi == e) {
        int leader = (int)__builtin_ctzll(msk);
        int rank = __popcll(msk & ((1ull << tid) - 1ull));
        int basep = 0;
        if (tid == leader) basep = atomicAdd(&counts[e], __popcll(msk));
        basep = __shfl(basep, leader);
        slot = basep + rank;
      }
    }
    bucket[bi * NPTS + slot] = (ushort_t)(blk * 64 + tid);
  }
}

__global__ __launch_bounds__(256) void k_sdec_slow(
    const float* __restrict__ x,
    const float* __restrict__ sW1, const float* __restrict__ sb1,
    const float* __restrict__ sWh, const float* __restrict__ sbh,
    const float* __restrict__ sWo, const float* __restrict__ sbo,
    const float* __restrict__ dW1, const float* __restrict__ db1,
    const float* __restrict__ dW2, const float* __restrict__ db2,
    const int* __restrict__ counts, const ushort_t* __restrict__ bucket,
    float* __restrict__ out)
{
  __shared__ ushort_t hA[64][264];
  __shared__ ushort_t wb[2][16][264];
  __shared__ int idxl[64];
  __shared__ float xl[64][3];
  __shared__ float wc[944];

  int e = blockIdx.y;
  int base = blockIdx.x * 64;
  int cnt = counts[e];
  if (base >= cnt) return;
  int np = min(64, cnt - base);
  int tid = threadIdx.x;

  if (tid < 64) {
    int s = base + (tid < np ? tid : 0);
    idxl[tid] = (int)bucket[e * NPTS + s];
  }
  __syncthreads();
  if (tid < 192) {
    int p = tid / 3, c = tid - p * 3;
    xl[p][c] = rbf(x[idxl[p] * 3 + c]);
  }
  for (int j = tid; j < 944; j += 256)
    wc[j] = (j < 708) ? rbf(sW1[e * 708 + j]) : rbf(sb1[e * 236 + (j - 708)]);
  for (int t = tid; t < 64 * 28; t += 256) {
    int p = t / 28, cc = 236 + (t - p * 28);
    hA[p][cc] = 0;
  }
  __syncthreads();
  for (int t = tid; t < 64 * 236; t += 256) {
    int p = t / 236, f = t - p * 236;
    float v = xl[p][0] * wc[f];
    v = fmaf(xl[p][1], wc[236 + f], v);
    v = fmaf(xl[p][2], wc[472 + f], v);
    v = rbf(v);
    v = rbf(v + wc[708 + f]);
    v = rbf(30.f * v);
    hA[p][f] = f2bf(sinf(v));
  }

  int w = tid >> 6, lane = tid & 63;
  int l15 = lane & 15, quad = lane >> 4;

  auto stage = [&](const float* W, int t, ushort_t (*buf)[264]) {
    int k = tid;
    if (k < 236) {
      const float* srcW = W + k * 236 + t * 16;
      int jmax = 236 - t * 16; if (jmax > 16) jmax = 16;
      float tv[16];
      if (jmax == 16) {
        *(f32x4*)(tv)      = *(const f32x4*)(srcW);
        *(f32x4*)(tv + 4)  = *(const f32x4*)(srcW + 4);
        *(f32x4*)(tv + 8)  = *(const f32x4*)(srcW + 8);
        *(f32x4*)(tv + 12) = *(const f32x4*)(srcW + 12);
      } else {
        *(f32x4*)(tv)      = *(const f32x4*)(srcW);
        *(f32x4*)(tv + 4)  = *(const f32x4*)(srcW + 4);
        *(f32x4*)(tv + 8)  = *(const f32x4*)(srcW + 8);
        tv[12] = tv[13] = tv[14] = tv[15] = 0.f;
      }
      #pragma unroll
      for (int j = 0; j < 16; ++j)
        buf[j][k] = (j < jmax) ? f2bf(tv[j]) : (ushort_t)0;
    } else {
      #pragma unroll
      for (int j = 0; j < 16; ++j) buf[j][k] = 0;
    }
  };

  for (int l = 0; l < 5; ++l) {
    const float* W; const float* bias; int act;
    if (l < 3)       { W = sWh + (l * 8 + e) * 55696; bias = sbh + (l * 8 + e) * 236; act = 0; }
    else if (l == 3) { W = sWo + e * 55696;           bias = sbo + e * 236;           act = 1; }
    else             { W = dW1 + e * 55696;           bias = db1;                     act = 2; }

    __syncthreads();
    bf16x8 afr[4][8];
    #pragma unroll
    for (int mt = 0; mt < 4; ++mt)
      #pragma unroll
      for (int kt = 0; kt < 8; ++kt)
        afr[mt][kt] = *(const bf16x8*)(&hA[mt * 16 + l15][kt * 32 + quad * 8]);
    stage(W, 0, wb[0]);
    __syncthreads();

    for (int t = 0; t < 15; ++t) {
      if (t < 14) stage(W, t + 1, wb[(t + 1) & 1]);
      if ((t & 3) == w) {
        f32x4 acc[4];
        #pragma unroll
        for (int mt = 0; mt < 4; ++mt) acc[mt] = (f32x4){0.f, 0.f, 0.f, 0.f};
        #pragma unroll
        for (int kt = 0; kt < 8; ++kt) {
          bf16x8 b = *(const bf16x8*)(&wb[t & 1][l15][kt * 32 + quad * 8]);
          #pragma unroll
          for (int mt = 0; mt < 4; ++mt)
            acc[mt] = __builtin_amdgcn_mfma_f32_16x16x32_bf16(afr[mt][kt], b, acc[mt], 0, 0, 0);
        }
        int n = t * 16 + l15;
        if (n < 236) {
          float bv = rbf(bias[n]);
          #pragma unroll
          for (int mt = 0; mt < 4; ++mt) {
            #pragma unroll
            for (int r = 0; r < 4; ++r) {
              int m = mt * 16 + quad * 4 + r;
              float v = rbf(acc[mt][r]);
              v = rbf(v + bv);
              if (act == 0) { v = rbf(30.f * v); v = sinf(v); }
              else if (act == 2) v = fmaxf(v, 0.f);
              hA[m][n] = f2bf(v);
            }
          }
        }
      }
      __syncthreads();
    }
  }

  for (int j = tid; j < 711; j += 256)
    wc[j] = (j < 708) ? rbf(dW2[j]) : rbf(db2[j - 708]);
  __syncthreads();
  if (tid < 192) {
    int p = tid / 3, o = tid - p * 3;
    if (p < np) {
      float s = 0.f;
      for (int k = 0; k < 236; ++k)
        s = fmaf(bf2f(hA[p][k]), wc[k * 3 + o], s);
      s = rbf(s);
      s = rbf(s + wc[708 + o]);
      out[idxl[p] * 3 + o] = nan_bits(s) ? 16.0f : fminf(fmaxf(s, -4.f), 4.f);
    }
  }
}

extern "C" void kernel_launch(void* const* d_in, const int* in_sizes, int n_in,
                              void* d_out, int out_size, void* d_ws, size_t ws_size,
                              hipStream_t stream) {
  const float* x   = (const float*)d_in[0];
  const float* sW1 = (const float*)d_in[1];
  const float* sb1 = (const float*)d_in[2];
  const float* sWh = (const float*)d_in[3];
  const float* sbh = (const float*)d_in[4];
  const float* sWo = (const float*)d_in[5];
  const float* sbo = (const float*)d_in[6];
  const float* mW1 = (const float*)d_in[7];
  const float* mb1 = (const float*)d_in[8];
  const float* mW2 = (const float*)d_in[9];
  const float* mb2 = (const float*)d_in[10];
  const float* mW3 = (const float*)d_in[11];
  const float* mb3 = (const float*)d_in[12];
  const float* dW1 = (const float*)d_in[13];
  const float* db1 = (const float*)d_in[14];
  const float* dW2 = (const float*)d_in[15];
  const float* db2 = (const float*)d_in[16];

  float* outp = (float*)d_out;
  char* ws = (char*)d_ws;
  int* counts      = (int*)(ws + WS_CNT);
  ushort_t* bucket = (ushort_t*)(ws + WS_BKT);

  if (ws_size >= (size_t)WS_FAST) {
    ushort_t* W2S = (ushort_t*)(ws + OFF_W2S);
    ushort_t* w3T = (ushort_t*)(ws + OFF_W3T);
    ushort_t* swt = (ushort_t*)(ws + OFF_SWT);
    k_prep_fast<<<dim3(2048), dim3(256), 0, stream>>>(sWh, sWo, dW1, mW2, mW3,
                                                      counts, W2S, w3T, swt, outp);
    k_gate_fast<<<dim3(1024), dim3(256), 0, stream>>>(x, mW1, mb1, mb2, mb3,
                                                      W2S, w3T, counts, bucket);
    k_sdec_fast<<<dim3(1024, 8), dim3(256), 0, stream>>>(x, sW1, sb1, sbh, sbo,
                                                         db1, dW2, db2, swt,
                                                         counts, bucket, outp);
  } else if (ws_size >= (size_t)WS_SLOW) {
    k_prep_slow<<<dim3(1), dim3(64), 0, stream>>>(counts, outp);
    k_gate_slow<<<dim3(1024), dim3(256), 62976, stream>>>(x, mW1, mb1, mW2, mb2, mW3, mb3,
                                                          counts, bucket);
    k_sdec_slow<<<dim3(1024, 8), dim3(256), 0, stream>>>(x, sW1, sb1, sWh, sbh, sWo, sbo,
                                                         dW1, db1, dW2, db2, counts, bucket, outp);
  } else {
    k_sentinel<<<dim3(1), dim3(64), 0, stream>>>(outp);
  }
}

// Round 8
// 390.868 us; speedup vs baseline: 3.4509x; 1.5119x over previous
//
#include <hip/hip_runtime.h>
#include <cstdint>

typedef unsigned short ushort_t;
typedef short bf16x8 __attribute__((ext_vector_type(8)));
typedef unsigned short u16x8 __attribute__((ext_vector_type(8)));
typedef float f32x4 __attribute__((ext_vector_type(4)));

#define NPTS 65536
// ws layout (fast): counts@0 | bucket@64 (1,048,576) | W2S@1,048,640 (401,408)
//                 | w3T@1,450,048 (14,592) | swt@1,464,640 (5,068,800) => 6,533,440
#define WS_CNT 0
#define WS_BKT 64
#define OFF_W2S 1048640
#define OFF_W3T 1450048
#define OFF_SWT 1464640
#define WS_FAST 6533440u
#define WS_SLOW (64 + 8 * NPTS * 2)

__device__ __forceinline__ float bf2f(ushort_t u) {
  union { unsigned u; float f; } c; c.u = ((unsigned)u) << 16; return c.f;
}
__device__ __forceinline__ ushort_t f2bf(float f) {
  union { float f; unsigned u; } c; c.f = f;
  unsigned u = c.u + 0x7fffu + ((c.u >> 16) & 1u);
  return (ushort_t)(u >> 16);
}
__device__ __forceinline__ float rbf(float v) { return bf2f(f2bf(v)); }
__device__ __forceinline__ bool nan_bits(float v) {
  union { float f; unsigned u; } c; c.f = v;
  return ((c.u >> 23) & 0xFFu) == 0xFFu && (c.u & 0x7FFFFFu) != 0u;
}

__global__ void k_sentinel(float* out) {
  if (threadIdx.x == 0) out[0] = 1.0e30f;  // ws_size-too-small marker
}

// ==================== FAST PATH ====================

// prep: all weight transpose/bf16-convert hoisted here (runs once per launch).
__global__ __launch_bounds__(256) void k_prep_fast(
    const float* __restrict__ sWh, const float* __restrict__ sWo,
    const float* __restrict__ dW1, const float* __restrict__ mW2,
    const float* __restrict__ mW3,
    int* __restrict__ counts, ushort_t* __restrict__ W2S,
    ushort_t* __restrict__ w3T, ushort_t* __restrict__ swt, float* __restrict__ out)
{
  long gid = (long)blockIdx.x * 256 + threadIdx.x;
  long gs = (long)gridDim.x * 256;
  // swt: 40 mats x [240 n][264 k]; swt[mat][n][k] = bf16(W[k*236+n]); zero-padded
  for (long i = gid; i < 40L * 63360; i += gs) {
    int mat = (int)(i / 63360);
    int r = (int)(i - (long)mat * 63360);
    int n = r / 264, k = r - n * 264;
    ushort_t v = 0;
    if (n < 236 && k < 236) {
      const float* W = (mat < 24) ? (sWh + (long)mat * 55696)
                     : (mat < 32) ? (sWo + (long)(mat - 24) * 55696)
                                  : (dW1 + (long)(mat - 32) * 55696);
      v = f2bf(W[k * 236 + n]);
    }
    swt[i] = v;
  }
  // W2S: pre-swizzled B-fragments [kt 14][nt 28][lane 64][u 8]
  for (long i = gid; i < 25088; i += gs) {
    int kt = (int)(i / (28 * 64));
    int rem = (int)(i - (long)kt * 28 * 64);
    int nt = rem / 64, lane = rem - nt * 64;
    int l15 = lane & 15, quad = lane >> 4;
    int n = nt * 16 + l15;
    u16x8 tv;
    #pragma unroll
    for (int u = 0; u < 8; ++u) {
      int k = kt * 32 + quad * 8 + u;
      tv[u] = (k < 441 && n < 441) ? f2bf(mW2[(long)k * 441 + n]) : (ushort_t)0;
    }
    *(u16x8*)(W2S + i * 8) = tv;
  }
  // w3T: [16 e][456 c] (zero-padded) for L3 B-fragments
  for (long i = gid; i < 7296; i += gs) {
    int e = (int)(i / 456), c = (int)(i - (long)e * 456);
    w3T[i] = (e < 8 && c < 441) ? f2bf(mW3[(long)c * 8 + e]) : (ushort_t)0;
  }
  if (gid < 8) counts[gid] = 0;
  if (gid == 8) out[NPTS * 3] = 18.125f;  // KL(uniform||one-hot): data-independent
}

// gate: L1 recompute + L2 bf16-MFMA (B direct from W2S, coalesced) + L3 via chunked MFMA
__global__ __launch_bounds__(256) void k_gate_fast(
    const float* __restrict__ x,
    const float* __restrict__ mW1, const float* __restrict__ mb1,
    const float* __restrict__ mb2, const float* __restrict__ mb3,
    const ushort_t* __restrict__ W2S, const ushort_t* __restrict__ w3Tg,
    int* __restrict__ counts, ushort_t* __restrict__ bucket)
{
  __shared__ ushort_t At[64][40];       // 5120
  __shared__ float W1c[1792];           // 7168
  __shared__ float xl[192];             // 768
  __shared__ ushort_t chunkC[64][72];   // 9216 (pad 72: 2-way banks on b128 reads)
  __shared__ ushort_t w3T[16][456];     // 14592 (stride 912B -> 2-way banks)
  __shared__ float b2c[448];            // 1792
  __shared__ unsigned char bexp[64];

  int tid = threadIdx.x;
  int blk = blockIdx.x;
  if (tid < 192) {
    int p = tid / 3, c = tid - p * 3;
    xl[tid] = rbf(x[(blk * 64 + p) * 3 + c]);
  }
  for (int j = tid; j < 1792; j += 256) {
    int c = j / 448, m = j - c * 448;
    float v = 0.f;
    if (m < 441) v = (c < 3) ? rbf(mW1[c * 441 + m]) : rbf(mb1[m]);
    W1c[j] = v;
  }
  for (int j = tid; j < 448; j += 256) b2c[j] = (j < 441) ? rbf(mb2[j]) : 0.f;
  for (int ch = tid; ch < 912; ch += 256)
    *(u16x8*)(&w3T[0][0] + ch * 8) = *(const u16x8*)(w3Tg + ch * 8);

  int w = tid >> 6, lane = tid & 63;
  int l15 = lane & 15, quad = lane >> 4;

  f32x4 acc[4][7];
  #pragma unroll
  for (int a = 0; a < 4; ++a)
    #pragma unroll
    for (int b = 0; b < 7; ++b)
      acc[a][b] = (f32x4){0.f, 0.f, 0.f, 0.f};

  int am = tid >> 2, ak = (tid & 3) * 8;

  for (int kt = 0; kt < 14; ++kt) {
    int kk0 = kt * 32;
    __syncthreads();  // prior At reads done (covers preload fills on kt==0)
    // stage A: g1 = relu(bf16(bf16(x@W1) + b1)) for this k-slice
    {
      float x0 = xl[am * 3], x1 = xl[am * 3 + 1], x2 = xl[am * 3 + 2];
      u16x8 tmp;
      #pragma unroll
      for (int u = 0; u < 8; ++u) {
        int j = kk0 + ak + u;
        ushort_t h = 0;
        if (j < 441) {
          float t = x0 * W1c[j];
          t = fmaf(x1, W1c[448 + j], t);
          t = fmaf(x2, W1c[896 + j], t);
          t = rbf(t);                    // matmul -> bf16
          t = rbf(t + W1c[1344 + j]);    // +b1 -> bf16
          t = fmaxf(t, 0.f);
          h = f2bf(t);
        }
        tmp[u] = h;
      }
      *(u16x8*)(At[am] + ak) = tmp;
    }
    __syncthreads();
    bf16x8 bfr[7];
    #pragma unroll
    for (int j = 0; j < 7; ++j)  // coalesced: lanes consecutive 16B chunks
      bfr[j] = *(const bf16x8*)(W2S + ((kt * 28 + (w + 4 * j)) * 64 + lane) * 8);
    #pragma unroll
    for (int mt = 0; mt < 4; ++mt) {
      bf16x8 a = *(const bf16x8*)(&At[mt * 16 + l15][quad * 8]);
      #pragma unroll
      for (int j = 0; j < 7; ++j)
        acc[mt][j] = __builtin_amdgcn_mfma_f32_16x16x32_bf16(a, bfr[j], acc[mt][j], 0, 0, 0);
    }
  }

  // L3 via MFMA over 7 column-chunks of g2 (64 c each); g2 chunk from live acc regs.
  // NOTE: j-loop MUST be unrolled — runtime-indexed acc[mt][j] demotes acc to scratch
  // (round-7: 1.7 GB/dispatch spill writes, WRITE_SIZE counter).
  f32x4 acc3[4];
  #pragma unroll
  for (int mt = 0; mt < 4; ++mt) acc3[mt] = (f32x4){0.f, 0.f, 0.f, 0.f};
  #pragma unroll
  for (int j = 0; j < 7; ++j) {
    __syncthreads();  // previous chunk reads (or kt-loop At reads) done
    #pragma unroll
    for (int mt = 0; mt < 4; ++mt) {
      #pragma unroll
      for (int r = 0; r < 4; ++r) {
        int cg = j * 64 + w * 16 + l15;        // global col
        int m = mt * 16 + quad * 4 + r;
        float v = rbf(acc[mt][j][r]);          // einsum -> bf16
        v = rbf(v + b2c[cg]);                  // +b2 -> bf16
        v = fmaxf(v, 0.f);                     // relu
        chunkC[m][w * 16 + l15] = f2bf(v);
      }
    }
    __syncthreads();
    bf16x8 b0 = *(const bf16x8*)(&w3T[l15][j * 64 + quad * 8]);
    bf16x8 b1 = *(const bf16x8*)(&w3T[l15][j * 64 + 32 + quad * 8]);
    #pragma unroll
    for (int mt = 0; mt < 4; ++mt) {
      bf16x8 a0 = *(const bf16x8*)(&chunkC[mt * 16 + l15][quad * 8]);
      bf16x8 a1 = *(const bf16x8*)(&chunkC[mt * 16 + l15][32 + quad * 8]);
      acc3[mt] = __builtin_amdgcn_mfma_f32_16x16x32_bf16(a0, b0, acc3[mt], 0, 0, 0);
      acc3[mt] = __builtin_amdgcn_mfma_f32_16x16x32_bf16(a1, b1, acc3[mt], 0, 0, 0);
    }
  }
  // logits in C-layout: e = l15, m = mt*16+quad*4+r. Argmax via 8-lane butterfly.
  float b3v = (l15 < 8) ? rbf(mb3[l15]) : 0.f;
  if (w == 0) {
    #pragma unroll
    for (int mt = 0; mt < 4; ++mt) {
      #pragma unroll
      for (int r = 0; r < 4; ++r) {
        float lv = rbf(acc3[mt][r]);
        lv = rbf(lv + b3v);
        float v = (l15 < 8) ? lv : -1.0e30f;
        int ii = l15;
        #pragma unroll
        for (int mk = 1; mk < 8; mk <<= 1) {
          float ov = __shfl_xor(v, mk);
          int oi = __shfl_xor(ii, mk);
          if (ov > v || (ov == v && oi < ii)) { v = ov; ii = oi; }  // first-max = np.argmax
        }
        if (l15 == 0) bexp[mt * 16 + quad * 4 + r] = (unsigned char)ii;
      }
    }
  }
  __syncthreads();
  if (tid < 64) {  // wave 0: wave-aggregated bucket scatter (<=8 atomics/block)
    int bi = (int)bexp[tid];
    int slot = 0;
    #pragma unroll
    for (int ee = 0; ee < 8; ++ee) {
      unsigned long long msk = __ballot(bi == ee);
      if (bi == ee) {
        int leader = (int)__builtin_ctzll(msk);
        int rank = __popcll(msk & ((1ull << tid) - 1ull));
        int basep = 0;
        if (tid == leader) basep = atomicAdd(&counts[ee], __popcll(msk));
        basep = __shfl(basep, leader);
        slot = basep + rank;
      }
    }
    bucket[bi * NPTS + slot] = (ushort_t)(blk * 64 + tid);
  }
}

// sdec: bucketed, wave-per-mt MFMA, weights pre-staged bf16 in swt (copy-only staging)
__global__ __launch_bounds__(256) void k_sdec_fast(
    const float* __restrict__ x,
    const float* __restrict__ sW1, const float* __restrict__ sb1,
    const float* __restrict__ sbh, const float* __restrict__ sbo,
    const float* __restrict__ db1, const float* __restrict__ dW2,
    const float* __restrict__ db2,
    const ushort_t* __restrict__ swt,
    const int* __restrict__ counts, const ushort_t* __restrict__ bucket,
    float* __restrict__ out)
{
  __shared__ ushort_t hA[64][264];        // 33792
  __shared__ ushort_t wbuf[2][16][264];   // 16896 (wc overlays: only used outside layer loop)
  __shared__ int idxl[64];
  __shared__ float xl[64][3];
  float* wc = (float*)&wbuf[0][0][0];     // 944 f32 = 3776 B

  int e = blockIdx.y;
  int base = blockIdx.x * 64;
  int cnt = counts[e];
  if (base >= cnt) return;
  int np = min(64, cnt - base);
  int tid = threadIdx.x;

  if (tid < 64) {
    int s = base + (tid < np ? tid : 0);   // pad rows duplicate a real point
    idxl[tid] = (int)bucket[e * NPTS + s];
  }
  __syncthreads();
  if (tid < 192) {
    int p = tid / 3, c = tid - p * 3;
    xl[p][c] = rbf(x[idxl[p] * 3 + c]);
  }
  for (int j = tid; j < 944; j += 256)
    wc[j] = (j < 708) ? rbf(sW1[e * 708 + j]) : rbf(sb1[e * 236 + (j - 708)]);
  for (int t = tid; t < 64 * 28; t += 256) {   // zero K-pad cols [236,264) once
    int p = t / 28, cc = 236 + (t - p * 28);
    hA[p][cc] = 0;
  }
  __syncthreads();
  // L1: h = bf16(sin(bf16(30*bf16(bf16(x@W1)+b1))))
  for (int t = tid; t < 64 * 236; t += 256) {
    int p = t / 236, f = t - p * 236;
    float v = xl[p][0] * wc[f];
    v = fmaf(xl[p][1], wc[236 + f], v);
    v = fmaf(xl[p][2], wc[472 + f], v);
    v = rbf(v);
    v = rbf(v + wc[708 + f]);
    v = rbf(30.f * v);
    hA[p][f] = f2bf(sinf(v));
  }

  int w = tid >> 6, lane = tid & 63;
  int l15 = lane & 15, quad = lane >> 4;

  for (int l = 0; l < 5; ++l) {
    const ushort_t* Wt; const float* bias; int act;
    if (l < 3)       { Wt = swt + (l * 8 + e) * 63360; bias = sbh + (l * 8 + e) * 236; act = 0; }
    else if (l == 3) { Wt = swt + (24 + e) * 63360;    bias = sbo + e * 236;           act = 1; }
    else             { Wt = swt + (32 + e) * 63360;    bias = db1;                     act = 2; }

    __syncthreads();  // hA complete; wbuf free (covers L1/wc phase on l==0)
    bf16x8 afr[8];    // wave w caches only its own 16 rows -> in-place hA update safe
    #pragma unroll
    for (int kt = 0; kt < 8; ++kt)
      afr[kt] = *(const bf16x8*)(&hA[w * 16 + l15][kt * 32 + quad * 8]);
    {  // stage tile 0 (pure 16B copies; tile = contiguous 8448 B, zero-padded in prep)
      const ushort_t* src = Wt;
      ushort_t* dst = &wbuf[0][0][0];
      *(u16x8*)(dst + tid * 8)         = *(const u16x8*)(src + tid * 8);
      *(u16x8*)(dst + (tid + 256) * 8) = *(const u16x8*)(src + (tid + 256) * 8);
      if (tid < 16)
        *(u16x8*)(dst + (tid + 512) * 8) = *(const u16x8*)(src + (tid + 512) * 8);
    }
    __syncthreads();

    for (int t = 0; t < 15; ++t) {
      if (t < 14) {  // prefetch next tile into other buffer
        const ushort_t* src = Wt + (t + 1) * 4224;
        ushort_t* dst = &wbuf[(t + 1) & 1][0][0];
        *(u16x8*)(dst + tid * 8)         = *(const u16x8*)(src + tid * 8);
        *(u16x8*)(dst + (tid + 256) * 8) = *(const u16x8*)(src + (tid + 256) * 8);
        if (tid < 16)
          *(u16x8*)(dst + (tid + 512) * 8) = *(const u16x8*)(src + (tid + 512) * 8);
      }
      f32x4 acc = (f32x4){0.f, 0.f, 0.f, 0.f};
      #pragma unroll
      for (int kt = 0; kt < 8; ++kt) {
        bf16x8 b = *(const bf16x8*)(&wbuf[t & 1][l15][kt * 32 + quad * 8]);
        acc = __builtin_amdgcn_mfma_f32_16x16x32_bf16(afr[kt], b, acc, 0, 0, 0);
      }
      int n = t * 16 + l15;
      if (n < 236) {
        float bv = rbf(bias[n]);
        #pragma unroll
        for (int r = 0; r < 4; ++r) {
          int m = w * 16 + quad * 4 + r;
          float v = rbf(acc[r]);      // einsum -> bf16
          v = rbf(v + bv);            // +bias -> bf16
          if (act == 0) { v = rbf(30.f * v); v = sinf(v); }
          else if (act == 2) v = fmaxf(v, 0.f);
          hA[m][n] = f2bf(v);         // wave w writes only its own rows
        }
      }
      __syncthreads();
    }
  }

  // dec2: out = bf16(bf16(h@dW2) + db2), float32 store
  for (int j = tid; j < 711; j += 256)
    wc[j] = (j < 708) ? rbf(dW2[j]) : rbf(db2[j - 708]);
  __syncthreads();
  if (tid < 192) {
    int p = tid / 3, o = tid - p * 3;
    if (p < np) {
      float s = 0.f;
      for (int k = 0; k < 236; ++k)
        s = fmaf(bf2f(hA[p][k]), wc[k * 3 + o], s);
      s = rbf(s);
      s = rbf(s + wc[708 + o]);
      out[idxl[p] * 3 + o] = nan_bits(s) ? 16.0f : fminf(fmaxf(s, -4.f), 4.f);
    }
  }
}

// ==================== SLOW PATH (round-6, proven; used when ws too small) ====================

__global__ void k_prep_slow(int* counts, float* out) {
  int t = threadIdx.x;
  if (t < 8) counts[t] = 0;
  if (t == 8) out[NPTS * 3] = 18.125f;
}

__global__ __launch_bounds__(256) void k_gate_slow(
    const float* __restrict__ x,
    const float* __restrict__ mW1, const float* __restrict__ mb1,
    const float* __restrict__ mW2, const float* __restrict__ mb2,
    const float* __restrict__ mW3, const float* __restrict__ mb3,
    int* __restrict__ counts, ushort_t* __restrict__ bucket)
{
  extern __shared__ char smem[];
  ushort_t* At  = (ushort_t*)smem;
  ushort_t* Bt  = (ushort_t*)(smem + 5120);
  float*    W1c = (float*)(smem + 40960);
  ushort_t* g2  = (ushort_t*)smem;
  float*    b2c = (float*)(smem + 58368);
  float*    xl  = (float*)(smem + 60160);
  float*    lg  = (float*)(smem + 60928);

  int tid = threadIdx.x;
  int blk = blockIdx.x;
  if (tid < 192) {
    int p = tid / 3, c = tid - p * 3;
    xl[tid] = rbf(x[(blk * 64 + p) * 3 + c]);
  }
  for (int j = tid; j < 1792; j += 256) {
    int c = j / 448, m = j - c * 448;
    float v = 0.f;
    if (m < 441) v = (c < 3) ? rbf(mW1[c * 441 + m]) : rbf(mb1[m]);
    W1c[j] = v;
  }
  for (int j = tid; j < 448; j += 256) b2c[j] = (j < 441) ? rbf(mb2[j]) : 0.f;

  int w = tid >> 6, lane = tid & 63;
  int l15 = lane & 15, quad = lane >> 4;

  f32x4 acc[4][7];
  #pragma unroll
  for (int a = 0; a < 4; ++a)
    #pragma unroll
    for (int b = 0; b < 7; ++b)
      acc[a][b] = (f32x4){0.f, 0.f, 0.f, 0.f};

  int am = tid >> 2, ak = (tid & 3) * 8;

  for (int kt = 0; kt < 14; ++kt) {
    int kk0 = kt * 32;
    __syncthreads();
    {
      float x0 = xl[am * 3], x1 = xl[am * 3 + 1], x2 = xl[am * 3 + 2];
      u16x8 tmp;
      #pragma unroll
      for (int u = 0; u < 8; ++u) {
        int j = kk0 + ak + u;
        ushort_t h = 0;
        if (j < 441) {
          float t = x0 * W1c[j];
          t = fmaf(x1, W1c[448 + j], t);
          t = fmaf(x2, W1c[896 + j], t);
          t = rbf(t);
          t = rbf(t + W1c[1344 + j]);
          t = fmaxf(t, 0.f);
          h = f2bf(t);
        }
        tmp[u] = h;
      }
      *(u16x8*)(At + am * 40 + ak) = tmp;
    }
    {
      int n1 = tid;
      #pragma unroll
      for (int q = 0; q < 4; ++q) {
        u16x8 tv;
        #pragma unroll
        for (int u = 0; u < 8; ++u) {
          int kk = kk0 + q * 8 + u;
          tv[u] = (kk < 441 && n1 < 441) ? f2bf(mW2[kk * 441 + n1]) : (ushort_t)0;
        }
        *(u16x8*)(Bt + n1 * 40 + q * 8) = tv;
      }
      int n2 = tid + 256;
      if (n2 < 448) {
        #pragma unroll
        for (int q = 0; q < 4; ++q) {
          u16x8 tv;
          #pragma unroll
          for (int u = 0; u < 8; ++u) {
            int kk = kk0 + q * 8 + u;
            tv[u] = (kk < 441 && n2 < 441) ? f2bf(mW2[kk * 441 + n2]) : (ushort_t)0;
          }
          *(u16x8*)(Bt + n2 * 40 + q * 8) = tv;
        }
      }
    }
    __syncthreads();
    bf16x8 bfr[7];
    #pragma unroll
    for (int j = 0; j < 7; ++j) {
      int nt = w + 4 * j;
      bfr[j] = *(const bf16x8*)(Bt + (nt * 16 + l15) * 40 + quad * 8);
    }
    #pragma unroll
    for (int mt = 0; mt < 4; ++mt) {
      bf16x8 a = *(const bf16x8*)(At + (mt * 16 + l15) * 40 + quad * 8);
      #pragma unroll
      for (int j = 0; j < 7; ++j)
        acc[mt][j] = __builtin_amdgcn_mfma_f32_16x16x32_bf16(a, bfr[j], acc[mt][j], 0, 0, 0);
    }
  }
  __syncthreads();
  #pragma unroll
  for (int mt = 0; mt < 4; ++mt) {
    #pragma unroll
    for (int j = 0; j < 7; ++j) {
      int c = (w + 4 * j) * 16 + l15;
      float bv = b2c[c];
      #pragma unroll
      for (int r = 0; r < 4; ++r) {
        int m = mt * 16 + quad * 4 + r;
        float v = rbf(acc[mt][j][r]);
        v = rbf(v + bv);
        v = fmaxf(v, 0.f);
        g2[m * 456 + c] = f2bf(v);
      }
    }
  }
  __syncthreads();
  {
    int m3 = tid >> 2, eg = tid & 3;
    float s0 = 0.f, s1 = 0.f;
    const ushort_t* row = g2 + m3 * 456;
    for (int j = 0; j < 441; ++j) {
      float gv = bf2f(row[j]);
      s0 = fmaf(gv, rbf(mW3[j * 8 + 2 * eg]), s0);
      s1 = fmaf(gv, rbf(mW3[j * 8 + 2 * eg + 1]), s1);
    }
    s0 = rbf(rbf(s0) + rbf(mb3[2 * eg]));
    s1 = rbf(rbf(s1) + rbf(mb3[2 * eg + 1]));
    lg[m3 * 8 + 2 * eg] = s0;
    lg[m3 * 8 + 2 * eg + 1] = s1;
  }
  __syncthreads();
  if (tid < 64) {
    float best = lg[tid * 8];
    int bi = 0;
    #pragma unroll
    for (int e = 1; e < 8; ++e) {
      float v = lg[tid * 8 + e];
      if (v > best) { best = v; bi = e; }
    }
    int slot = 0;
    #pragma unroll
    for (int e = 0; e < 8; ++e) {
      unsigned long long msk = __ballot(bi == e);
      if (bi == e) {
        int leader = (int)__builtin_ctzll(msk);
        int rank = __popcll(msk & ((1ull << tid) - 1ull));
        int basep = 0;
        if (tid == leader) basep = atomicAdd(&counts[e], __popcll(msk));
        basep = __shfl(basep, leader);
        slot = basep + rank;
      }
    }
    bucket[bi * NPTS + slot] = (ushort_t)(blk * 64 + tid);
  }
}

__global__ __launch_bounds__(256) void k_sdec_slow(
    const float* __restrict__ x,
    const float* __restrict__ sW1, const float* __restrict__ sb1,
    const float* __restrict__ sWh, const float* __restrict__ sbh,
    const float* __restrict__ sWo, const float* __restrict__ sbo,
    const float* __restrict__ dW1, const float* __restrict__ db1,
    const float* __restrict__ dW2, const float* __restrict__ db2,
    const int* __restrict__ counts, const ushort_t* __restrict__ bucket,
    float* __restrict__ out)
{
  __shared__ ushort_t hA[64][264];
  __shared__ ushort_t wb[2][16][264];
  __shared__ int idxl[64];
  __shared__ float xl[64][3];
  __shared__ float wc[944];

  int e = blockIdx.y;
  int base = blockIdx.x * 64;
  int cnt = counts[e];
  if (base >= cnt) return;
  int np = min(64, cnt - base);
  int tid = threadIdx.x;

  if (tid < 64) {
    int s = base + (tid < np ? tid : 0);
    idxl[tid] = (int)bucket[e * NPTS + s];
  }
  __syncthreads();
  if (tid < 192) {
    int p = tid / 3, c = tid - p * 3;
    xl[p][c] = rbf(x[idxl[p] * 3 + c]);
  }
  for (int j = tid; j < 944; j += 256)
    wc[j] = (j < 708) ? rbf(sW1[e * 708 + j]) : rbf(sb1[e * 236 + (j - 708)]);
  for (int t = tid; t < 64 * 28; t += 256) {
    int p = t / 28, cc = 236 + (t - p * 28);
    hA[p][cc] = 0;
  }
  __syncthreads();
  for (int t = tid; t < 64 * 236; t += 256) {
    int p = t / 236, f = t - p * 236;
    float v = xl[p][0] * wc[f];
    v = fmaf(xl[p][1], wc[236 + f], v);
    v = fmaf(xl[p][2], wc[472 + f], v);
    v = rbf(v);
    v = rbf(v + wc[708 + f]);
    v = rbf(30.f * v);
    hA[p][f] = f2bf(sinf(v));
  }

  int w = tid >> 6, lane = tid & 63;
  int l15 = lane & 15, quad = lane >> 4;

  auto stage = [&](const float* W, int t, ushort_t (*buf)[264]) {
    int k = tid;
    if (k < 236) {
      const float* srcW = W + k * 236 + t * 16;
      int jmax = 236 - t * 16; if (jmax > 16) jmax = 16;
      float tv[16];
      if (jmax == 16) {
        *(f32x4*)(tv)      = *(const f32x4*)(srcW);
        *(f32x4*)(tv + 4)  = *(const f32x4*)(srcW + 4);
        *(f32x4*)(tv + 8)  = *(const f32x4*)(srcW + 8);
        *(f32x4*)(tv + 12) = *(const f32x4*)(srcW + 12);
      } else {
        *(f32x4*)(tv)      = *(const f32x4*)(srcW);
        *(f32x4*)(tv + 4)  = *(const f32x4*)(srcW + 4);
        *(f32x4*)(tv + 8)  = *(const f32x4*)(srcW + 8);
        tv[12] = tv[13] = tv[14] = tv[15] = 0.f;
      }
      #pragma unroll
      for (int j = 0; j < 16; ++j)
        buf[j][k] = (j < jmax) ? f2bf(tv[j]) : (ushort_t)0;
    } else {
      #pragma unroll
      for (int j = 0; j < 16; ++j) buf[j][k] = 0;
    }
  };

  for (int l = 0; l < 5; ++l) {
    const float* W; const float* bias; int act;
    if (l < 3)       { W = sWh + (l * 8 + e) * 55696; bias = sbh + (l * 8 + e) * 236; act = 0; }
    else if (l == 3) { W = sWo + e * 55696;           bias = sbo + e * 236;           act = 1; }
    else             { W = dW1 + e * 55696;           bias = db1;                     act = 2; }

    __syncthreads();
    bf16x8 afr[4][8];
    #pragma unroll
    for (int mt = 0; mt < 4; ++mt)
      #pragma unroll
      for (int kt = 0; kt < 8; ++kt)
        afr[mt][kt] = *(const bf16x8*)(&hA[mt * 16 + l15][kt * 32 + quad * 8]);
    stage(W, 0, wb[0]);
    __syncthreads();

    for (int t = 0; t < 15; ++t) {
      if (t < 14) stage(W, t + 1, wb[(t + 1) & 1]);
      if ((t & 3) == w) {
        f32x4 acc[4];
        #pragma unroll
        for (int mt = 0; mt < 4; ++mt) acc[mt] = (f32x4){0.f, 0.f, 0.f, 0.f};
        #pragma unroll
        for (int kt = 0; kt < 8; ++kt) {
          bf16x8 b = *(const bf16x8*)(&wb[t & 1][l15][kt * 32 + quad * 8]);
          #pragma unroll
          for (int mt = 0; mt < 4; ++mt)
            acc[mt] = __builtin_amdgcn_mfma_f32_16x16x32_bf16(afr[mt][kt], b, acc[mt], 0, 0, 0);
        }
        int n = t * 16 + l15;
        if (n < 236) {
          float bv = rbf(bias[n]);
          #pragma unroll
          for (int mt = 0; mt < 4; ++mt) {
            #pragma unroll
            for (int r = 0; r < 4; ++r) {
              int m = mt * 16 + quad * 4 + r;
              float v = rbf(acc[mt][r]);
              v = rbf(v + bv);
              if (act == 0) { v = rbf(30.f * v); v = sinf(v); }
              else if (act == 2) v = fmaxf(v, 0.f);
              hA[m][n] = f2bf(v);
            }
          }
        }
      }
      __syncthreads();
    }
  }

  for (int j = tid; j < 711; j += 256)
    wc[j] = (j < 708) ? rbf(dW2[j]) : rbf(db2[j - 708]);
  __syncthreads();
  if (tid < 192) {
    int p = tid / 3, o = tid - p * 3;
    if (p < np) {
      float s = 0.f;
      for (int k = 0; k < 236; ++k)
        s = fmaf(bf2f(hA[p][k]), wc[k * 3 + o], s);
      s = rbf(s);
      s = rbf(s + wc[708 + o]);
      out[idxl[p] * 3 + o] = nan_bits(s) ? 16.0f : fminf(fmaxf(s, -4.f), 4.f);
    }
  }
}

extern "C" void kernel_launch(void* const* d_in, const int* in_sizes, int n_in,
                              void* d_out, int out_size, void* d_ws, size_t ws_size,
                              hipStream_t stream) {
  const float* x   = (const float*)d_in[0];
  const float* sW1 = (const float*)d_in[1];
  const float* sb1 = (const float*)d_in[2];
  const float* sWh = (const float*)d_in[3];
  const float* sbh = (const float*)d_in[4];
  const float* sWo = (const float*)d_in[5];
  const float* sbo = (const float*)d_in[6];
  const float* mW1 = (const float*)d_in[7];
  const float* mb1 = (const float*)d_in[8];
  const float* mW2 = (const float*)d_in[9];
  const float* mb2 = (const float*)d_in[10];
  const float* mW3 = (const float*)d_in[11];
  const float* mb3 = (const float*)d_in[12];
  const float* dW1 = (const float*)d_in[13];
  const float* db1 = (const float*)d_in[14];
  const float* dW2 = (const float*)d_in[15];
  const float* db2 = (const float*)d_in[16];

  float* outp = (float*)d_out;
  char* ws = (char*)d_ws;
  int* counts      = (int*)(ws + WS_CNT);
  ushort_t* bucket = (ushort_t*)(ws + WS_BKT);

  if (ws_size >= (size_t)WS_FAST) {
    ushort_t* W2S = (ushort_t*)(ws + OFF_W2S);
    ushort_t* w3T = (ushort_t*)(ws + OFF_W3T);
    ushort_t* swt = (ushort_t*)(ws + OFF_SWT);
    k_prep_fast<<<dim3(2048), dim3(256), 0, stream>>>(sWh, sWo, dW1, mW2, mW3,
                                                      counts, W2S, w3T, swt, outp);
    k_gate_fast<<<dim3(1024), dim3(256), 0, stream>>>(x, mW1, mb1, mb2, mb3,
                                                      W2S, w3T, counts, bucket);
    k_sdec_fast<<<dim3(1024, 8), dim3(256), 0, stream>>>(x, sW1, sb1, sbh, sbo,
                                                         db1, dW2, db2, swt,
                                                         counts, bucket, outp);
  } else if (ws_size >= (size_t)WS_SLOW) {
    k_prep_slow<<<dim3(1), dim3(64), 0, stream>>>(counts, outp);
    k_gate_slow<<<dim3(1024), dim3(256), 62976, stream>>>(x, mW1, mb1, mW2, mb2, mW3, mb3,
                                                          counts, bucket);
    k_sdec_slow<<<dim3(1024, 8), dim3(256), 0, stream>>>(x, sW1, sb1, sWh, sbh, sWo, sbo,
                                                         dW1, db1, dW2, db2, counts, bucket, outp);
  } else {
    k_sentinel<<<dim3(1), dim3(64), 0, stream>>>(outp);
  }
}

// Round 9
// 295.352 us; speedup vs baseline: 4.5669x; 1.3234x over previous
//
#include <hip/hip_runtime.h>
#include <cstdint>

typedef unsigned short ushort_t;
typedef short bf16x8 __attribute__((ext_vector_type(8)));
typedef unsigned short u16x8 __attribute__((ext_vector_type(8)));
typedef float f32x4 __attribute__((ext_vector_type(4)));

#define NPTS 65536
// ws layout (fast): counts@0 | bucket@64 (1,048,576) | W2S@1,048,640 (401,408)
//                 | w3T@1,450,048 (14,592) | swt@1,464,640 (4,915,200) => 6,379,840
#define WS_CNT 0
#define WS_BKT 64
#define OFF_W2S 1048640
#define OFF_W3T 1450048
#define OFF_SWT 1464640
#define WS_FAST 6379840u
#define WS_SLOW (64 + 8 * NPTS * 2)

__device__ __forceinline__ float bf2f(ushort_t u) {
  union { unsigned u; float f; } c; c.u = ((unsigned)u) << 16; return c.f;
}
__device__ __forceinline__ ushort_t f2bf(float f) {
  union { float f; unsigned u; } c; c.f = f;
  unsigned u = c.u + 0x7fffu + ((c.u >> 16) & 1u);
  return (ushort_t)(u >> 16);
}
__device__ __forceinline__ float rbf(float v) { return bf2f(f2bf(v)); }
__device__ __forceinline__ bool nan_bits(float v) {
  union { float f; unsigned u; } c; c.f = v;
  return ((c.u >> 23) & 0xFFu) == 0xFFu && (c.u & 0x7FFFFFu) != 0u;
}

__global__ void k_sentinel(float* out) {
  if (threadIdx.x == 0) out[0] = 1.0e30f;  // ws_size-too-small marker
}

// ==================== FAST PATH ====================

// prep: all weight transpose/bf16-convert/fragment-swizzle hoisted here (once per launch).
__global__ __launch_bounds__(256) void k_prep_fast(
    const float* __restrict__ sWh, const float* __restrict__ sWo,
    const float* __restrict__ dW1, const float* __restrict__ mW2,
    const float* __restrict__ mW3,
    int* __restrict__ counts, ushort_t* __restrict__ W2S,
    ushort_t* __restrict__ w3T, ushort_t* __restrict__ swt, float* __restrict__ out)
{
  long gid = (long)blockIdx.x * 256 + threadIdx.x;
  long gs = (long)gridDim.x * 256;
  // swt fragment-major: [mat 40][t 15][kt 8][lane 64][u 8] bf16; B-frag for 16x16x32:
  // n = t*16 + (lane&15), k = kt*32 + (lane>>4)*8 + u; zero-padded beyond 236.
  for (long i = gid; i < 40L * 61440; i += gs) {
    int mat = (int)(i / 61440);
    int f = (int)(i - (long)mat * 61440);
    int u = f & 7, ln = (f >> 3) & 63, kt = (f >> 9) & 7, t = f >> 12;
    int n = t * 16 + (ln & 15);
    int k = kt * 32 + (ln >> 4) * 8 + u;
    ushort_t v = 0;
    if (n < 236 && k < 236) {
      const float* W = (mat < 24) ? (sWh + (long)mat * 55696)
                     : (mat < 32) ? (sWo + (long)(mat - 24) * 55696)
                                  : (dW1 + (long)(mat - 32) * 55696);
      v = f2bf(W[k * 236 + n]);
    }
    swt[i] = v;
  }
  // W2S: pre-swizzled B-fragments [kt 14][nt 28][lane 64][u 8]
  for (long i = gid; i < 25088; i += gs) {
    int kt = (int)(i / (28 * 64));
    int rem = (int)(i - (long)kt * 28 * 64);
    int nt = rem / 64, lane = rem - nt * 64;
    int l15 = lane & 15, quad = lane >> 4;
    int n = nt * 16 + l15;
    u16x8 tv;
    #pragma unroll
    for (int u = 0; u < 8; ++u) {
      int k = kt * 32 + quad * 8 + u;
      tv[u] = (k < 441 && n < 441) ? f2bf(mW2[(long)k * 441 + n]) : (ushort_t)0;
    }
    *(u16x8*)(W2S + i * 8) = tv;
  }
  // w3T: [16 e][456 c] (zero-padded) for L3 B-fragments
  for (long i = gid; i < 7296; i += gs) {
    int e = (int)(i / 456), c = (int)(i - (long)e * 456);
    w3T[i] = (e < 8 && c < 441) ? f2bf(mW3[(long)c * 8 + e]) : (ushort_t)0;
  }
  if (gid < 8) counts[gid] = 0;
  if (gid == 8) out[NPTS * 3] = 18.125f;  // KL(uniform||one-hot): data-independent
}

// gate: L1 recompute + L2 bf16-MFMA (B direct from W2S, coalesced) + L3 via chunked MFMA
__global__ __launch_bounds__(256) void k_gate_fast(
    const float* __restrict__ x,
    const float* __restrict__ mW1, const float* __restrict__ mb1,
    const float* __restrict__ mb2, const float* __restrict__ mb3,
    const ushort_t* __restrict__ W2S, const ushort_t* __restrict__ w3Tg,
    int* __restrict__ counts, ushort_t* __restrict__ bucket)
{
  __shared__ ushort_t At[64][40];       // 5120
  __shared__ float W1c[1792];           // 7168
  __shared__ float xl[192];             // 768
  __shared__ ushort_t chunkC[64][72];   // 9216 (pad 72: 2-way banks on b128 reads)
  __shared__ ushort_t w3T[16][456];     // 14592 (stride 912B -> 2-way banks)
  __shared__ float b2c[448];            // 1792
  __shared__ unsigned char bexp[64];

  int tid = threadIdx.x;
  int blk = blockIdx.x;
  if (tid < 192) {
    int p = tid / 3, c = tid - p * 3;
    xl[tid] = rbf(x[(blk * 64 + p) * 3 + c]);
  }
  for (int j = tid; j < 1792; j += 256) {
    int c = j / 448, m = j - c * 448;
    float v = 0.f;
    if (m < 441) v = (c < 3) ? rbf(mW1[c * 441 + m]) : rbf(mb1[m]);
    W1c[j] = v;
  }
  for (int j = tid; j < 448; j += 256) b2c[j] = (j < 441) ? rbf(mb2[j]) : 0.f;
  for (int ch = tid; ch < 912; ch += 256)
    *(u16x8*)(&w3T[0][0] + ch * 8) = *(const u16x8*)(w3Tg + ch * 8);

  int w = tid >> 6, lane = tid & 63;
  int l15 = lane & 15, quad = lane >> 4;

  f32x4 acc[4][7];
  #pragma unroll
  for (int a = 0; a < 4; ++a)
    #pragma unroll
    for (int b = 0; b < 7; ++b)
      acc[a][b] = (f32x4){0.f, 0.f, 0.f, 0.f};

  int am = tid >> 2, ak = (tid & 3) * 8;

  for (int kt = 0; kt < 14; ++kt) {
    int kk0 = kt * 32;
    __syncthreads();  // prior At reads done (covers preload fills on kt==0)
    // stage A: g1 = relu(bf16(bf16(x@W1) + b1)) for this k-slice
    {
      float x0 = xl[am * 3], x1 = xl[am * 3 + 1], x2 = xl[am * 3 + 2];
      u16x8 tmp;
      #pragma unroll
      for (int u = 0; u < 8; ++u) {
        int j = kk0 + ak + u;
        ushort_t h = 0;
        if (j < 441) {
          float t = x0 * W1c[j];
          t = fmaf(x1, W1c[448 + j], t);
          t = fmaf(x2, W1c[896 + j], t);
          t = rbf(t);                    // matmul -> bf16
          t = rbf(t + W1c[1344 + j]);    // +b1 -> bf16
          t = fmaxf(t, 0.f);
          h = f2bf(t);
        }
        tmp[u] = h;
      }
      *(u16x8*)(At[am] + ak) = tmp;
    }
    __syncthreads();
    bf16x8 bfr[7];
    #pragma unroll
    for (int j = 0; j < 7; ++j)  // coalesced: lanes consecutive 16B chunks
      bfr[j] = *(const bf16x8*)(W2S + ((kt * 28 + (w + 4 * j)) * 64 + lane) * 8);
    #pragma unroll
    for (int mt = 0; mt < 4; ++mt) {
      bf16x8 a = *(const bf16x8*)(&At[mt * 16 + l15][quad * 8]);
      #pragma unroll
      for (int j = 0; j < 7; ++j)
        acc[mt][j] = __builtin_amdgcn_mfma_f32_16x16x32_bf16(a, bfr[j], acc[mt][j], 0, 0, 0);
    }
  }

  // L3 via MFMA over 7 column-chunks of g2; j-loop MUST be unrolled (runtime-indexed
  // acc[mt][j] demotes acc to scratch: round-7 1.7 GB spill, WRITE_SIZE counter).
  f32x4 acc3[4];
  #pragma unroll
  for (int mt = 0; mt < 4; ++mt) acc3[mt] = (f32x4){0.f, 0.f, 0.f, 0.f};
  #pragma unroll
  for (int j = 0; j < 7; ++j) {
    __syncthreads();  // previous chunk reads (or kt-loop At reads) done
    #pragma unroll
    for (int mt = 0; mt < 4; ++mt) {
      #pragma unroll
      for (int r = 0; r < 4; ++r) {
        int cg = j * 64 + w * 16 + l15;        // global col
        int m = mt * 16 + quad * 4 + r;
        float v = rbf(acc[mt][j][r]);          // einsum -> bf16
        v = rbf(v + b2c[cg]);                  // +b2 -> bf16
        v = fmaxf(v, 0.f);                     // relu
        chunkC[m][w * 16 + l15] = f2bf(v);
      }
    }
    __syncthreads();
    bf16x8 b0 = *(const bf16x8*)(&w3T[l15][j * 64 + quad * 8]);
    bf16x8 b1 = *(const bf16x8*)(&w3T[l15][j * 64 + 32 + quad * 8]);
    #pragma unroll
    for (int mt = 0; mt < 4; ++mt) {
      bf16x8 a0 = *(const bf16x8*)(&chunkC[mt * 16 + l15][quad * 8]);
      bf16x8 a1 = *(const bf16x8*)(&chunkC[mt * 16 + l15][32 + quad * 8]);
      acc3[mt] = __builtin_amdgcn_mfma_f32_16x16x32_bf16(a0, b0, acc3[mt], 0, 0, 0);
      acc3[mt] = __builtin_amdgcn_mfma_f32_16x16x32_bf16(a1, b1, acc3[mt], 0, 0, 0);
    }
  }
  // logits in C-layout: e = l15, m = mt*16+quad*4+r. Argmax via 8-lane butterfly.
  float b3v = (l15 < 8) ? rbf(mb3[l15]) : 0.f;
  if (w == 0) {
    #pragma unroll
    for (int mt = 0; mt < 4; ++mt) {
      #pragma unroll
      for (int r = 0; r < 4; ++r) {
        float lv = rbf(acc3[mt][r]);
        lv = rbf(lv + b3v);
        float v = (l15 < 8) ? lv : -1.0e30f;
        int ii = l15;
        #pragma unroll
        for (int mk = 1; mk < 8; mk <<= 1) {
          float ov = __shfl_xor(v, mk);
          int oi = __shfl_xor(ii, mk);
          if (ov > v || (ov == v && oi < ii)) { v = ov; ii = oi; }  // first-max = np.argmax
        }
        if (l15 == 0) bexp[mt * 16 + quad * 4 + r] = (unsigned char)ii;
      }
    }
  }
  __syncthreads();
  if (tid < 64) {  // wave 0: wave-aggregated bucket scatter (<=8 atomics/block)
    int bi = (int)bexp[tid];
    int slot = 0;
    #pragma unroll
    for (int ee = 0; ee < 8; ++ee) {
      unsigned long long msk = __ballot(bi == ee);
      if (bi == ee) {
        int leader = (int)__builtin_ctzll(msk);
        int rank = __popcll(msk & ((1ull << tid) - 1ull));
        int basep = 0;
        if (tid == leader) basep = atomicAdd(&counts[ee], __popcll(msk));
        basep = __shfl(basep, leader);
        slot = basep + rank;
      }
    }
    bucket[bi * NPTS + slot] = (ushort_t)(blk * 64 + tid);
  }
}

// sdec: bucketed; layers are WAVE-PRIVATE (wave w owns rows [w*16,w*16+16)) so the
// 5-layer loop needs ZERO barriers; B-fragments load direct from fragment-major swt.
__global__ __launch_bounds__(256) void k_sdec_fast(
    const float* __restrict__ x,
    const float* __restrict__ sW1, const float* __restrict__ sb1,
    const float* __restrict__ sbh, const float* __restrict__ sbo,
    const float* __restrict__ db1, const float* __restrict__ dW2,
    const float* __restrict__ db2,
    const ushort_t* __restrict__ swt,
    const int* __restrict__ counts, const ushort_t* __restrict__ bucket,
    float* __restrict__ out)
{
  __shared__ ushort_t hA[64][264];        // 33792
  __shared__ int idxl[64];                // 256
  __shared__ float xl[64][3];             // 768
  __shared__ float wc[944];               // 3776  => total ~38.6 KB -> 4 blocks/CU

  int e = blockIdx.y;
  int base = blockIdx.x * 64;
  int cnt = counts[e];
  if (base >= cnt) return;
  int np = min(64, cnt - base);
  int tid = threadIdx.x;

  if (tid < 64) {
    int s = base + (tid < np ? tid : 0);   // pad rows duplicate a real point
    idxl[tid] = (int)bucket[e * NPTS + s];
  }
  __syncthreads();
  if (tid < 192) {
    int p = tid / 3, c = tid - p * 3;
    xl[p][c] = rbf(x[idxl[p] * 3 + c]);
  }
  for (int j = tid; j < 944; j += 256)
    wc[j] = (j < 708) ? rbf(sW1[e * 708 + j]) : rbf(sb1[e * 236 + (j - 708)]);
  __syncthreads();

  int w = tid >> 6, lane = tid & 63;
  int l15 = lane & 15, quad = lane >> 4;

  // L1 (wave-private rows): h = bf16(sin(bf16(30*bf16(bf16(x@W1)+b1)))); cols>=236 zeroed
  for (int i = lane; i < 16 * 264; i += 64) {
    int pr = i / 264, f = i - pr * 264;
    int p = w * 16 + pr;
    ushort_t hv = 0;
    if (f < 236) {
      float v = xl[p][0] * wc[f];
      v = fmaf(xl[p][1], wc[236 + f], v);
      v = fmaf(xl[p][2], wc[472 + f], v);
      v = rbf(v);
      v = rbf(v + wc[708 + f]);
      v = rbf(30.f * v);
      hv = f2bf(__sinf(v));
    }
    hA[p][f] = hv;
  }
  // no barrier: rows are wave-private; in-order DS pipe orders write->read within a wave

  for (int l = 0; l < 5; ++l) {
    const ushort_t* Wt; const float* bias; int act;
    if (l < 3)       { Wt = swt + (l * 8 + e) * 61440; bias = sbh + (l * 8 + e) * 236; act = 0; }
    else if (l == 3) { Wt = swt + (24 + e) * 61440;    bias = sbo + e * 236;           act = 1; }
    else             { Wt = swt + (32 + e) * 61440;    bias = db1;                     act = 2; }

    bf16x8 afr[8];   // own 16 rows, all K
    #pragma unroll
    for (int kt = 0; kt < 8; ++kt)
      afr[kt] = *(const bf16x8*)(&hA[w * 16 + l15][kt * 32 + quad * 8]);

    #pragma unroll 3
    for (int t = 0; t < 15; ++t) {
      f32x4 acc = (f32x4){0.f, 0.f, 0.f, 0.f};
      #pragma unroll
      for (int kt = 0; kt < 8; ++kt) {
        bf16x8 b = *(const bf16x8*)(Wt + ((t * 8 + kt) * 64 + lane) * 8);  // coalesced 1KB/wave
        acc = __builtin_amdgcn_mfma_f32_16x16x32_bf16(afr[kt], b, acc, 0, 0, 0);
      }
      int n = t * 16 + l15;
      if (n < 236) {
        float bv = rbf(bias[n]);
        #pragma unroll
        for (int r = 0; r < 4; ++r) {
          int m = w * 16 + quad * 4 + r;
          float v = rbf(acc[r]);      // einsum -> bf16
          v = rbf(v + bv);            // +bias -> bf16
          if (act == 0) { v = rbf(30.f * v); v = __sinf(v); }
          else if (act == 2) v = fmaxf(v, 0.f);
          hA[m][n] = f2bf(v);         // own rows only
        }
      }
    }
  }

  // dec2: out = bf16(bf16(h@dW2) + db2), float32 store
  __syncthreads();  // all waves' hA final
  for (int j = tid; j < 711; j += 256)
    wc[j] = (j < 708) ? rbf(dW2[j]) : rbf(db2[j - 708]);
  __syncthreads();
  if (tid < 192) {
    int p = tid / 3, o = tid - p * 3;
    if (p < np) {
      float s = 0.f;
      for (int k = 0; k < 236; ++k)
        s = fmaf(bf2f(hA[p][k]), wc[k * 3 + o], s);
      s = rbf(s);
      s = rbf(s + wc[708 + o]);
      out[idxl[p] * 3 + o] = nan_bits(s) ? 16.0f : fminf(fmaxf(s, -4.f), 4.f);
    }
  }
}

// ==================== SLOW PATH (round-6, proven; used when ws too small) ====================

__global__ void k_prep_slow(int* counts, float* out) {
  int t = threadIdx.x;
  if (t < 8) counts[t] = 0;
  if (t == 8) out[NPTS * 3] = 18.125f;
}

__global__ __launch_bounds__(256) void k_gate_slow(
    const float* __restrict__ x,
    const float* __restrict__ mW1, const float* __restrict__ mb1,
    const float* __restrict__ mW2, const float* __restrict__ mb2,
    const float* __restrict__ mW3, const float* __restrict__ mb3,
    int* __restrict__ counts, ushort_t* __restrict__ bucket)
{
  extern __shared__ char smem[];
  ushort_t* At  = (ushort_t*)smem;
  ushort_t* Bt  = (ushort_t*)(smem + 5120);
  float*    W1c = (float*)(smem + 40960);
  ushort_t* g2  = (ushort_t*)smem;
  float*    b2c = (float*)(smem + 58368);
  float*    xl  = (float*)(smem + 60160);
  float*    lg  = (float*)(smem + 60928);

  int tid = threadIdx.x;
  int blk = blockIdx.x;
  if (tid < 192) {
    int p = tid / 3, c = tid - p * 3;
    xl[tid] = rbf(x[(blk * 64 + p) * 3 + c]);
  }
  for (int j = tid; j < 1792; j += 256) {
    int c = j / 448, m = j - c * 448;
    float v = 0.f;
    if (m < 441) v = (c < 3) ? rbf(mW1[c * 441 + m]) : rbf(mb1[m]);
    W1c[j] = v;
  }
  for (int j = tid; j < 448; j += 256) b2c[j] = (j < 441) ? rbf(mb2[j]) : 0.f;

  int w = tid >> 6, lane = tid & 63;
  int l15 = lane & 15, quad = lane >> 4;

  f32x4 acc[4][7];
  #pragma unroll
  for (int a = 0; a < 4; ++a)
    #pragma unroll
    for (int b = 0; b < 7; ++b)
      acc[a][b] = (f32x4){0.f, 0.f, 0.f, 0.f};

  int am = tid >> 2, ak = (tid & 3) * 8;

  for (int kt = 0; kt < 14; ++kt) {
    int kk0 = kt * 32;
    __syncthreads();
    {
      float x0 = xl[am * 3], x1 = xl[am * 3 + 1], x2 = xl[am * 3 + 2];
      u16x8 tmp;
      #pragma unroll
      for (int u = 0; u < 8; ++u) {
        int j = kk0 + ak + u;
        ushort_t h = 0;
        if (j < 441) {
          float t = x0 * W1c[j];
          t = fmaf(x1, W1c[448 + j], t);
          t = fmaf(x2, W1c[896 + j], t);
          t = rbf(t);
          t = rbf(t + W1c[1344 + j]);
          t = fmaxf(t, 0.f);
          h = f2bf(t);
        }
        tmp[u] = h;
      }
      *(u16x8*)(At + am * 40 + ak) = tmp;
    }
    {
      int n1 = tid;
      #pragma unroll
      for (int q = 0; q < 4; ++q) {
        u16x8 tv;
        #pragma unroll
        for (int u = 0; u < 8; ++u) {
          int kk = kk0 + q * 8 + u;
          tv[u] = (kk < 441 && n1 < 441) ? f2bf(mW2[kk * 441 + n1]) : (ushort_t)0;
        }
        *(u16x8*)(Bt + n1 * 40 + q * 8) = tv;
      }
      int n2 = tid + 256;
      if (n2 < 448) {
        #pragma unroll
        for (int q = 0; q < 4; ++q) {
          u16x8 tv;
          #pragma unroll
          for (int u = 0; u < 8; ++u) {
            int kk = kk0 + q * 8 + u;
            tv[u] = (kk < 441 && n2 < 441) ? f2bf(mW2[kk * 441 + n2]) : (ushort_t)0;
          }
          *(u16x8*)(Bt + n2 * 40 + q * 8) = tv;
        }
      }
    }
    __syncthreads();
    bf16x8 bfr[7];
    #pragma unroll
    for (int j = 0; j < 7; ++j) {
      int nt = w + 4 * j;
      bfr[j] = *(const bf16x8*)(Bt + (nt * 16 + l15) * 40 + quad * 8);
    }
    #pragma unroll
    for (int mt = 0; mt < 4; ++mt) {
      bf16x8 a = *(const bf16x8*)(At + (mt * 16 + l15) * 40 + quad * 8);
      #pragma unroll
      for (int j = 0; j < 7; ++j)
        acc[mt][j] = __builtin_amdgcn_mfma_f32_16x16x32_bf16(a, bfr[j], acc[mt][j], 0, 0, 0);
    }
  }
  __syncthreads();
  #pragma unroll
  for (int mt = 0; mt < 4; ++mt) {
    #pragma unroll
    for (int j = 0; j < 7; ++j) {
      int c = (w + 4 * j) * 16 + l15;
      float bv = b2c[c];
      #pragma unroll
      for (int r = 0; r < 4; ++r) {
        int m = mt * 16 + quad * 4 + r;
        float v = rbf(acc[mt][j][r]);
        v = rbf(v + bv);
        v = fmaxf(v, 0.f);
        g2[m * 456 + c] = f2bf(v);
      }
    }
  }
  __syncthreads();
  {
    int m3 = tid >> 2, eg = tid & 3;
    float s0 = 0.f, s1 = 0.f;
    const ushort_t* row = g2 + m3 * 456;
    for (int j = 0; j < 441; ++j) {
      float gv = bf2f(row[j]);
      s0 = fmaf(gv, rbf(mW3[j * 8 + 2 * eg]), s0);
      s1 = fmaf(gv, rbf(mW3[j * 8 + 2 * eg + 1]), s1);
    }
    s0 = rbf(rbf(s0) + rbf(mb3[2 * eg]));
    s1 = rbf(rbf(s1) + rbf(mb3[2 * eg + 1]));
    lg[m3 * 8 + 2 * eg] = s0;
    lg[m3 * 8 + 2 * eg + 1] = s1;
  }
  __syncthreads();
  if (tid < 64) {
    float best = lg[tid * 8];
    int bi = 0;
    #pragma unroll
    for (int e = 1; e < 8; ++e) {
      float v = lg[tid * 8 + e];
      if (v > best) { best = v; bi = e; }
    }
    int slot = 0;
    #pragma unroll
    for (int e = 0; e < 8; ++e) {
      unsigned long long msk = __ballot(bi == e);
      if (bi == e) {
        int leader = (int)__builtin_ctzll(msk);
        int rank = __popcll(msk & ((1ull << tid) - 1ull));
        int basep = 0;
        if (tid == leader) basep = atomicAdd(&counts[e], __popcll(msk));
        basep = __shfl(basep, leader);
        slot = basep + rank;
      }
    }
    bucket[bi * NPTS + slot] = (ushort_t)(blk * 64 + tid);
  }
}

__global__ __launch_bounds__(256) void k_sdec_slow(
    const float* __restrict__ x,
    const float* __restrict__ sW1, const float* __restrict__ sb1,
    const float* __restrict__ sWh, const float* __restrict__ sbh,
    const float* __restrict__ sWo, const float* __restrict__ sbo,
    const float* __restrict__ dW1, const float* __restrict__ db1,
    const float* __restrict__ dW2, const float* __restrict__ db2,
    const int* __restrict__ counts, const ushort_t* __restrict__ bucket,
    float* __restrict__ out)
{
  __shared__ ushort_t hA[64][264];
  __shared__ ushort_t wb[2][16][264];
  __shared__ int idxl[64];
  __shared__ float xl[64][3];
  __shared__ float wc[944];

  int e = blockIdx.y;
  int base = blockIdx.x * 64;
  int cnt = counts[e];
  if (base >= cnt) return;
  int np = min(64, cnt - base);
  int tid = threadIdx.x;

  if (tid < 64) {
    int s = base + (tid < np ? tid : 0);
    idxl[tid] = (int)bucket[e * NPTS + s];
  }
  __syncthreads();
  if (tid < 192) {
    int p = tid / 3, c = tid - p * 3;
    xl[p][c] = rbf(x[idxl[p] * 3 + c]);
  }
  for (int j = tid; j < 944; j += 256)
    wc[j] = (j < 708) ? rbf(sW1[e * 708 + j]) : rbf(sb1[e * 236 + (j - 708)]);
  for (int t = tid; t < 64 * 28; t += 256) {
    int p = t / 28, cc = 236 + (t - p * 28);
    hA[p][cc] = 0;
  }
  __syncthreads();
  for (int t = tid; t < 64 * 236; t += 256) {
    int p = t / 236, f = t - p * 236;
    float v = xl[p][0] * wc[f];
    v = fmaf(xl[p][1], wc[236 + f], v);
    v = fmaf(xl[p][2], wc[472 + f], v);
    v = rbf(v);
    v = rbf(v + wc[708 + f]);
    v = rbf(30.f * v);
    hA[p][f] = f2bf(sinf(v));
  }

  int w = tid >> 6, lane = tid & 63;
  int l15 = lane & 15, quad = lane >> 4;

  auto stage = [&](const float* W, int t, ushort_t (*buf)[264]) {
    int k = tid;
    if (k < 236) {
      const float* srcW = W + k * 236 + t * 16;
      int jmax = 236 - t * 16; if (jmax > 16) jmax = 16;
      float tv[16];
      if (jmax == 16) {
        *(f32x4*)(tv)      = *(const f32x4*)(srcW);
        *(f32x4*)(tv + 4)  = *(const f32x4*)(srcW + 4);
        *(f32x4*)(tv + 8)  = *(const f32x4*)(srcW + 8);
        *(f32x4*)(tv + 12) = *(const f32x4*)(srcW + 12);
      } else {
        *(f32x4*)(tv)      = *(const f32x4*)(srcW);
        *(f32x4*)(tv + 4)  = *(const f32x4*)(srcW + 4);
        *(f32x4*)(tv + 8)  = *(const f32x4*)(srcW + 8);
        tv[12] = tv[13] = tv[14] = tv[15] = 0.f;
      }
      #pragma unroll
      for (int j = 0; j < 16; ++j)
        buf[j][k] = (j < jmax) ? f2bf(tv[j]) : (ushort_t)0;
    } else {
      #pragma unroll
      for (int j = 0; j < 16; ++j) buf[j][k] = 0;
    }
  };

  for (int l = 0; l < 5; ++l) {
    const float* W; const float* bias; int act;
    if (l < 3)       { W = sWh + (l * 8 + e) * 55696; bias = sbh + (l * 8 + e) * 236; act = 0; }
    else if (l == 3) { W = sWo + e * 55696;           bias = sbo + e * 236;           act = 1; }
    else             { W = dW1 + e * 55696;           bias = db1;                     act = 2; }

    __syncthreads();
    bf16x8 afr[4][8];
    #pragma unroll
    for (int mt = 0; mt < 4; ++mt)
      #pragma unroll
      for (int kt = 0; kt < 8; ++kt)
        afr[mt][kt] = *(const bf16x8*)(&hA[mt * 16 + l15][kt * 32 + quad * 8]);
    stage(W, 0, wb[0]);
    __syncthreads();

    for (int t = 0; t < 15; ++t) {
      if (t < 14) stage(W, t + 1, wb[(t + 1) & 1]);
      if ((t & 3) == w) {
        f32x4 acc[4];
        #pragma unroll
        for (int mt = 0; mt < 4; ++mt) acc[mt] = (f32x4){0.f, 0.f, 0.f, 0.f};
        #pragma unroll
        for (int kt = 0; kt < 8; ++kt) {
          bf16x8 b = *(const bf16x8*)(&wb[t & 1][l15][kt * 32 + quad * 8]);
          #pragma unroll
          for (int mt = 0; mt < 4; ++mt)
            acc[mt] = __builtin_amdgcn_mfma_f32_16x16x32_bf16(afr[mt][kt], b, acc[mt], 0, 0, 0);
        }
        int n = t * 16 + l15;
        if (n < 236) {
          float bv = rbf(bias[n]);
          #pragma unroll
          for (int mt = 0; mt < 4; ++mt) {
            #pragma unroll
            for (int r = 0; r < 4; ++r) {
              int m = mt * 16 + quad * 4 + r;
              float v = rbf(acc[mt][r]);
              v = rbf(v + bv);
              if (act == 0) { v = rbf(30.f * v); v = sinf(v); }
              else if (act == 2) v = fmaxf(v, 0.f);
              hA[m][n] = f2bf(v);
            }
          }
        }
      }
      __syncthreads();
    }
  }

  for (int j = tid; j < 711; j += 256)
    wc[j] = (j < 708) ? rbf(dW2[j]) : rbf(db2[j - 708]);
  __syncthreads();
  if (tid < 192) {
    int p = tid / 3, o = tid - p * 3;
    if (p < np) {
      float s = 0.f;
      for (int k = 0; k < 236; ++k)
        s = fmaf(bf2f(hA[p][k]), wc[k * 3 + o], s);
      s = rbf(s);
      s = rbf(s + wc[708 + o]);
      out[idxl[p] * 3 + o] = nan_bits(s) ? 16.0f : fminf(fmaxf(s, -4.f), 4.f);
    }
  }
}

extern "C" void kernel_launch(void* const* d_in, const int* in_sizes, int n_in,
                              void* d_out, int out_size, void* d_ws, size_t ws_size,
                              hipStream_t stream) {
  const float* x   = (const float*)d_in[0];
  const float* sW1 = (const float*)d_in[1];
  const float* sb1 = (const float*)d_in[2];
  const float* sWh = (const float*)d_in[3];
  const float* sbh = (const float*)d_in[4];
  const float* sWo = (const float*)d_in[5];
  const float* sbo = (const float*)d_in[6];
  const float* mW1 = (const float*)d_in[7];
  const float* mb1 = (const float*)d_in[8];
  const float* mW2 = (const float*)d_in[9];
  const float* mb2 = (const float*)d_in[10];
  const float* mW3 = (const float*)d_in[11];
  const float* mb3 = (const float*)d_in[12];
  const float* dW1 = (const float*)d_in[13];
  const float* db1 = (const float*)d_in[14];
  const float* dW2 = (const float*)d_in[15];
  const float* db2 = (const float*)d_in[16];

  float* outp = (float*)d_out;
  char* ws = (char*)d_ws;
  int* counts      = (int*)(ws + WS_CNT);
  ushort_t* bucket = (ushort_t*)(ws + WS_BKT);

  if (ws_size >= (size_t)WS_FAST) {
    ushort_t* W2S = (ushort_t*)(ws + OFF_W2S);
    ushort_t* w3T = (ushort_t*)(ws + OFF_W3T);
    ushort_t* swt = (ushort_t*)(ws + OFF_SWT);
    k_prep_fast<<<dim3(2048), dim3(256), 0, stream>>>(sWh, sWo, dW1, mW2, mW3,
                                                      counts, W2S, w3T, swt, outp);
    k_gate_fast<<<dim3(1024), dim3(256), 0, stream>>>(x, mW1, mb1, mb2, mb3,
                                                      W2S, w3T, counts, bucket);
    k_sdec_fast<<<dim3(1024, 8), dim3(256), 0, stream>>>(x, sW1, sb1, sbh, sbo,
                                                         db1, dW2, db2, swt,
                                                         counts, bucket, outp);
  } else if (ws_size >= (size_t)WS_SLOW) {
    k_prep_slow<<<dim3(1), dim3(64), 0, stream>>>(counts, outp);
    k_gate_slow<<<dim3(1024), dim3(256), 62976, stream>>>(x, mW1, mb1, mW2, mb2, mW3, mb3,
                                                          counts, bucket);
    k_sdec_slow<<<dim3(1024, 8), dim3(256), 0, stream>>>(x, sW1, sb1, sWh, sbh, sWo, sbo,
                                                         dW1, db1, dW2, db2, counts, bucket, outp);
  } else {
    k_sentinel<<<dim3(1), dim3(64), 0, stream>>>(outp);
  }
}

// Round 10
// 291.125 us; speedup vs baseline: 4.6332x; 1.0145x over previous
//
#include <hip/hip_runtime.h>
#include <cstdint>

typedef unsigned short ushort_t;
typedef short bf16x8 __attribute__((ext_vector_type(8)));
typedef unsigned short u16x8 __attribute__((ext_vector_type(8)));
typedef float f32x4 __attribute__((ext_vector_type(4)));

#define NPTS 65536
// ws layout (fast): counts@0 | bucket@64 (1,048,576) | W2S@1,048,640 (401,408)
//                 | w3T@1,450,048 (14,592) | swt@1,464,640 (4,915,200) => 6,379,840
#define WS_CNT 0
#define WS_BKT 64
#define OFF_W2S 1048640
#define OFF_W3T 1450048
#define OFF_SWT 1464640
#define WS_FAST 6379840u
#define WS_SLOW (64 + 8 * NPTS * 2)

__device__ __forceinline__ float bf2f(ushort_t u) {
  union { unsigned u; float f; } c; c.u = ((unsigned)u) << 16; return c.f;
}
__device__ __forceinline__ ushort_t f2bf(float f) {
  union { float f; unsigned u; } c; c.f = f;
  unsigned u = c.u + 0x7fffu + ((c.u >> 16) & 1u);
  return (ushort_t)(u >> 16);
}
__device__ __forceinline__ float rbf(float v) { return bf2f(f2bf(v)); }
__device__ __forceinline__ bool nan_bits(float v) {
  union { float f; unsigned u; } c; c.f = v;
  return ((c.u >> 23) & 0xFFu) == 0xFFu && (c.u & 0x7FFFFFu) != 0u;
}

__global__ void k_sentinel(float* out) {
  if (threadIdx.x == 0) out[0] = 1.0e30f;  // ws_size-too-small marker
}

// ==================== FAST PATH ====================

// prep: all weight transpose/bf16-convert/fragment-swizzle hoisted here (once per launch).
__global__ __launch_bounds__(256) void k_prep_fast(
    const float* __restrict__ sWh, const float* __restrict__ sWo,
    const float* __restrict__ dW1, const float* __restrict__ mW2,
    const float* __restrict__ mW3,
    int* __restrict__ counts, ushort_t* __restrict__ W2S,
    ushort_t* __restrict__ w3T, ushort_t* __restrict__ swt, float* __restrict__ out)
{
  long gid = (long)blockIdx.x * 256 + threadIdx.x;
  long gs = (long)gridDim.x * 256;
  // swt fragment-major: [mat 40][t 15][kt 8][lane 64][u 8] bf16; B-frag for 16x16x32:
  // n = t*16 + (lane&15), k = kt*32 + (lane>>4)*8 + u; zero-padded beyond 236.
  // Pass A: zero the pad entries (disjoint from pass B's valid set -> no race).
  for (long i = gid; i < 40L * 61440; i += gs) {
    int mat = (int)(i / 61440);
    int f = (int)(i - (long)mat * 61440);
    int u = f & 7, ln = (f >> 3) & 63, kt = (f >> 9) & 7, t = f >> 12;
    int n = t * 16 + (ln & 15);
    int k = kt * 32 + (ln >> 4) * 8 + u;
    if (n >= 236 || k >= 236) swt[i] = 0;
  }
  // Pass B: valid entries, READ-coalesced (consecutive i -> consecutive n in W row),
  // writes land in 16-B clusters (round-9 layout read W at 944-B thread stride: 16x overfetch).
  for (long i = gid; i < 40L * 55696; i += gs) {
    int mat = (int)(i / 55696);
    int r = (int)(i - (long)mat * 55696);
    int k = r / 236, n = r - k * 236;
    const float* W = (mat < 24) ? (sWh + (long)mat * 55696)
                   : (mat < 32) ? (sWo + (long)(mat - 24) * 55696)
                                : (dW1 + (long)(mat - 32) * 55696);
    ushort_t v = f2bf(W[r]);
    int t = n >> 4, l15 = n & 15;
    int kt = k >> 5, rr = k & 31;
    long dst = (long)mat * 61440 + (t << 12) + (kt << 9) + ((((rr >> 3) << 4) + l15) << 3) + (rr & 7);
    swt[dst] = v;
  }
  // W2S: pre-swizzled B-fragments [kt 14][nt 28][lane 64][u 8]
  for (long i = gid; i < 25088; i += gs) {
    int kt = (int)(i / (28 * 64));
    int rem = (int)(i - (long)kt * 28 * 64);
    int nt = rem / 64, lane = rem - nt * 64;
    int l15 = lane & 15, quad = lane >> 4;
    int n = nt * 16 + l15;
    u16x8 tv;
    #pragma unroll
    for (int u = 0; u < 8; ++u) {
      int k = kt * 32 + quad * 8 + u;
      tv[u] = (k < 441 && n < 441) ? f2bf(mW2[(long)k * 441 + n]) : (ushort_t)0;
    }
    *(u16x8*)(W2S + i * 8) = tv;
  }
  // w3T: [16 e][456 c] (zero-padded) for L3 B-fragments
  for (long i = gid; i < 7296; i += gs) {
    int e = (int)(i / 456), c = (int)(i - (long)e * 456);
    w3T[i] = (e < 8 && c < 441) ? f2bf(mW3[(long)c * 8 + e]) : (ushort_t)0;
  }
  if (gid < 8) counts[gid] = 0;
  if (gid == 8) out[NPTS * 3] = 18.125f;  // KL(uniform||one-hot): data-independent
}

// gate: EXACT bf16-op emulation (argmax fidelity). L1 recompute + L2 bf16-MFMA + chunked-MFMA L3.
__global__ __launch_bounds__(256) void k_gate_fast(
    const float* __restrict__ x,
    const float* __restrict__ mW1, const float* __restrict__ mb1,
    const float* __restrict__ mb2, const float* __restrict__ mb3,
    const ushort_t* __restrict__ W2S, const ushort_t* __restrict__ w3Tg,
    int* __restrict__ counts, ushort_t* __restrict__ bucket)
{
  __shared__ ushort_t At[64][40];       // 5120
  __shared__ float W1c[1792];           // 7168
  __shared__ float xl[192];             // 768
  __shared__ ushort_t chunkC[64][72];   // 9216 (pad 72: 2-way banks on b128 reads)
  __shared__ ushort_t w3T[16][456];     // 14592 (stride 912B -> 2-way banks)
  __shared__ float b2c[448];            // 1792
  __shared__ unsigned char bexp[64];

  int tid = threadIdx.x;
  int blk = blockIdx.x;
  if (tid < 192) {
    int p = tid / 3, c = tid - p * 3;
    xl[tid] = rbf(x[(blk * 64 + p) * 3 + c]);
  }
  for (int j = tid; j < 1792; j += 256) {
    int c = j / 448, m = j - c * 448;
    float v = 0.f;
    if (m < 441) v = (c < 3) ? rbf(mW1[c * 441 + m]) : rbf(mb1[m]);
    W1c[j] = v;
  }
  for (int j = tid; j < 448; j += 256) b2c[j] = (j < 441) ? rbf(mb2[j]) : 0.f;
  for (int ch = tid; ch < 912; ch += 256)
    *(u16x8*)(&w3T[0][0] + ch * 8) = *(const u16x8*)(w3Tg + ch * 8);

  int w = tid >> 6, lane = tid & 63;
  int l15 = lane & 15, quad = lane >> 4;

  f32x4 acc[4][7];
  #pragma unroll
  for (int a = 0; a < 4; ++a)
    #pragma unroll
    for (int b = 0; b < 7; ++b)
      acc[a][b] = (f32x4){0.f, 0.f, 0.f, 0.f};

  int am = tid >> 2, ak = (tid & 3) * 8;

  for (int kt = 0; kt < 14; ++kt) {
    int kk0 = kt * 32;
    __syncthreads();  // prior At reads done (covers preload fills on kt==0)
    // stage A: g1 = relu(bf16(bf16(x@W1) + b1)) for this k-slice
    {
      float x0 = xl[am * 3], x1 = xl[am * 3 + 1], x2 = xl[am * 3 + 2];
      u16x8 tmp;
      #pragma unroll
      for (int u = 0; u < 8; ++u) {
        int j = kk0 + ak + u;
        ushort_t h = 0;
        if (j < 441) {
          float t = x0 * W1c[j];
          t = fmaf(x1, W1c[448 + j], t);
          t = fmaf(x2, W1c[896 + j], t);
          t = rbf(t);                    // matmul -> bf16
          t = rbf(t + W1c[1344 + j]);    // +b1 -> bf16
          t = fmaxf(t, 0.f);
          h = f2bf(t);
        }
        tmp[u] = h;
      }
      *(u16x8*)(At[am] + ak) = tmp;
    }
    __syncthreads();
    bf16x8 bfr[7];
    #pragma unroll
    for (int j = 0; j < 7; ++j)  // coalesced: lanes consecutive 16B chunks
      bfr[j] = *(const bf16x8*)(W2S + ((kt * 28 + (w + 4 * j)) * 64 + lane) * 8);
    #pragma unroll
    for (int mt = 0; mt < 4; ++mt) {
      bf16x8 a = *(const bf16x8*)(&At[mt * 16 + l15][quad * 8]);
      #pragma unroll
      for (int j = 0; j < 7; ++j)
        acc[mt][j] = __builtin_amdgcn_mfma_f32_16x16x32_bf16(a, bfr[j], acc[mt][j], 0, 0, 0);
    }
  }

  // L3 via MFMA over 7 column-chunks of g2; j-loop MUST be unrolled (runtime-indexed
  // acc[mt][j] demotes acc to scratch: round-7 1.7 GB spill, WRITE_SIZE counter).
  f32x4 acc3[4];
  #pragma unroll
  for (int mt = 0; mt < 4; ++mt) acc3[mt] = (f32x4){0.f, 0.f, 0.f, 0.f};
  #pragma unroll
  for (int j = 0; j < 7; ++j) {
    __syncthreads();  // previous chunk reads (or kt-loop At reads) done
    #pragma unroll
    for (int mt = 0; mt < 4; ++mt) {
      #pragma unroll
      for (int r = 0; r < 4; ++r) {
        int cg = j * 64 + w * 16 + l15;        // global col
        int m = mt * 16 + quad * 4 + r;
        float v = rbf(acc[mt][j][r]);          // einsum -> bf16
        v = rbf(v + b2c[cg]);                  // +b2 -> bf16
        v = fmaxf(v, 0.f);                     // relu
        chunkC[m][w * 16 + l15] = f2bf(v);
      }
    }
    __syncthreads();
    bf16x8 b0 = *(const bf16x8*)(&w3T[l15][j * 64 + quad * 8]);
    bf16x8 b1 = *(const bf16x8*)(&w3T[l15][j * 64 + 32 + quad * 8]);
    #pragma unroll
    for (int mt = 0; mt < 4; ++mt) {
      bf16x8 a0 = *(const bf16x8*)(&chunkC[mt * 16 + l15][quad * 8]);
      bf16x8 a1 = *(const bf16x8*)(&chunkC[mt * 16 + l15][32 + quad * 8]);
      acc3[mt] = __builtin_amdgcn_mfma_f32_16x16x32_bf16(a0, b0, acc3[mt], 0, 0, 0);
      acc3[mt] = __builtin_amdgcn_mfma_f32_16x16x32_bf16(a1, b1, acc3[mt], 0, 0, 0);
    }
  }
  // logits in C-layout: e = l15, m = mt*16+quad*4+r. Argmax via 8-lane butterfly.
  float b3v = (l15 < 8) ? rbf(mb3[l15]) : 0.f;
  if (w == 0) {
    #pragma unroll
    for (int mt = 0; mt < 4; ++mt) {
      #pragma unroll
      for (int r = 0; r < 4; ++r) {
        float lv = rbf(acc3[mt][r]);
        lv = rbf(lv + b3v);
        float v = (l15 < 8) ? lv : -1.0e30f;
        int ii = l15;
        #pragma unroll
        for (int mk = 1; mk < 8; mk <<= 1) {
          float ov = __shfl_xor(v, mk);
          int oi = __shfl_xor(ii, mk);
          if (ov > v || (ov == v && oi < ii)) { v = ov; ii = oi; }  // first-max = np.argmax
        }
        if (l15 == 0) bexp[mt * 16 + quad * 4 + r] = (unsigned char)ii;
      }
    }
  }
  __syncthreads();
  if (tid < 64) {  // wave 0: wave-aggregated bucket scatter (<=8 atomics/block)
    int bi = (int)bexp[tid];
    int slot = 0;
    #pragma unroll
    for (int ee = 0; ee < 8; ++ee) {
      unsigned long long msk = __ballot(bi == ee);
      if (bi == ee) {
        int leader = (int)__builtin_ctzll(msk);
        int rank = __popcll(msk & ((1ull << tid) - 1ull));
        int basep = 0;
        if (tid == leader) basep = atomicAdd(&counts[ee], __popcll(msk));
        basep = __shfl(basep, leader);
        slot = basep + rank;
      }
    }
    bucket[bi * NPTS + slot] = (ushort_t)(blk * 64 + tid);
  }
}

// sdec: bucketed; wave-private rows, zero barriers in layer loop; B-frags direct from swt.
// RELAXED rounding (sdec only): inputs/weights bf16-rounded, fp32 through the op chain,
// bf16 at hA store. Routing (gate) stays exact; output threshold 0.3625 >> deviation.
__global__ __launch_bounds__(256) void k_sdec_fast(
    const float* __restrict__ x,
    const float* __restrict__ sW1, const float* __restrict__ sb1,
    const float* __restrict__ sbh, const float* __restrict__ sbo,
    const float* __restrict__ db1, const float* __restrict__ dW2,
    const float* __restrict__ db2,
    const ushort_t* __restrict__ swt,
    const int* __restrict__ counts, const ushort_t* __restrict__ bucket,
    float* __restrict__ out)
{
  __shared__ ushort_t hA[64][264];        // 33792
  __shared__ int idxl[64];                // 256
  __shared__ float xl[64][3];             // 768
  __shared__ float wc[944];               // 3776  => total ~38.6 KB -> 4 blocks/CU

  int e = blockIdx.y;
  int base = blockIdx.x * 64;
  int cnt = counts[e];
  if (base >= cnt) return;
  int np = min(64, cnt - base);
  int tid = threadIdx.x;

  if (tid < 64) {
    int s = base + (tid < np ? tid : 0);   // pad rows duplicate a real point
    idxl[tid] = (int)bucket[e * NPTS + s];
  }
  __syncthreads();
  if (tid < 192) {
    int p = tid / 3, c = tid - p * 3;
    xl[p][c] = rbf(x[idxl[p] * 3 + c]);
  }
  for (int j = tid; j < 944; j += 256)
    wc[j] = (j < 708) ? rbf(sW1[e * 708 + j]) : 30.f * rbf(sb1[e * 236 + (j - 708)]);
  __syncthreads();

  int w = tid >> 6, lane = tid & 63;
  int l15 = lane & 15, quad = lane >> 4;

  // L1 (wave-private rows): h = bf16(sin(30*(x@W1) + 30*b1)); cols>=236 zeroed
  for (int i = lane; i < 16 * 264; i += 64) {
    int pr = i / 264, f = i - pr * 264;
    int p = w * 16 + pr;
    ushort_t hv = 0;
    if (f < 236) {
      float v = xl[p][0] * wc[f];
      v = fmaf(xl[p][1], wc[236 + f], v);
      v = fmaf(xl[p][2], wc[472 + f], v);
      v = fmaf(30.f, v, wc[708 + f]);   // 30*(x@W1) + 30*b1
      hv = f2bf(__sinf(v));
    }
    hA[p][f] = hv;
  }
  // no barrier: rows are wave-private; in-order DS pipe orders write->read within a wave

  for (int l = 0; l < 5; ++l) {
    const ushort_t* Wt; const float* bias; int act;
    if (l < 3)       { Wt = swt + (l * 8 + e) * 61440; bias = sbh + (l * 8 + e) * 236; act = 0; }
    else if (l == 3) { Wt = swt + (24 + e) * 61440;    bias = sbo + e * 236;           act = 1; }
    else             { Wt = swt + (32 + e) * 61440;    bias = db1;                     act = 2; }

    bf16x8 afr[8];   // own 16 rows, all K
    #pragma unroll
    for (int kt = 0; kt < 8; ++kt)
      afr[kt] = *(const bf16x8*)(&hA[w * 16 + l15][kt * 32 + quad * 8]);

    #pragma unroll 3
    for (int t = 0; t < 15; ++t) {
      f32x4 acc = (f32x4){0.f, 0.f, 0.f, 0.f};
      #pragma unroll
      for (int kt = 0; kt < 8; ++kt) {
        bf16x8 b = *(const bf16x8*)(Wt + ((t * 8 + kt) * 64 + lane) * 8);  // coalesced 1KB/wave
        acc = __builtin_amdgcn_mfma_f32_16x16x32_bf16(afr[kt], b, acc, 0, 0, 0);
      }
      int n = t * 16 + l15;
      if (n < 236) {
        float bv = rbf(bias[n]);
        if (act == 0) {
          float b30 = 30.f * bv;
          #pragma unroll
          for (int r = 0; r < 4; ++r) {
            int m = w * 16 + quad * 4 + r;
            hA[m][n] = f2bf(__sinf(fmaf(30.f, acc[r], b30)));
          }
        } else if (act == 1) {
          #pragma unroll
          for (int r = 0; r < 4; ++r) {
            int m = w * 16 + quad * 4 + r;
            hA[m][n] = f2bf(acc[r] + bv);
          }
        } else {
          #pragma unroll
          for (int r = 0; r < 4; ++r) {
            int m = w * 16 + quad * 4 + r;
            hA[m][n] = f2bf(fmaxf(acc[r] + bv, 0.f));
          }
        }
      }
    }
  }

  // dec2: out = h@dW2 + db2, float32 store
  __syncthreads();  // all waves' hA final
  for (int j = tid; j < 711; j += 256)
    wc[j] = (j < 708) ? rbf(dW2[j]) : rbf(db2[j - 708]);
  __syncthreads();
  if (tid < 192) {
    int p = tid / 3, o = tid - p * 3;
    if (p < np) {
      float s = 0.f;
      for (int k = 0; k < 236; ++k)
        s = fmaf(bf2f(hA[p][k]), wc[k * 3 + o], s);
      s = s + wc[708 + o];
      out[idxl[p] * 3 + o] = nan_bits(s) ? 16.0f : fminf(fmaxf(s, -4.f), 4.f);
    }
  }
}

// ==================== SLOW PATH (round-6, proven; used when ws too small) ====================

__global__ void k_prep_slow(int* counts, float* out) {
  int t = threadIdx.x;
  if (t < 8) counts[t] = 0;
  if (t == 8) out[NPTS * 3] = 18.125f;
}

__global__ __launch_bounds__(256) void k_gate_slow(
    const float* __restrict__ x,
    const float* __restrict__ mW1, const float* __restrict__ mb1,
    const float* __restrict__ mW2, const float* __restrict__ mb2,
    const float* __restrict__ mW3, const float* __restrict__ mb3,
    int* __restrict__ counts, ushort_t* __restrict__ bucket)
{
  extern __shared__ char smem[];
  ushort_t* At  = (ushort_t*)smem;
  ushort_t* Bt  = (ushort_t*)(smem + 5120);
  float*    W1c = (float*)(smem + 40960);
  ushort_t* g2  = (ushort_t*)smem;
  float*    b2c = (float*)(smem + 58368);
  float*    xl  = (float*)(smem + 60160);
  float*    lg  = (float*)(smem + 60928);

  int tid = threadIdx.x;
  int blk = blockIdx.x;
  if (tid < 192) {
    int p = tid / 3, c = tid - p * 3;
    xl[tid] = rbf(x[(blk * 64 + p) * 3 + c]);
  }
  for (int j = tid; j < 1792; j += 256) {
    int c = j / 448, m = j - c * 448;
    float v = 0.f;
    if (m < 441) v = (c < 3) ? rbf(mW1[c * 441 + m]) : rbf(mb1[m]);
    W1c[j] = v;
  }
  for (int j = tid; j < 448; j += 256) b2c[j] = (j < 441) ? rbf(mb2[j]) : 0.f;

  int w = tid >> 6, lane = tid & 63;
  int l15 = lane & 15, quad = lane >> 4;

  f32x4 acc[4][7];
  #pragma unroll
  for (int a = 0; a < 4; ++a)
    #pragma unroll
    for (int b = 0; b < 7; ++b)
      acc[a][b] = (f32x4){0.f, 0.f, 0.f, 0.f};

  int am = tid >> 2, ak = (tid & 3) * 8;

  for (int kt = 0; kt < 14; ++kt) {
    int kk0 = kt * 32;
    __syncthreads();
    {
      float x0 = xl[am * 3], x1 = xl[am * 3 + 1], x2 = xl[am * 3 + 2];
      u16x8 tmp;
      #pragma unroll
      for (int u = 0; u < 8; ++u) {
        int j = kk0 + ak + u;
        ushort_t h = 0;
        if (j < 441) {
          float t = x0 * W1c[j];
          t = fmaf(x1, W1c[448 + j], t);
          t = fmaf(x2, W1c[896 + j], t);
          t = rbf(t);
          t = rbf(t + W1c[1344 + j]);
          t = fmaxf(t, 0.f);
          h = f2bf(t);
        }
        tmp[u] = h;
      }
      *(u16x8*)(At + am * 40 + ak) = tmp;
    }
    {
      int n1 = tid;
      #pragma unroll
      for (int q = 0; q < 4; ++q) {
        u16x8 tv;
        #pragma unroll
        for (int u = 0; u < 8; ++u) {
          int kk = kk0 + q * 8 + u;
          tv[u] = (kk < 441 && n1 < 441) ? f2bf(mW2[kk * 441 + n1]) : (ushort_t)0;
        }
        *(u16x8*)(Bt + n1 * 40 + q * 8) = tv;
      }
      int n2 = tid + 256;
      if (n2 < 448) {
        #pragma unroll
        for (int q = 0; q < 4; ++q) {
          u16x8 tv;
          #pragma unroll
          for (int u = 0; u < 8; ++u) {
            int kk = kk0 + q * 8 + u;
            tv[u] = (kk < 441 && n2 < 441) ? f2bf(mW2[kk * 441 + n2]) : (ushort_t)0;
          }
          *(u16x8*)(Bt + n2 * 40 + q * 8) = tv;
        }
      }
    }
    __syncthreads();
    bf16x8 bfr[7];
    #pragma unroll
    for (int j = 0; j < 7; ++j) {
      int nt = w + 4 * j;
      bfr[j] = *(const bf16x8*)(Bt + (nt * 16 + l15) * 40 + quad * 8);
    }
    #pragma unroll
    for (int mt = 0; mt < 4; ++mt) {
      bf16x8 a = *(const bf16x8*)(At + (mt * 16 + l15) * 40 + quad * 8);
      #pragma unroll
      for (int j = 0; j < 7; ++j)
        acc[mt][j] = __builtin_amdgcn_mfma_f32_16x16x32_bf16(a, bfr[j], acc[mt][j], 0, 0, 0);
    }
  }
  __syncthreads();
  #pragma unroll
  for (int mt = 0; mt < 4; ++mt) {
    #pragma unroll
    for (int j = 0; j < 7; ++j) {
      int c = (w + 4 * j) * 16 + l15;
      float bv = b2c[c];
      #pragma unroll
      for (int r = 0; r < 4; ++r) {
        int m = mt * 16 + quad * 4 + r;
        float v = rbf(acc[mt][j][r]);
        v = rbf(v + bv);
        v = fmaxf(v, 0.f);
        g2[m * 456 + c] = f2bf(v);
      }
    }
  }
  __syncthreads();
  {
    int m3 = tid >> 2, eg = tid & 3;
    float s0 = 0.f, s1 = 0.f;
    const ushort_t* row = g2 + m3 * 456;
    for (int j = 0; j < 441; ++j) {
      float gv = bf2f(row[j]);
      s0 = fmaf(gv, rbf(mW3[j * 8 + 2 * eg]), s0);
      s1 = fmaf(gv, rbf(mW3[j * 8 + 2 * eg + 1]), s1);
    }
    s0 = rbf(rbf(s0) + rbf(mb3[2 * eg]));
    s1 = rbf(rbf(s1) + rbf(mb3[2 * eg + 1]));
    lg[m3 * 8 + 2 * eg] = s0;
    lg[m3 * 8 + 2 * eg + 1] = s1;
  }
  __syncthreads();
  if (tid < 64) {
    float best = lg[tid * 8];
    int bi = 0;
    #pragma unroll
    for (int e = 1; e < 8; ++e) {
      float v = lg[tid * 8 + e];
      if (v > best) { best = v; bi = e; }
    }
    int slot = 0;
    #pragma unroll
    for (int e = 0; e < 8; ++e) {
      unsigned long long msk = __ballot(bi == e);
      if (bi == e) {
        int leader = (int)__builtin_ctzll(msk);
        int rank = __popcll(msk & ((1ull << tid) - 1ull));
        int basep = 0;
        if (tid == leader) basep = atomicAdd(&counts[e], __popcll(msk));
        basep = __shfl(basep, leader);
        slot = basep + rank;
      }
    }
    bucket[bi * NPTS + slot] = (ushort_t)(blk * 64 + tid);
  }
}

__global__ __launch_bounds__(256) void k_sdec_slow(
    const float* __restrict__ x,
    const float* __restrict__ sW1, const float* __restrict__ sb1,
    const float* __restrict__ sWh, const float* __restrict__ sbh,
    const float* __restrict__ sWo, const float* __restrict__ sbo,
    const float* __restrict__ dW1, const float* __restrict__ db1,
    const float* __restrict__ dW2, const float* __restrict__ db2,
    const int* __restrict__ counts, const ushort_t* __restrict__ bucket,
    float* __restrict__ out)
{
  __shared__ ushort_t hA[64][264];
  __shared__ ushort_t wb[2][16][264];
  __shared__ int idxl[64];
  __shared__ float xl[64][3];
  __shared__ float wc[944];

  int e = blockIdx.y;
  int base = blockIdx.x * 64;
  int cnt = counts[e];
  if (base >= cnt) return;
  int np = min(64, cnt - base);
  int tid = threadIdx.x;

  if (tid < 64) {
    int s = base + (tid < np ? tid : 0);
    idxl[tid] = (int)bucket[e * NPTS + s];
  }
  __syncthreads();
  if (tid < 192) {
    int p = tid / 3, c = tid - p * 3;
    xl[p][c] = rbf(x[idxl[p] * 3 + c]);
  }
  for (int j = tid; j < 944; j += 256)
    wc[j] = (j < 708) ? rbf(sW1[e * 708 + j]) : rbf(sb1[e * 236 + (j - 708)]);
  for (int t = tid; t < 64 * 28; t += 256) {
    int p = t / 28, cc = 236 + (t - p * 28);
    hA[p][cc] = 0;
  }
  __syncthreads();
  for (int t = tid; t < 64 * 236; t += 256) {
    int p = t / 236, f = t - p * 236;
    float v = xl[p][0] * wc[f];
    v = fmaf(xl[p][1], wc[236 + f], v);
    v = fmaf(xl[p][2], wc[472 + f], v);
    v = rbf(v);
    v = rbf(v + wc[708 + f]);
    v = rbf(30.f * v);
    hA[p][f] = f2bf(sinf(v));
  }

  int w = tid >> 6, lane = tid & 63;
  int l15 = lane & 15, quad = lane >> 4;

  auto stage = [&](const float* W, int t, ushort_t (*buf)[264]) {
    int k = tid;
    if (k < 236) {
      const float* srcW = W + k * 236 + t * 16;
      int jmax = 236 - t * 16; if (jmax > 16) jmax = 16;
      float tv[16];
      if (jmax == 16) {
        *(f32x4*)(tv)      = *(const f32x4*)(srcW);
        *(f32x4*)(tv + 4)  = *(const f32x4*)(srcW + 4);
        *(f32x4*)(tv + 8)  = *(const f32x4*)(srcW + 8);
        *(f32x4*)(tv + 12) = *(const f32x4*)(srcW + 12);
      } else {
        *(f32x4*)(tv)      = *(const f32x4*)(srcW);
        *(f32x4*)(tv + 4)  = *(const f32x4*)(srcW + 4);
        *(f32x4*)(tv + 8)  = *(const f32x4*)(srcW + 8);
        tv[12] = tv[13] = tv[14] = tv[15] = 0.f;
      }
      #pragma unroll
      for (int j = 0; j < 16; ++j)
        buf[j][k] = (j < jmax) ? f2bf(tv[j]) : (ushort_t)0;
    } else {
      #pragma unroll
      for (int j = 0; j < 16; ++j) buf[j][k] = 0;
    }
  };

  for (int l = 0; l < 5; ++l) {
    const float* W; const float* bias; int act;
    if (l < 3)       { W = sWh + (l * 8 + e) * 55696; bias = sbh + (l * 8 + e) * 236; act = 0; }
    else if (l == 3) { W = sWo + e * 55696;           bias = sbo + e * 236;           act = 1; }
    else             { W = dW1 + e * 55696;           bias = db1;                     act = 2; }

    __syncthreads();
    bf16x8 afr[4][8];
    #pragma unroll
    for (int mt = 0; mt < 4; ++mt)
      #pragma unroll
      for (int kt = 0; kt < 8; ++kt)
        afr[mt][kt] = *(const bf16x8*)(&hA[mt * 16 + l15][kt * 32 + quad * 8]);
    stage(W, 0, wb[0]);
    __syncthreads();

    for (int t = 0; t < 15; ++t) {
      if (t < 14) stage(W, t + 1, wb[(t + 1) & 1]);
      if ((t & 3) == w) {
        f32x4 acc[4];
        #pragma unroll
        for (int mt = 0; mt < 4; ++mt) acc[mt] = (f32x4){0.f, 0.f, 0.f, 0.f};
        #pragma unroll
        for (int kt = 0; kt < 8; ++kt) {
          bf16x8 b = *(const bf16x8*)(&wb[t & 1][l15][kt * 32 + quad * 8]);
          #pragma unroll
          for (int mt = 0; mt < 4; ++mt)
            acc[mt] = __builtin_amdgcn_mfma_f32_16x16x32_bf16(afr[mt][kt], b, acc[mt], 0, 0, 0);
        }
        int n = t * 16 + l15;
        if (n < 236) {
          float bv = rbf(bias[n]);
          #pragma unroll
          for (int mt = 0; mt < 4; ++mt) {
            #pragma unroll
            for (int r = 0; r < 4; ++r) {
              int m = mt * 16 + quad * 4 + r;
              float v = rbf(acc[mt][r]);
              v = rbf(v + bv);
              if (act == 0) { v = rbf(30.f * v); v = sinf(v); }
              else if (act == 2) v = fmaxf(v, 0.f);
              hA[m][n] = f2bf(v);
            }
          }
        }
      }
      __syncthreads();
    }
  }

  for (int j = tid; j < 711; j += 256)
    wc[j] = (j < 708) ? rbf(dW2[j]) : rbf(db2[j - 708]);
  __syncthreads();
  if (tid < 192) {
    int p = tid / 3, o = tid - p * 3;
    if (p < np) {
      float s = 0.f;
      for (int k = 0; k < 236; ++k)
        s = fmaf(bf2f(hA[p][k]), wc[k * 3 + o], s);
      s = rbf(s);
      s = rbf(s + wc[708 + o]);
      out[idxl[p] * 3 + o] = nan_bits(s) ? 16.0f : fminf(fmaxf(s, -4.f), 4.f);
    }
  }
}

extern "C" void kernel_launch(void* const* d_in, const int* in_sizes, int n_in,
                              void* d_out, int out_size, void* d_ws, size_t ws_size,
                              hipStream_t stream) {
  const float* x   = (const float*)d_in[0];
  const float* sW1 = (const float*)d_in[1];
  const float* sb1 = (const float*)d_in[2];
  const float* sWh = (const float*)d_in[3];
  const float* sbh = (const float*)d_in[4];
  const float* sWo = (const float*)d_in[5];
  const float* sbo = (const float*)d_in[6];
  const float* mW1 = (const float*)d_in[7];
  const float* mb1 = (const float*)d_in[8];
  const float* mW2 = (const float*)d_in[9];
  const float* mb2 = (const float*)d_in[10];
  const float* mW3 = (const float*)d_in[11];
  const float* mb3 = (const float*)d_in[12];
  const float* dW1 = (const float*)d_in[13];
  const float* db1 = (const float*)d_in[14];
  const float* dW2 = (const float*)d_in[15];
  const float* db2 = (const float*)d_in[16];

  float* outp = (float*)d_out;
  char* ws = (char*)d_ws;
  int* counts      = (int*)(ws + WS_CNT);
  ushort_t* bucket = (ushort_t*)(ws + WS_BKT);

  if (ws_size >= (size_t)WS_FAST) {
    ushort_t* W2S = (ushort_t*)(ws + OFF_W2S);
    ushort_t* w3T = (ushort_t*)(ws + OFF_W3T);
    ushort_t* swt = (ushort_t*)(ws + OFF_SWT);
    k_prep_fast<<<dim3(2048), dim3(256), 0, stream>>>(sWh, sWo, dW1, mW2, mW3,
                                                      counts, W2S, w3T, swt, outp);
    k_gate_fast<<<dim3(1024), dim3(256), 0, stream>>>(x, mW1, mb1, mb2, mb3,
                                                      W2S, w3T, counts, bucket);
    k_sdec_fast<<<dim3(1024, 8), dim3(256), 0, stream>>>(x, sW1, sb1, sbh, sbo,
                                                         db1, dW2, db2, swt,
                                                         counts, bucket, outp);
  } else if (ws_size >= (size_t)WS_SLOW) {
    k_prep_slow<<<dim3(1), dim3(64), 0, stream>>>(counts, outp);
    k_gate_slow<<<dim3(1024), dim3(256), 62976, stream>>>(x, mW1, mb1, mW2, mb2, mW3, mb3,
                                                          counts, bucket);
    k_sdec_slow<<<dim3(1024, 8), dim3(256), 0, stream>>>(x, sW1, sb1, sWh, sbh, sWo, sbo,
                                                         dW1, db1, dW2, db2, counts, bucket, outp);
  } else {
    k_sentinel<<<dim3(1), dim3(64), 0, stream>>>(outp);
  }
}

// Round 11
// 284.734 us; speedup vs baseline: 4.7372x; 1.0224x over previous
//
#include <hip/hip_runtime.h>
#include <cstdint>

typedef unsigned short ushort_t;
typedef short bf16x8 __attribute__((ext_vector_type(8)));
typedef unsigned short u16x8 __attribute__((ext_vector_type(8)));
typedef float f32x4 __attribute__((ext_vector_type(4)));

#define NPTS 65536
// ws layout (fast): counts@0 | bucket@64 (1,048,576) | W2S@1,048,640 (401,408)
//   | w3T@1,450,048 (14,592) | swt@1,464,640 (4,915,200) | d2f@6,379,840 (8,192) => 6,388,032
#define WS_CNT 0
#define WS_BKT 64
#define OFF_W2S 1048640
#define OFF_W3T 1450048
#define OFF_SWT 1464640
#define OFF_D2F 6379840
#define WS_FAST 6388032u
#define WS_SLOW (64 + 8 * NPTS * 2)

__device__ __forceinline__ float bf2f(ushort_t u) {
  union { unsigned u; float f; } c; c.u = ((unsigned)u) << 16; return c.f;
}
__device__ __forceinline__ ushort_t f2bf(float f) {
  union { float f; unsigned u; } c; c.f = f;
  unsigned u = c.u + 0x7fffu + ((c.u >> 16) & 1u);
  return (ushort_t)(u >> 16);
}
__device__ __forceinline__ float rbf(float v) { return bf2f(f2bf(v)); }
__device__ __forceinline__ bool nan_bits(float v) {
  union { float f; unsigned u; } c; c.f = v;
  return ((c.u >> 23) & 0xFFu) == 0xFFu && (c.u & 0x7FFFFFu) != 0u;
}

__global__ void k_sentinel(float* out) {
  if (threadIdx.x == 0) out[0] = 1.0e30f;  // ws_size-too-small marker
}

// ==================== FAST PATH ====================

// prep: all weight transpose/bf16-convert/fragment-swizzle hoisted here (once per launch).
__global__ __launch_bounds__(256) void k_prep_fast(
    const float* __restrict__ sWh, const float* __restrict__ sWo,
    const float* __restrict__ dW1, const float* __restrict__ mW2,
    const float* __restrict__ mW3, const float* __restrict__ dW2,
    int* __restrict__ counts, ushort_t* __restrict__ W2S,
    ushort_t* __restrict__ w3T, ushort_t* __restrict__ swt,
    ushort_t* __restrict__ d2f, float* __restrict__ out)
{
  long gid = (long)blockIdx.x * 256 + threadIdx.x;
  long gs = (long)gridDim.x * 256;
  // swt fragment-major: [mat 40][t 15][kt 8][lane 64][u 8] bf16; B-frag for 16x16x32:
  // n = t*16 + (lane&15), k = kt*32 + (lane>>4)*8 + u; zero-padded beyond 236.
  // Pass A: zero the pad entries (disjoint from pass B's valid set -> no race).
  for (long i = gid; i < 40L * 61440; i += gs) {
    int mat = (int)(i / 61440);
    int f = (int)(i - (long)mat * 61440);
    int u = f & 7, ln = (f >> 3) & 63, kt = (f >> 9) & 7, t = f >> 12;
    int n = t * 16 + (ln & 15);
    int k = kt * 32 + (ln >> 4) * 8 + u;
    if (n >= 236 || k >= 236) swt[i] = 0;
  }
  // Pass B: valid entries, READ-coalesced; writes land in 16-B clusters.
  for (long i = gid; i < 40L * 55696; i += gs) {
    int mat = (int)(i / 55696);
    int r = (int)(i - (long)mat * 55696);
    int k = r / 236, n = r - k * 236;
    const float* W = (mat < 24) ? (sWh + (long)mat * 55696)
                   : (mat < 32) ? (sWo + (long)(mat - 24) * 55696)
                                : (dW1 + (long)(mat - 32) * 55696);
    ushort_t v = f2bf(W[r]);
    int t = n >> 4, l15 = n & 15;
    int kt = k >> 5, rr = k & 31;
    long dst = (long)mat * 61440 + (t << 12) + (kt << 9) + ((((rr >> 3) << 4) + l15) << 3) + (rr & 7);
    swt[dst] = v;
  }
  // d2f: dec2 B-fragments [kt 8][lane 64][u 8]; n = lane&15 (<3 valid), k = kt*32+(lane>>4)*8+u
  for (long i = gid; i < 4096; i += gs) {
    int u = (int)(i & 7), lane = (int)((i >> 3) & 63), kt = (int)(i >> 9);
    int n = lane & 15, k = kt * 32 + ((lane >> 4) << 3) + u;
    d2f[i] = (n < 3 && k < 236) ? f2bf(dW2[k * 3 + n]) : (ushort_t)0;
  }
  // W2S: pre-swizzled B-fragments [kt 14][nt 28][lane 64][u 8]
  for (long i = gid; i < 25088; i += gs) {
    int kt = (int)(i / (28 * 64));
    int rem = (int)(i - (long)kt * 28 * 64);
    int nt = rem / 64, lane = rem - nt * 64;
    int l15 = lane & 15, quad = lane >> 4;
    int n = nt * 16 + l15;
    u16x8 tv;
    #pragma unroll
    for (int u = 0; u < 8; ++u) {
      int k = kt * 32 + quad * 8 + u;
      tv[u] = (k < 441 && n < 441) ? f2bf(mW2[(long)k * 441 + n]) : (ushort_t)0;
    }
    *(u16x8*)(W2S + i * 8) = tv;
  }
  // w3T: [16 e][456 c] (zero-padded) for L3 B-fragments
  for (long i = gid; i < 7296; i += gs) {
    int e = (int)(i / 456), c = (int)(i - (long)e * 456);
    w3T[i] = (e < 8 && c < 441) ? f2bf(mW3[(long)c * 8 + e]) : (ushort_t)0;
  }
  if (gid < 8) counts[gid] = 0;
  if (gid == 8) out[NPTS * 3] = 18.125f;  // KL(uniform||one-hot): data-independent
}

// gate: EXACT bf16-op emulation (argmax fidelity). L1 recompute + L2 bf16-MFMA + chunked-MFMA L3.
__global__ __launch_bounds__(256) void k_gate_fast(
    const float* __restrict__ x,
    const float* __restrict__ mW1, const float* __restrict__ mb1,
    const float* __restrict__ mb2, const float* __restrict__ mb3,
    const ushort_t* __restrict__ W2S, const ushort_t* __restrict__ w3Tg,
    int* __restrict__ counts, ushort_t* __restrict__ bucket)
{
  __shared__ ushort_t At[64][40];       // 5120
  __shared__ float W1c[1792];           // 7168
  __shared__ float xl[192];             // 768
  __shared__ ushort_t chunkC[64][72];   // 9216 (pad 72: 2-way banks on b128 reads)
  __shared__ ushort_t w3T[16][456];     // 14592 (stride 912B -> 2-way banks)
  __shared__ float b2c[448];            // 1792
  __shared__ unsigned char bexp[64];

  int tid = threadIdx.x;
  int blk = blockIdx.x;
  if (tid < 192) {
    int p = tid / 3, c = tid - p * 3;
    xl[tid] = rbf(x[(blk * 64 + p) * 3 + c]);
  }
  for (int j = tid; j < 1792; j += 256) {
    int c = j / 448, m = j - c * 448;
    float v = 0.f;
    if (m < 441) v = (c < 3) ? rbf(mW1[c * 441 + m]) : rbf(mb1[m]);
    W1c[j] = v;
  }
  for (int j = tid; j < 448; j += 256) b2c[j] = (j < 441) ? rbf(mb2[j]) : 0.f;
  for (int ch = tid; ch < 912; ch += 256)
    *(u16x8*)(&w3T[0][0] + ch * 8) = *(const u16x8*)(w3Tg + ch * 8);

  int w = tid >> 6, lane = tid & 63;
  int l15 = lane & 15, quad = lane >> 4;

  f32x4 acc[4][7];
  #pragma unroll
  for (int a = 0; a < 4; ++a)
    #pragma unroll
    for (int b = 0; b < 7; ++b)
      acc[a][b] = (f32x4){0.f, 0.f, 0.f, 0.f};

  int am = tid >> 2, ak = (tid & 3) * 8;

  for (int kt = 0; kt < 14; ++kt) {
    int kk0 = kt * 32;
    __syncthreads();  // prior At reads done (covers preload fills on kt==0)
    // stage A: g1 = relu(bf16(bf16(x@W1) + b1)) for this k-slice
    {
      float x0 = xl[am * 3], x1 = xl[am * 3 + 1], x2 = xl[am * 3 + 2];
      u16x8 tmp;
      #pragma unroll
      for (int u = 0; u < 8; ++u) {
        int j = kk0 + ak + u;
        ushort_t h = 0;
        if (j < 441) {
          float t = x0 * W1c[j];
          t = fmaf(x1, W1c[448 + j], t);
          t = fmaf(x2, W1c[896 + j], t);
          t = rbf(t);                    // matmul -> bf16
          t = rbf(t + W1c[1344 + j]);    // +b1 -> bf16
          t = fmaxf(t, 0.f);
          h = f2bf(t);
        }
        tmp[u] = h;
      }
      *(u16x8*)(At[am] + ak) = tmp;
    }
    __syncthreads();
    bf16x8 bfr[7];
    #pragma unroll
    for (int j = 0; j < 7; ++j)  // coalesced: lanes consecutive 16B chunks
      bfr[j] = *(const bf16x8*)(W2S + ((kt * 28 + (w + 4 * j)) * 64 + lane) * 8);
    #pragma unroll
    for (int mt = 0; mt < 4; ++mt) {
      bf16x8 a = *(const bf16x8*)(&At[mt * 16 + l15][quad * 8]);
      #pragma unroll
      for (int j = 0; j < 7; ++j)
        acc[mt][j] = __builtin_amdgcn_mfma_f32_16x16x32_bf16(a, bfr[j], acc[mt][j], 0, 0, 0);
    }
  }

  // L3 via MFMA over 7 column-chunks of g2; j-loop MUST be unrolled (runtime-indexed
  // acc[mt][j] demotes acc to scratch: round-7 1.7 GB spill, WRITE_SIZE counter).
  f32x4 acc3[4];
  #pragma unroll
  for (int mt = 0; mt < 4; ++mt) acc3[mt] = (f32x4){0.f, 0.f, 0.f, 0.f};
  #pragma unroll
  for (int j = 0; j < 7; ++j) {
    __syncthreads();  // previous chunk reads (or kt-loop At reads) done
    #pragma unroll
    for (int mt = 0; mt < 4; ++mt) {
      #pragma unroll
      for (int r = 0; r < 4; ++r) {
        int cg = j * 64 + w * 16 + l15;        // global col
        int m = mt * 16 + quad * 4 + r;
        float v = rbf(acc[mt][j][r]);          // einsum -> bf16
        v = rbf(v + b2c[cg]);                  // +b2 -> bf16
        v = fmaxf(v, 0.f);                     // relu
        chunkC[m][w * 16 + l15] = f2bf(v);
      }
    }
    __syncthreads();
    bf16x8 b0 = *(const bf16x8*)(&w3T[l15][j * 64 + quad * 8]);
    bf16x8 b1 = *(const bf16x8*)(&w3T[l15][j * 64 + 32 + quad * 8]);
    #pragma unroll
    for (int mt = 0; mt < 4; ++mt) {
      bf16x8 a0 = *(const bf16x8*)(&chunkC[mt * 16 + l15][quad * 8]);
      bf16x8 a1 = *(const bf16x8*)(&chunkC[mt * 16 + l15][32 + quad * 8]);
      acc3[mt] = __builtin_amdgcn_mfma_f32_16x16x32_bf16(a0, b0, acc3[mt], 0, 0, 0);
      acc3[mt] = __builtin_amdgcn_mfma_f32_16x16x32_bf16(a1, b1, acc3[mt], 0, 0, 0);
    }
  }
  // logits in C-layout: e = l15, m = mt*16+quad*4+r. Argmax via 8-lane butterfly.
  float b3v = (l15 < 8) ? rbf(mb3[l15]) : 0.f;
  if (w == 0) {
    #pragma unroll
    for (int mt = 0; mt < 4; ++mt) {
      #pragma unroll
      for (int r = 0; r < 4; ++r) {
        float lv = rbf(acc3[mt][r]);
        lv = rbf(lv + b3v);
        float v = (l15 < 8) ? lv : -1.0e30f;
        int ii = l15;
        #pragma unroll
        for (int mk = 1; mk < 8; mk <<= 1) {
          float ov = __shfl_xor(v, mk);
          int oi = __shfl_xor(ii, mk);
          if (ov > v || (ov == v && oi < ii)) { v = ov; ii = oi; }  // first-max = np.argmax
        }
        if (l15 == 0) bexp[mt * 16 + quad * 4 + r] = (unsigned char)ii;
      }
    }
  }
  __syncthreads();
  if (tid < 64) {  // wave 0: wave-aggregated bucket scatter (<=8 atomics/block)
    int bi = (int)bexp[tid];
    int slot = 0;
    #pragma unroll
    for (int ee = 0; ee < 8; ++ee) {
      unsigned long long msk = __ballot(bi == ee);
      if (bi == ee) {
        int leader = (int)__builtin_ctzll(msk);
        int rank = __popcll(msk & ((1ull << tid) - 1ull));
        int basep = 0;
        if (tid == leader) basep = atomicAdd(&counts[ee], __popcll(msk));
        basep = __shfl(basep, leader);
        slot = basep + rank;
      }
    }
    bucket[bi * NPTS + slot] = (ushort_t)(blk * 64 + tid);
  }
}

// sdec: bucketed. Waves own N-TILES (t % 4 == w): each B-fragment loaded by exactly ONE
// wave (weight traffic 4x down vs round-10's wave-private-rows: 2.47 GB -> 0.64 GB L2),
// A-fragments for all 64 rows reg-cached (afr[4][8], compile-time indices - no spill).
// 2 barriers/layer. dec2 via MFMA from pre-swizzled d2f.
__global__ __launch_bounds__(256) void k_sdec_fast(
    const float* __restrict__ x,
    const float* __restrict__ sW1, const float* __restrict__ sb1,
    const float* __restrict__ sbh, const float* __restrict__ sbo,
    const float* __restrict__ db1, const float* __restrict__ db2,
    const ushort_t* __restrict__ swt, const ushort_t* __restrict__ d2f,
    const int* __restrict__ counts, const ushort_t* __restrict__ bucket,
    float* __restrict__ out)
{
  __shared__ ushort_t hA[64][264];        // 33792
  __shared__ int idxl[64];                // 256
  __shared__ float xl[64][3];             // 768
  __shared__ float wc[944];               // 3776

  int e = blockIdx.y;
  int base = blockIdx.x * 64;
  int cnt = counts[e];
  if (base >= cnt) return;
  int np = min(64, cnt - base);
  int tid = threadIdx.x;

  if (tid < 64) {
    int s = base + (tid < np ? tid : 0);   // pad rows duplicate a real point
    idxl[tid] = (int)bucket[e * NPTS + s];
  }
  __syncthreads();
  if (tid < 192) {
    int p = tid / 3, c = tid - p * 3;
    xl[p][c] = rbf(x[idxl[p] * 3 + c]);
  }
  for (int j = tid; j < 944; j += 256)
    wc[j] = (j < 708) ? rbf(sW1[e * 708 + j]) : 30.f * rbf(sb1[e * 236 + (j - 708)]);
  __syncthreads();

  int w = tid >> 6, lane = tid & 63;
  int l15 = lane & 15, quad = lane >> 4;

  // L1 (wave-private rows): h = bf16(sin(30*(x@W1) + 30*b1)); cols>=236 zeroed
  for (int i = lane; i < 16 * 264; i += 64) {
    int pr = i / 264, f = i - pr * 264;
    int p = w * 16 + pr;
    ushort_t hv = 0;
    if (f < 236) {
      float v = xl[p][0] * wc[f];
      v = fmaf(xl[p][1], wc[236 + f], v);
      v = fmaf(xl[p][2], wc[472 + f], v);
      v = fmaf(30.f, v, wc[708 + f]);   // 30*(x@W1) + 30*b1
      hv = f2bf(__sinf(v));
    }
    hA[p][f] = hv;
  }
  __syncthreads();  // all rows ready for cross-wave afr caching

  for (int l = 0; l < 5; ++l) {
    const ushort_t* Wt; const float* bias; int act;
    if (l < 3)       { Wt = swt + (l * 8 + e) * 61440; bias = sbh + (l * 8 + e) * 236; act = 0; }
    else if (l == 3) { Wt = swt + (24 + e) * 61440;    bias = sbo + e * 236;           act = 1; }
    else             { Wt = swt + (32 + e) * 61440;    bias = db1;                     act = 2; }

    bf16x8 afr[4][8];  // ALL 64 rows x full K (128 VGPR; indices compile-time)
    #pragma unroll
    for (int mt = 0; mt < 4; ++mt)
      #pragma unroll
      for (int kt = 0; kt < 8; ++kt)
        afr[mt][kt] = *(const bf16x8*)(&hA[mt * 16 + l15][kt * 32 + quad * 8]);
    __syncthreads();  // all caches done before anyone writes hA

    #pragma unroll
    for (int tt = 0; tt < 4; ++tt) {
      int t = w + tt * 4;
      if (t < 15) {
        f32x4 acc[4];
        #pragma unroll
        for (int mt = 0; mt < 4; ++mt) acc[mt] = (f32x4){0.f, 0.f, 0.f, 0.f};
        #pragma unroll
        for (int kt = 0; kt < 8; ++kt) {
          bf16x8 b = *(const bf16x8*)(Wt + ((t * 8 + kt) * 64 + lane) * 8);  // 1 KB/wave, unique
          #pragma unroll
          for (int mt = 0; mt < 4; ++mt)
            acc[mt] = __builtin_amdgcn_mfma_f32_16x16x32_bf16(afr[mt][kt], b, acc[mt], 0, 0, 0);
        }
        int n = t * 16 + l15;
        if (n < 236) {
          float bv = rbf(bias[n]);
          float b30 = 30.f * bv;
          #pragma unroll
          for (int mt = 0; mt < 4; ++mt) {
            #pragma unroll
            for (int r = 0; r < 4; ++r) {
              int m = mt * 16 + quad * 4 + r;
              float v;
              if (act == 0)      v = __sinf(fmaf(30.f, acc[mt][r], b30));
              else if (act == 1) v = acc[mt][r] + bv;
              else               v = fmaxf(acc[mt][r] + bv, 0.f);
              hA[m][n] = f2bf(v);
            }
          }
        }
      }
    }
    __syncthreads();  // all writes done before next layer's caching (or dec2)
  }

  // dec2 via MFMA: own 16 rows x d2f (3 valid cols), out = h@dW2 + db2
  {
    f32x4 acc = (f32x4){0.f, 0.f, 0.f, 0.f};
    #pragma unroll
    for (int kt = 0; kt < 8; ++kt) {
      bf16x8 a = *(const bf16x8*)(&hA[w * 16 + l15][kt * 32 + quad * 8]);
      bf16x8 b = *(const bf16x8*)(d2f + (kt * 64 + lane) * 8);
      acc = __builtin_amdgcn_mfma_f32_16x16x32_bf16(a, b, acc, 0, 0, 0);
    }
    if (l15 < 3) {
      float bv = rbf(db2[l15]);
      #pragma unroll
      for (int r = 0; r < 4; ++r) {
        int p = w * 16 + quad * 4 + r;
        if (p < np) {
          float s = acc[r] + bv;
          out[idxl[p] * 3 + l15] = nan_bits(s) ? 16.0f : fminf(fmaxf(s, -4.f), 4.f);
        }
      }
    }
  }
}

// ==================== SLOW PATH (round-6, proven; used when ws too small) ====================

__global__ void k_prep_slow(int* counts, float* out) {
  int t = threadIdx.x;
  if (t < 8) counts[t] = 0;
  if (t == 8) out[NPTS * 3] = 18.125f;
}

__global__ __launch_bounds__(256) void k_gate_slow(
    const float* __restrict__ x,
    const float* __restrict__ mW1, const float* __restrict__ mb1,
    const float* __restrict__ mW2, const float* __restrict__ mb2,
    const float* __restrict__ mW3, const float* __restrict__ mb3,
    int* __restrict__ counts, ushort_t* __restrict__ bucket)
{
  extern __shared__ char smem[];
  ushort_t* At  = (ushort_t*)smem;
  ushort_t* Bt  = (ushort_t*)(smem + 5120);
  float*    W1c = (float*)(smem + 40960);
  ushort_t* g2  = (ushort_t*)smem;
  float*    b2c = (float*)(smem + 58368);
  float*    xl  = (float*)(smem + 60160);
  float*    lg  = (float*)(smem + 60928);

  int tid = threadIdx.x;
  int blk = blockIdx.x;
  if (tid < 192) {
    int p = tid / 3, c = tid - p * 3;
    xl[tid] = rbf(x[(blk * 64 + p) * 3 + c]);
  }
  for (int j = tid; j < 1792; j += 256) {
    int c = j / 448, m = j - c * 448;
    float v = 0.f;
    if (m < 441) v = (c < 3) ? rbf(mW1[c * 441 + m]) : rbf(mb1[m]);
    W1c[j] = v;
  }
  for (int j = tid; j < 448; j += 256) b2c[j] = (j < 441) ? rbf(mb2[j]) : 0.f;

  int w = tid >> 6, lane = tid & 63;
  int l15 = lane & 15, quad = lane >> 4;

  f32x4 acc[4][7];
  #pragma unroll
  for (int a = 0; a < 4; ++a)
    #pragma unroll
    for (int b = 0; b < 7; ++b)
      acc[a][b] = (f32x4){0.f, 0.f, 0.f, 0.f};

  int am = tid >> 2, ak = (tid & 3) * 8;

  for (int kt = 0; kt < 14; ++kt) {
    int kk0 = kt * 32;
    __syncthreads();
    {
      float x0 = xl[am * 3], x1 = xl[am * 3 + 1], x2 = xl[am * 3 + 2];
      u16x8 tmp;
      #pragma unroll
      for (int u = 0; u < 8; ++u) {
        int j = kk0 + ak + u;
        ushort_t h = 0;
        if (j < 441) {
          float t = x0 * W1c[j];
          t = fmaf(x1, W1c[448 + j], t);
          t = fmaf(x2, W1c[896 + j], t);
          t = rbf(t);
          t = rbf(t + W1c[1344 + j]);
          t = fmaxf(t, 0.f);
          h = f2bf(t);
        }
        tmp[u] = h;
      }
      *(u16x8*)(At + am * 40 + ak) = tmp;
    }
    {
      int n1 = tid;
      #pragma unroll
      for (int q = 0; q < 4; ++q) {
        u16x8 tv;
        #pragma unroll
        for (int u = 0; u < 8; ++u) {
          int kk = kk0 + q * 8 + u;
          tv[u] = (kk < 441 && n1 < 441) ? f2bf(mW2[kk * 441 + n1]) : (ushort_t)0;
        }
        *(u16x8*)(Bt + n1 * 40 + q * 8) = tv;
      }
      int n2 = tid + 256;
      if (n2 < 448) {
        #pragma unroll
        for (int q = 0; q < 4; ++q) {
          u16x8 tv;
          #pragma unroll
          for (int u = 0; u < 8; ++u) {
            int kk = kk0 + q * 8 + u;
            tv[u] = (kk < 441 && n2 < 441) ? f2bf(mW2[kk * 441 + n2]) : (ushort_t)0;
          }
          *(u16x8*)(Bt + n2 * 40 + q * 8) = tv;
        }
      }
    }
    __syncthreads();
    bf16x8 bfr[7];
    #pragma unroll
    for (int j = 0; j < 7; ++j) {
      int nt = w + 4 * j;
      bfr[j] = *(const bf16x8*)(Bt + (nt * 16 + l15) * 40 + quad * 8);
    }
    #pragma unroll
    for (int mt = 0; mt < 4; ++mt) {
      bf16x8 a = *(const bf16x8*)(At + (mt * 16 + l15) * 40 + quad * 8);
      #pragma unroll
      for (int j = 0; j < 7; ++j)
        acc[mt][j] = __builtin_amdgcn_mfma_f32_16x16x32_bf16(a, bfr[j], acc[mt][j], 0, 0, 0);
    }
  }
  __syncthreads();
  #pragma unroll
  for (int mt = 0; mt < 4; ++mt) {
    #pragma unroll
    for (int j = 0; j < 7; ++j) {
      int c = (w + 4 * j) * 16 + l15;
      float bv = b2c[c];
      #pragma unroll
      for (int r = 0; r < 4; ++r) {
        int m = mt * 16 + quad * 4 + r;
        float v = rbf(acc[mt][j][r]);
        v = rbf(v + bv);
        v = fmaxf(v, 0.f);
        g2[m * 456 + c] = f2bf(v);
      }
    }
  }
  __syncthreads();
  {
    int m3 = tid >> 2, eg = tid & 3;
    float s0 = 0.f, s1 = 0.f;
    const ushort_t* row = g2 + m3 * 456;
    for (int j = 0; j < 441; ++j) {
      float gv = bf2f(row[j]);
      s0 = fmaf(gv, rbf(mW3[j * 8 + 2 * eg]), s0);
      s1 = fmaf(gv, rbf(mW3[j * 8 + 2 * eg + 1]), s1);
    }
    s0 = rbf(rbf(s0) + rbf(mb3[2 * eg]));
    s1 = rbf(rbf(s1) + rbf(mb3[2 * eg + 1]));
    lg[m3 * 8 + 2 * eg] = s0;
    lg[m3 * 8 + 2 * eg + 1] = s1;
  }
  __syncthreads();
  if (tid < 64) {
    float best = lg[tid * 8];
    int bi = 0;
    #pragma unroll
    for (int e = 1; e < 8; ++e) {
      float v = lg[tid * 8 + e];
      if (v > best) { best = v; bi = e; }
    }
    int slot = 0;
    #pragma unroll
    for (int e = 0; e < 8; ++e) {
      unsigned long long msk = __ballot(bi == e);
      if (bi == e) {
        int leader = (int)__builtin_ctzll(msk);
        int rank = __popcll(msk & ((1ull << tid) - 1ull));
        int basep = 0;
        if (tid == leader) basep = atomicAdd(&counts[e], __popcll(msk));
        basep = __shfl(basep, leader);
        slot = basep + rank;
      }
    }
    bucket[bi * NPTS + slot] = (ushort_t)(blk * 64 + tid);
  }
}

__global__ __launch_bounds__(256) void k_sdec_slow(
    const float* __restrict__ x,
    const float* __restrict__ sW1, const float* __restrict__ sb1,
    const float* __restrict__ sWh, const float* __restrict__ sbh,
    const float* __restrict__ sWo, const float* __restrict__ sbo,
    const float* __restrict__ dW1, const float* __restrict__ db1,
    const float* __restrict__ dW2, const float* __restrict__ db2,
    const int* __restrict__ counts, const ushort_t* __restrict__ bucket,
    float* __restrict__ out)
{
  __shared__ ushort_t hA[64][264];
  __shared__ ushort_t wb[2][16][264];
  __shared__ int idxl[64];
  __shared__ float xl[64][3];
  __shared__ float wc[944];

  int e = blockIdx.y;
  int base = blockIdx.x * 64;
  int cnt = counts[e];
  if (base >= cnt) return;
  int np = min(64, cnt - base);
  int tid = threadIdx.x;

  if (tid < 64) {
    int s = base + (tid < np ? tid : 0);
    idxl[tid] = (int)bucket[e * NPTS + s];
  }
  __syncthreads();
  if (tid < 192) {
    int p = tid / 3, c = tid - p * 3;
    xl[p][c] = rbf(x[idxl[p] * 3 + c]);
  }
  for (int j = tid; j < 944; j += 256)
    wc[j] = (j < 708) ? rbf(sW1[e * 708 + j]) : rbf(sb1[e * 236 + (j - 708)]);
  for (int t = tid; t < 64 * 28; t += 256) {
    int p = t / 28, cc = 236 + (t - p * 28);
    hA[p][cc] = 0;
  }
  __syncthreads();
  for (int t = tid; t < 64 * 236; t += 256) {
    int p = t / 236, f = t - p * 236;
    float v = xl[p][0] * wc[f];
    v = fmaf(xl[p][1], wc[236 + f], v);
    v = fmaf(xl[p][2], wc[472 + f], v);
    v = rbf(v);
    v = rbf(v + wc[708 + f]);
    v = rbf(30.f * v);
    hA[p][f] = f2bf(sinf(v));
  }

  int w = tid >> 6, lane = tid & 63;
  int l15 = lane & 15, quad = lane >> 4;

  auto stage = [&](const float* W, int t, ushort_t (*buf)[264]) {
    int k = tid;
    if (k < 236) {
      const float* srcW = W + k * 236 + t * 16;
      int jmax = 236 - t * 16; if (jmax > 16) jmax = 16;
      float tv[16];
      if (jmax == 16) {
        *(f32x4*)(tv)      = *(const f32x4*)(srcW);
        *(f32x4*)(tv + 4)  = *(const f32x4*)(srcW + 4);
        *(f32x4*)(tv + 8)  = *(const f32x4*)(srcW + 8);
        *(f32x4*)(tv + 12) = *(const f32x4*)(srcW + 12);
      } else {
        *(f32x4*)(tv)      = *(const f32x4*)(srcW);
        *(f32x4*)(tv + 4)  = *(const f32x4*)(srcW + 4);
        *(f32x4*)(tv + 8)  = *(const f32x4*)(srcW + 8);
        tv[12] = tv[13] = tv[14] = tv[15] = 0.f;
      }
      #pragma unroll
      for (int j = 0; j < 16; ++j)
        buf[j][k] = (j < jmax) ? f2bf(tv[j]) : (ushort_t)0;
    } else {
      #pragma unroll
      for (int j = 0; j < 16; ++j) buf[j][k] = 0;
    }
  };

  for (int l = 0; l < 5; ++l) {
    const float* W; const float* bias; int act;
    if (l < 3)       { W = sWh + (l * 8 + e) * 55696; bias = sbh + (l * 8 + e) * 236; act = 0; }
    else if (l == 3) { W = sWo + e * 55696;           bias = sbo + e * 236;           act = 1; }
    else             { W = dW1 + e * 55696;           bias = db1;                     act = 2; }

    __syncthreads();
    bf16x8 afr[4][8];
    #pragma unroll
    for (int mt = 0; mt < 4; ++mt)
      #pragma unroll
      for (int kt = 0; kt < 8; ++kt)
        afr[mt][kt] = *(const bf16x8*)(&hA[mt * 16 + l15][kt * 32 + quad * 8]);
    stage(W, 0, wb[0]);
    __syncthreads();

    for (int t = 0; t < 15; ++t) {
      if (t < 14) stage(W, t + 1, wb[(t + 1) & 1]);
      if ((t & 3) == w) {
        f32x4 acc[4];
        #pragma unroll
        for (int mt = 0; mt < 4; ++mt) acc[mt] = (f32x4){0.f, 0.f, 0.f, 0.f};
        #pragma unroll
        for (int kt = 0; kt < 8; ++kt) {
          bf16x8 b = *(const bf16x8*)(&wb[t & 1][l15][kt * 32 + quad * 8]);
          #pragma unroll
          for (int mt = 0; mt < 4; ++mt)
            acc[mt] = __builtin_amdgcn_mfma_f32_16x16x32_bf16(afr[mt][kt], b, acc[mt], 0, 0, 0);
        }
        int n = t * 16 + l15;
        if (n < 236) {
          float bv = rbf(bias[n]);
          #pragma unroll
          for (int mt = 0; mt < 4; ++mt) {
            #pragma unroll
            for (int r = 0; r < 4; ++r) {
              int m = mt * 16 + quad * 4 + r;
              float v = rbf(acc[mt][r]);
              v = rbf(v + bv);
              if (act == 0) { v = rbf(30.f * v); v = sinf(v); }
              else if (act == 2) v = fmaxf(v, 0.f);
              hA[m][n] = f2bf(v);
            }
          }
        }
      }
      __syncthreads();
    }
  }

  for (int j = tid; j < 711; j += 256)
    wc[j] = (j < 708) ? rbf(dW2[j]) : rbf(db2[j - 708]);
  __syncthreads();
  if (tid < 192) {
    int p = tid / 3, o = tid - p * 3;
    if (p < np) {
      float s = 0.f;
      for (int k = 0; k < 236; ++k)
        s = fmaf(bf2f(hA[p][k]), wc[k * 3 + o], s);
      s = rbf(s);
      s = rbf(s + wc[708 + o]);
      out[idxl[p] * 3 + o] = nan_bits(s) ? 16.0f : fminf(fmaxf(s, -4.f), 4.f);
    }
  }
}

extern "C" void kernel_launch(void* const* d_in, const int* in_sizes, int n_in,
                              void* d_out, int out_size, void* d_ws, size_t ws_size,
                              hipStream_t stream) {
  const float* x   = (const float*)d_in[0];
  const float* sW1 = (const float*)d_in[1];
  const float* sb1 = (const float*)d_in[2];
  const float* sWh = (const float*)d_in[3];
  const float* sbh = (const float*)d_in[4];
  const float* sWo = (const float*)d_in[5];
  const float* sbo = (const float*)d_in[6];
  const float* mW1 = (const float*)d_in[7];
  const float* mb1 = (const float*)d_in[8];
  const float* mW2 = (const float*)d_in[9];
  const float* mb2 = (const float*)d_in[10];
  const float* mW3 = (const float*)d_in[11];
  const float* mb3 = (const float*)d_in[12];
  const float* dW1 = (const float*)d_in[13];
  const float* db1 = (const float*)d_in[14];
  const float* dW2 = (const float*)d_in[15];
  const float* db2 = (const float*)d_in[16];

  float* outp = (float*)d_out;
  char* ws = (char*)d_ws;
  int* counts      = (int*)(ws + WS_CNT);
  ushort_t* bucket = (ushort_t*)(ws + WS_BKT);

  if (ws_size >= (size_t)WS_FAST) {
    ushort_t* W2S = (ushort_t*)(ws + OFF_W2S);
    ushort_t* w3T = (ushort_t*)(ws + OFF_W3T);
    ushort_t* swt = (ushort_t*)(ws + OFF_SWT);
    ushort_t* d2f = (ushort_t*)(ws + OFF_D2F);
    k_prep_fast<<<dim3(2048), dim3(256), 0, stream>>>(sWh, sWo, dW1, mW2, mW3, dW2,
                                                      counts, W2S, w3T, swt, d2f, outp);
    k_gate_fast<<<dim3(1024), dim3(256), 0, stream>>>(x, mW1, mb1, mb2, mb3,
                                                      W2S, w3T, counts, bucket);
    k_sdec_fast<<<dim3(1024, 8), dim3(256), 0, stream>>>(x, sW1, sb1, sbh, sbo,
                                                         db1, db2, swt, d2f,
                                                         counts, bucket, outp);
  } else if (ws_size >= (size_t)WS_SLOW) {
    k_prep_slow<<<dim3(1), dim3(64), 0, stream>>>(counts, outp);
    k_gate_slow<<<dim3(1024), dim3(256), 62976, stream>>>(x, mW1, mb1, mW2, mb2, mW3, mb3,
                                                          counts, bucket);
    k_sdec_slow<<<dim3(1024, 8), dim3(256), 0, stream>>>(x, sW1, sb1, sWh, sbh, sWo, sbo,
                                                         dW1, db1, dW2, db2, counts, bucket, outp);
  } else {
    k_sentinel<<<dim3(1), dim3(64), 0, stream>>>(outp);
  }
}

// Round 12
// 281.335 us; speedup vs baseline: 4.7945x; 1.0121x over previous
//
#include <hip/hip_runtime.h>
#include <cstdint>

typedef unsigned short ushort_t;
typedef short bf16x8 __attribute__((ext_vector_type(8)));
typedef unsigned short u16x8 __attribute__((ext_vector_type(8)));
typedef float f32x4 __attribute__((ext_vector_type(4)));

#define NPTS 65536
// ws layout (fast): counts@0 | bucket@64 (1,048,576) | W2S@1,048,640 (401,408)
//   | w3T@1,450,048 (14,592) | swt@1,464,640 (4,915,200) | d2f@6,379,840 (8,192) => 6,388,032
#define WS_CNT 0
#define WS_BKT 64
#define OFF_W2S 1048640
#define OFF_W3T 1450048
#define OFF_SWT 1464640
#define OFF_D2F 6379840
#define WS_FAST 6388032u
#define WS_SLOW (64 + 8 * NPTS * 2)

__device__ __forceinline__ float bf2f(ushort_t u) {
  union { unsigned u; float f; } c; c.u = ((unsigned)u) << 16; return c.f;
}
__device__ __forceinline__ ushort_t f2bf(float f) {
  union { float f; unsigned u; } c; c.f = f;
  unsigned u = c.u + 0x7fffu + ((c.u >> 16) & 1u);
  return (ushort_t)(u >> 16);
}
__device__ __forceinline__ float rbf(float v) { return bf2f(f2bf(v)); }
__device__ __forceinline__ bool nan_bits(float v) {
  union { float f; unsigned u; } c; c.f = v;
  return ((c.u >> 23) & 0xFFu) == 0xFFu && (c.u & 0x7FFFFFu) != 0u;
}

__global__ void k_sentinel(float* out) {
  if (threadIdx.x == 0) out[0] = 1.0e30f;  // ws_size-too-small marker
}

// ==================== FAST PATH ====================

// prep: all weight transpose/bf16-convert/fragment-swizzle hoisted here (once per launch).
__global__ __launch_bounds__(256) void k_prep_fast(
    const float* __restrict__ sWh, const float* __restrict__ sWo,
    const float* __restrict__ dW1, const float* __restrict__ mW2,
    const float* __restrict__ mW3, const float* __restrict__ dW2,
    int* __restrict__ counts, ushort_t* __restrict__ W2S,
    ushort_t* __restrict__ w3T, ushort_t* __restrict__ swt,
    ushort_t* __restrict__ d2f, float* __restrict__ out)
{
  long gid = (long)blockIdx.x * 256 + threadIdx.x;
  long gs = (long)gridDim.x * 256;
  // swt fragment-major: [mat 40][t 15][kt 8][lane 64][u 8] bf16; B-frag for 16x16x32:
  // n = t*16 + (lane&15), k = kt*32 + (lane>>4)*8 + u; zero-padded beyond 236.
  // Single pass: one u16x8 store per item; reads coalesced in 64-B runs per 16 lanes.
  // (round-11 layout read W at 944-B thread stride -> ~16x over-fetch, scalar stores)
  for (long i = gid; i < 307200; i += gs) {   // 40 * 15 * 8 * 64
    int mat = (int)(i / 7680);
    int r = (int)(i - (long)mat * 7680);
    int t = r >> 9;
    int r2 = r & 511;
    int kt = r2 >> 6, lane = r2 & 63;
    int n = t * 16 + (lane & 15);
    int q = lane >> 4;
    const float* W = (mat < 24) ? (sWh + (long)mat * 55696)
                   : (mat < 32) ? (sWo + (long)(mat - 24) * 55696)
                                : (dW1 + (long)(mat - 32) * 55696);
    u16x8 tv;
    #pragma unroll
    for (int u = 0; u < 8; ++u) {
      int k = kt * 32 + q * 8 + u;
      tv[u] = (n < 236 && k < 236) ? f2bf(W[k * 236 + n]) : (ushort_t)0;
    }
    *(u16x8*)(swt + i * 8) = tv;
  }
  // d2f: dec2 B-fragments [kt 8][lane 64][u 8]; n = lane&15 (<3 valid), k = kt*32+(lane>>4)*8+u
  for (long i = gid; i < 4096; i += gs) {
    int u = (int)(i & 7), lane = (int)((i >> 3) & 63), kt = (int)(i >> 9);
    int n = lane & 15, k = kt * 32 + ((lane >> 4) << 3) + u;
    d2f[i] = (n < 3 && k < 236) ? f2bf(dW2[k * 3 + n]) : (ushort_t)0;
  }
  // W2S: pre-swizzled B-fragments [kt 14][nt 28][lane 64][u 8]
  for (long i = gid; i < 25088; i += gs) {
    int kt = (int)(i / (28 * 64));
    int rem = (int)(i - (long)kt * 28 * 64);
    int nt = rem / 64, lane = rem - nt * 64;
    int l15 = lane & 15, quad = lane >> 4;
    int n = nt * 16 + l15;
    u16x8 tv;
    #pragma unroll
    for (int u = 0; u < 8; ++u) {
      int k = kt * 32 + quad * 8 + u;
      tv[u] = (k < 441 && n < 441) ? f2bf(mW2[(long)k * 441 + n]) : (ushort_t)0;
    }
    *(u16x8*)(W2S + i * 8) = tv;
  }
  // w3T: [16 e][456 c] (zero-padded) for L3 B-fragments
  for (long i = gid; i < 7296; i += gs) {
    int e = (int)(i / 456), c = (int)(i - (long)e * 456);
    w3T[i] = (e < 8 && c < 441) ? f2bf(mW3[(long)c * 8 + e]) : (ushort_t)0;
  }
  if (gid < 8) counts[gid] = 0;
  if (gid == 8) out[NPTS * 3] = 18.125f;  // KL(uniform||one-hot): data-independent
}

// gate: EXACT bf16-op emulation (argmax fidelity). L1 recompute + L2 bf16-MFMA + chunked-MFMA L3.
__global__ __launch_bounds__(256) void k_gate_fast(
    const float* __restrict__ x,
    const float* __restrict__ mW1, const float* __restrict__ mb1,
    const float* __restrict__ mb2, const float* __restrict__ mb3,
    const ushort_t* __restrict__ W2S, const ushort_t* __restrict__ w3Tg,
    int* __restrict__ counts, ushort_t* __restrict__ bucket)
{
  __shared__ ushort_t At[64][40];       // 5120
  __shared__ float W1c[1792];           // 7168
  __shared__ float xl[192];             // 768
  __shared__ ushort_t chunkC[64][72];   // 9216 (pad 72: 2-way banks on b128 reads)
  __shared__ ushort_t w3T[16][456];     // 14592 (stride 912B -> 2-way banks)
  __shared__ float b2c[448];            // 1792
  __shared__ unsigned char bexp[64];

  int tid = threadIdx.x;
  int blk = blockIdx.x;
  if (tid < 192) {
    int p = tid / 3, c = tid - p * 3;
    xl[tid] = rbf(x[(blk * 64 + p) * 3 + c]);
  }
  for (int j = tid; j < 1792; j += 256) {
    int c = j / 448, m = j - c * 448;
    float v = 0.f;
    if (m < 441) v = (c < 3) ? rbf(mW1[c * 441 + m]) : rbf(mb1[m]);
    W1c[j] = v;
  }
  for (int j = tid; j < 448; j += 256) b2c[j] = (j < 441) ? rbf(mb2[j]) : 0.f;
  for (int ch = tid; ch < 912; ch += 256)
    *(u16x8*)(&w3T[0][0] + ch * 8) = *(const u16x8*)(w3Tg + ch * 8);

  int w = tid >> 6, lane = tid & 63;
  int l15 = lane & 15, quad = lane >> 4;

  f32x4 acc[4][7];
  #pragma unroll
  for (int a = 0; a < 4; ++a)
    #pragma unroll
    for (int b = 0; b < 7; ++b)
      acc[a][b] = (f32x4){0.f, 0.f, 0.f, 0.f};

  int am = tid >> 2, ak = (tid & 3) * 8;

  for (int kt = 0; kt < 14; ++kt) {
    int kk0 = kt * 32;
    __syncthreads();  // prior At reads done (covers preload fills on kt==0)
    // stage A: g1 = relu(bf16(bf16(x@W1) + b1)) for this k-slice
    {
      float x0 = xl[am * 3], x1 = xl[am * 3 + 1], x2 = xl[am * 3 + 2];
      u16x8 tmp;
      #pragma unroll
      for (int u = 0; u < 8; ++u) {
        int j = kk0 + ak + u;
        ushort_t h = 0;
        if (j < 441) {
          float t = x0 * W1c[j];
          t = fmaf(x1, W1c[448 + j], t);
          t = fmaf(x2, W1c[896 + j], t);
          t = rbf(t);                    // matmul -> bf16
          t = rbf(t + W1c[1344 + j]);    // +b1 -> bf16
          t = fmaxf(t, 0.f);
          h = f2bf(t);
        }
        tmp[u] = h;
      }
      *(u16x8*)(At[am] + ak) = tmp;
    }
    __syncthreads();
    bf16x8 bfr[7];
    #pragma unroll
    for (int j = 0; j < 7; ++j)  // coalesced: lanes consecutive 16B chunks
      bfr[j] = *(const bf16x8*)(W2S + ((kt * 28 + (w + 4 * j)) * 64 + lane) * 8);
    #pragma unroll
    for (int mt = 0; mt < 4; ++mt) {
      bf16x8 a = *(const bf16x8*)(&At[mt * 16 + l15][quad * 8]);
      #pragma unroll
      for (int j = 0; j < 7; ++j)
        acc[mt][j] = __builtin_amdgcn_mfma_f32_16x16x32_bf16(a, bfr[j], acc[mt][j], 0, 0, 0);
    }
  }

  // L3 via MFMA over 7 column-chunks of g2; j-loop MUST be unrolled (runtime-indexed
  // acc[mt][j] demotes acc to scratch: round-7 1.7 GB spill, WRITE_SIZE counter).
  f32x4 acc3[4];
  #pragma unroll
  for (int mt = 0; mt < 4; ++mt) acc3[mt] = (f32x4){0.f, 0.f, 0.f, 0.f};
  #pragma unroll
  for (int j = 0; j < 7; ++j) {
    __syncthreads();  // previous chunk reads (or kt-loop At reads) done
    #pragma unroll
    for (int mt = 0; mt < 4; ++mt) {
      #pragma unroll
      for (int r = 0; r < 4; ++r) {
        int cg = j * 64 + w * 16 + l15;        // global col
        int m = mt * 16 + quad * 4 + r;
        float v = rbf(acc[mt][j][r]);          // einsum -> bf16
        v = rbf(v + b2c[cg]);                  // +b2 -> bf16
        v = fmaxf(v, 0.f);                     // relu
        chunkC[m][w * 16 + l15] = f2bf(v);
      }
    }
    __syncthreads();
    bf16x8 b0 = *(const bf16x8*)(&w3T[l15][j * 64 + quad * 8]);
    bf16x8 b1 = *(const bf16x8*)(&w3T[l15][j * 64 + 32 + quad * 8]);
    #pragma unroll
    for (int mt = 0; mt < 4; ++mt) {
      bf16x8 a0 = *(const bf16x8*)(&chunkC[mt * 16 + l15][quad * 8]);
      bf16x8 a1 = *(const bf16x8*)(&chunkC[mt * 16 + l15][32 + quad * 8]);
      acc3[mt] = __builtin_amdgcn_mfma_f32_16x16x32_bf16(a0, b0, acc3[mt], 0, 0, 0);
      acc3[mt] = __builtin_amdgcn_mfma_f32_16x16x32_bf16(a1, b1, acc3[mt], 0, 0, 0);
    }
  }
  // logits in C-layout: e = l15, m = mt*16+quad*4+r. Argmax via 8-lane butterfly.
  float b3v = (l15 < 8) ? rbf(mb3[l15]) : 0.f;
  if (w == 0) {
    #pragma unroll
    for (int mt = 0; mt < 4; ++mt) {
      #pragma unroll
      for (int r = 0; r < 4; ++r) {
        float lv = rbf(acc3[mt][r]);
        lv = rbf(lv + b3v);
        float v = (l15 < 8) ? lv : -1.0e30f;
        int ii = l15;
        #pragma unroll
        for (int mk = 1; mk < 8; mk <<= 1) {
          float ov = __shfl_xor(v, mk);
          int oi = __shfl_xor(ii, mk);
          if (ov > v || (ov == v && oi < ii)) { v = ov; ii = oi; }  // first-max = np.argmax
        }
        if (l15 == 0) bexp[mt * 16 + quad * 4 + r] = (unsigned char)ii;
      }
    }
  }
  __syncthreads();
  if (tid < 64) {  // wave 0: wave-aggregated bucket scatter (<=8 atomics/block)
    int bi = (int)bexp[tid];
    int slot = 0;
    #pragma unroll
    for (int ee = 0; ee < 8; ++ee) {
      unsigned long long msk = __ballot(bi == ee);
      if (bi == ee) {
        int leader = (int)__builtin_ctzll(msk);
        int rank = __popcll(msk & ((1ull << tid) - 1ull));
        int basep = 0;
        if (tid == leader) basep = atomicAdd(&counts[ee], __popcll(msk));
        basep = __shfl(basep, leader);
        slot = basep + rank;
      }
    }
    bucket[bi * NPTS + slot] = (ushort_t)(blk * 64 + tid);
  }
}

// sdec: DENSE 1-D grid (1032 blocks). Each block self-maps to (expert, base) by
// prefix-scanning counts (uniform scalar work) -> all real blocks contiguous in
// dispatch order -> full co-residency (round-11: 8192-block grid left real blocks
// in 8 sparse clusters at 0.5 blocks/CU, occupancy 22%).
// Waves own N-TILES (t%4==w): each B-fragment loaded once; afr[4][8] reg-cached.
__global__ __launch_bounds__(256) void k_sdec_fast(
    const float* __restrict__ x,
    const float* __restrict__ sW1, const float* __restrict__ sb1,
    const float* __restrict__ sbh, const float* __restrict__ sbo,
    const float* __restrict__ db1, const float* __restrict__ db2,
    const ushort_t* __restrict__ swt, const ushort_t* __restrict__ d2f,
    const int* __restrict__ counts, const ushort_t* __restrict__ bucket,
    float* __restrict__ out)
{
  __shared__ ushort_t hA[64][264];        // 33792
  __shared__ int idxl[64];                // 256
  __shared__ float xl[64][3];             // 768
  __shared__ float wc[944];               // 3776

  int b = blockIdx.x;
  int e = -1, base = 0, cnte = 0, cum = 0;
  #pragma unroll
  for (int ee = 0; ee < 8; ++ee) {
    int c = counts[ee];
    int nb = (c + 63) >> 6;
    if (e < 0 && b < cum + nb) { e = ee; base = (b - cum) << 6; cnte = c; }
    cum += nb;
  }
  if (e < 0) return;
  int np = min(64, cnte - base);
  int tid = threadIdx.x;

  if (tid < 64) {
    int s = base + (tid < np ? tid : 0);   // pad rows duplicate a real point
    idxl[tid] = (int)bucket[e * NPTS + s];
  }
  __syncthreads();
  if (tid < 192) {
    int p = tid / 3, c = tid - p * 3;
    xl[p][c] = rbf(x[idxl[p] * 3 + c]);
  }
  for (int j = tid; j < 944; j += 256)
    wc[j] = (j < 708) ? rbf(sW1[e * 708 + j]) : 30.f * rbf(sb1[e * 236 + (j - 708)]);
  __syncthreads();

  int w = tid >> 6, lane = tid & 63;
  int l15 = lane & 15, quad = lane >> 4;

  // L1 (wave-private rows): h = bf16(sin(30*(x@W1) + 30*b1)); cols>=236 zeroed
  for (int i = lane; i < 16 * 264; i += 64) {
    int pr = i / 264, f = i - pr * 264;
    int p = w * 16 + pr;
    ushort_t hv = 0;
    if (f < 236) {
      float v = xl[p][0] * wc[f];
      v = fmaf(xl[p][1], wc[236 + f], v);
      v = fmaf(xl[p][2], wc[472 + f], v);
      v = fmaf(30.f, v, wc[708 + f]);   // 30*(x@W1) + 30*b1
      hv = f2bf(__sinf(v));
    }
    hA[p][f] = hv;
  }
  __syncthreads();  // all rows ready for cross-wave afr caching

  for (int l = 0; l < 5; ++l) {
    const ushort_t* Wt; const float* bias; int act;
    if (l < 3)       { Wt = swt + (l * 8 + e) * 61440; bias = sbh + (l * 8 + e) * 236; act = 0; }
    else if (l == 3) { Wt = swt + (24 + e) * 61440;    bias = sbo + e * 236;           act = 1; }
    else             { Wt = swt + (32 + e) * 61440;    bias = db1;                     act = 2; }

    bf16x8 afr[4][8];  // ALL 64 rows x full K (128 VGPR; indices compile-time)
    #pragma unroll
    for (int mt = 0; mt < 4; ++mt)
      #pragma unroll
      for (int kt = 0; kt < 8; ++kt)
        afr[mt][kt] = *(const bf16x8*)(&hA[mt * 16 + l15][kt * 32 + quad * 8]);
    __syncthreads();  // all caches done before anyone writes hA

    #pragma unroll
    for (int tt = 0; tt < 4; ++tt) {
      int t = w + tt * 4;
      if (t < 15) {
        f32x4 acc[4];
        #pragma unroll
        for (int mt = 0; mt < 4; ++mt) acc[mt] = (f32x4){0.f, 0.f, 0.f, 0.f};
        #pragma unroll
        for (int kt = 0; kt < 8; ++kt) {
          bf16x8 bb = *(const bf16x8*)(Wt + ((t * 8 + kt) * 64 + lane) * 8);  // 1 KB/wave, unique
          #pragma unroll
          for (int mt = 0; mt < 4; ++mt)
            acc[mt] = __builtin_amdgcn_mfma_f32_16x16x32_bf16(afr[mt][kt], bb, acc[mt], 0, 0, 0);
        }
        int n = t * 16 + l15;
        if (n < 236) {
          float bv = rbf(bias[n]);
          float b30 = 30.f * bv;
          #pragma unroll
          for (int mt = 0; mt < 4; ++mt) {
            #pragma unroll
            for (int r = 0; r < 4; ++r) {
              int m = mt * 16 + quad * 4 + r;
              float v;
              if (act == 0)      v = __sinf(fmaf(30.f, acc[mt][r], b30));
              else if (act == 1) v = acc[mt][r] + bv;
              else               v = fmaxf(acc[mt][r] + bv, 0.f);
              hA[m][n] = f2bf(v);
            }
          }
        }
      }
    }
    __syncthreads();  // all writes done before next layer's caching (or dec2)
  }

  // dec2 via MFMA: own 16 rows x d2f (3 valid cols), out = h@dW2 + db2
  {
    f32x4 acc = (f32x4){0.f, 0.f, 0.f, 0.f};
    #pragma unroll
    for (int kt = 0; kt < 8; ++kt) {
      bf16x8 a = *(const bf16x8*)(&hA[w * 16 + l15][kt * 32 + quad * 8]);
      bf16x8 bb = *(const bf16x8*)(d2f + (kt * 64 + lane) * 8);
      acc = __builtin_amdgcn_mfma_f32_16x16x32_bf16(a, bb, acc, 0, 0, 0);
    }
    if (l15 < 3) {
      float bv = rbf(db2[l15]);
      #pragma unroll
      for (int r = 0; r < 4; ++r) {
        int p = w * 16 + quad * 4 + r;
        if (p < np) {
          float s = acc[r] + bv;
          out[idxl[p] * 3 + l15] = nan_bits(s) ? 16.0f : fminf(fmaxf(s, -4.f), 4.f);
        }
      }
    }
  }
}

// ==================== SLOW PATH (round-6, proven; used when ws too small) ====================

__global__ void k_prep_slow(int* counts, float* out) {
  int t = threadIdx.x;
  if (t < 8) counts[t] = 0;
  if (t == 8) out[NPTS * 3] = 18.125f;
}

__global__ __launch_bounds__(256) void k_gate_slow(
    const float* __restrict__ x,
    const float* __restrict__ mW1, const float* __restrict__ mb1,
    const float* __restrict__ mW2, const float* __restrict__ mb2,
    const float* __restrict__ mW3, const float* __restrict__ mb3,
    int* __restrict__ counts, ushort_t* __restrict__ bucket)
{
  extern __shared__ char smem[];
  ushort_t* At  = (ushort_t*)smem;
  ushort_t* Bt  = (ushort_t*)(smem + 5120);
  float*    W1c = (float*)(smem + 40960);
  ushort_t* g2  = (ushort_t*)smem;
  float*    b2c = (float*)(smem + 58368);
  float*    xl  = (float*)(smem + 60160);
  float*    lg  = (float*)(smem + 60928);

  int tid = threadIdx.x;
  int blk = blockIdx.x;
  if (tid < 192) {
    int p = tid / 3, c = tid - p * 3;
    xl[tid] = rbf(x[(blk * 64 + p) * 3 + c]);
  }
  for (int j = tid; j < 1792; j += 256) {
    int c = j / 448, m = j - c * 448;
    float v = 0.f;
    if (m < 441) v = (c < 3) ? rbf(mW1[c * 441 + m]) : rbf(mb1[m]);
    W1c[j] = v;
  }
  for (int j = tid; j < 448; j += 256) b2c[j] = (j < 441) ? rbf(mb2[j]) : 0.f;

  int w = tid >> 6, lane = tid & 63;
  int l15 = lane & 15, quad = lane >> 4;

  f32x4 acc[4][7];
  #pragma unroll
  for (int a = 0; a < 4; ++a)
    #pragma unroll
    for (int b = 0; b < 7; ++b)
      acc[a][b] = (f32x4){0.f, 0.f, 0.f, 0.f};

  int am = tid >> 2, ak = (tid & 3) * 8;

  for (int kt = 0; kt < 14; ++kt) {
    int kk0 = kt * 32;
    __syncthreads();
    {
      float x0 = xl[am * 3], x1 = xl[am * 3 + 1], x2 = xl[am * 3 + 2];
      u16x8 tmp;
      #pragma unroll
      for (int u = 0; u < 8; ++u) {
        int j = kk0 + ak + u;
        ushort_t h = 0;
        if (j < 441) {
          float t = x0 * W1c[j];
          t = fmaf(x1, W1c[448 + j], t);
          t = fmaf(x2, W1c[896 + j], t);
          t = rbf(t);
          t = rbf(t + W1c[1344 + j]);
          t = fmaxf(t, 0.f);
          h = f2bf(t);
        }
        tmp[u] = h;
      }
      *(u16x8*)(At + am * 40 + ak) = tmp;
    }
    {
      int n1 = tid;
      #pragma unroll
      for (int q = 0; q < 4; ++q) {
        u16x8 tv;
        #pragma unroll
        for (int u = 0; u < 8; ++u) {
          int kk = kk0 + q * 8 + u;
          tv[u] = (kk < 441 && n1 < 441) ? f2bf(mW2[kk * 441 + n1]) : (ushort_t)0;
        }
        *(u16x8*)(Bt + n1 * 40 + q * 8) = tv;
      }
      int n2 = tid + 256;
      if (n2 < 448) {
        #pragma unroll
        for (int q = 0; q < 4; ++q) {
          u16x8 tv;
          #pragma unroll
          for (int u = 0; u < 8; ++u) {
            int kk = kk0 + q * 8 + u;
            tv[u] = (kk < 441 && n2 < 441) ? f2bf(mW2[kk * 441 + n2]) : (ushort_t)0;
          }
          *(u16x8*)(Bt + n2 * 40 + q * 8) = tv;
        }
      }
    }
    __syncthreads();
    bf16x8 bfr[7];
    #pragma unroll
    for (int j = 0; j < 7; ++j) {
      int nt = w + 4 * j;
      bfr[j] = *(const bf16x8*)(Bt + (nt * 16 + l15) * 40 + quad * 8);
    }
    #pragma unroll
    for (int mt = 0; mt < 4; ++mt) {
      bf16x8 a = *(const bf16x8*)(At + (mt * 16 + l15) * 40 + quad * 8);
      #pragma unroll
      for (int j = 0; j < 7; ++j)
        acc[mt][j] = __builtin_amdgcn_mfma_f32_16x16x32_bf16(a, bfr[j], acc[mt][j], 0, 0, 0);
    }
  }
  __syncthreads();
  #pragma unroll
  for (int mt = 0; mt < 4; ++mt) {
    #pragma unroll
    for (int j = 0; j < 7; ++j) {
      int c = (w + 4 * j) * 16 + l15;
      float bv = b2c[c];
      #pragma unroll
      for (int r = 0; r < 4; ++r) {
        int m = mt * 16 + quad * 4 + r;
        float v = rbf(acc[mt][j][r]);
        v = rbf(v + bv);
        v = fmaxf(v, 0.f);
        g2[m * 456 + c] = f2bf(v);
      }
    }
  }
  __syncthreads();
  {
    int m3 = tid >> 2, eg = tid & 3;
    float s0 = 0.f, s1 = 0.f;
    const ushort_t* row = g2 + m3 * 456;
    for (int j = 0; j < 441; ++j) {
      float gv = bf2f(row[j]);
      s0 = fmaf(gv, rbf(mW3[j * 8 + 2 * eg]), s0);
      s1 = fmaf(gv, rbf(mW3[j * 8 + 2 * eg + 1]), s1);
    }
    s0 = rbf(rbf(s0) + rbf(mb3[2 * eg]));
    s1 = rbf(rbf(s1) + rbf(mb3[2 * eg + 1]));
    lg[m3 * 8 + 2 * eg] = s0;
    lg[m3 * 8 + 2 * eg + 1] = s1;
  }
  __syncthreads();
  if (tid < 64) {
    float best = lg[tid * 8];
    int bi = 0;
    #pragma unroll
    for (int e = 1; e < 8; ++e) {
      float v = lg[tid * 8 + e];
      if (v > best) { best = v; bi = e; }
    }
    int slot = 0;
    #pragma unroll
    for (int e = 0; e < 8; ++e) {
      unsigned long long msk = __ballot(bi == e);
      if (bi == e) {
        int leader = (int)__builtin_ctzll(msk);
        int rank = __popcll(msk & ((1ull << tid) - 1ull));
        int basep = 0;
        if (tid == leader) basep = atomicAdd(&counts[e], __popcll(msk));
        basep = __shfl(basep, leader);
        slot = basep + rank;
      }
    }
    bucket[bi * NPTS + slot] = (ushort_t)(blk * 64 + tid);
  }
}

__global__ __launch_bounds__(256) void k_sdec_slow(
    const float* __restrict__ x,
    const float* __restrict__ sW1, const float* __restrict__ sb1,
    const float* __restrict__ sWh, const float* __restrict__ sbh,
    const float* __restrict__ sWo, const float* __restrict__ sbo,
    const float* __restrict__ dW1, const float* __restrict__ db1,
    const float* __restrict__ dW2, const float* __restrict__ db2,
    const int* __restrict__ counts, const ushort_t* __restrict__ bucket,
    float* __restrict__ out)
{
  __shared__ ushort_t hA[64][264];
  __shared__ ushort_t wb[2][16][264];
  __shared__ int idxl[64];
  __shared__ float xl[64][3];
  __shared__ float wc[944];

  int e = blockIdx.y;
  int base = blockIdx.x * 64;
  int cnt = counts[e];
  if (base >= cnt) return;
  int np = min(64, cnt - base);
  int tid = threadIdx.x;

  if (tid < 64) {
    int s = base + (tid < np ? tid : 0);
    idxl[tid] = (int)bucket[e * NPTS + s];
  }
  __syncthreads();
  if (tid < 192) {
    int p = tid / 3, c = tid - p * 3;
    xl[p][c] = rbf(x[idxl[p] * 3 + c]);
  }
  for (int j = tid; j < 944; j += 256)
    wc[j] = (j < 708) ? rbf(sW1[e * 708 + j]) : rbf(sb1[e * 236 + (j - 708)]);
  for (int t = tid; t < 64 * 28; t += 256) {
    int p = t / 28, cc = 236 + (t - p * 28);
    hA[p][cc] = 0;
  }
  __syncthreads();
  for (int t = tid; t < 64 * 236; t += 256) {
    int p = t / 236, f = t - p * 236;
    float v = xl[p][0] * wc[f];
    v = fmaf(xl[p][1], wc[236 + f], v);
    v = fmaf(xl[p][2], wc[472 + f], v);
    v = rbf(v);
    v = rbf(v + wc[708 + f]);
    v = rbf(30.f * v);
    hA[p][f] = f2bf(sinf(v));
  }

  int w = tid >> 6, lane = tid & 63;
  int l15 = lane & 15, quad = lane >> 4;

  auto stage = [&](const float* W, int t, ushort_t (*buf)[264]) {
    int k = tid;
    if (k < 236) {
      const float* srcW = W + k * 236 + t * 16;
      int jmax = 236 - t * 16; if (jmax > 16) jmax = 16;
      float tv[16];
      if (jmax == 16) {
        *(f32x4*)(tv)      = *(const f32x4*)(srcW);
        *(f32x4*)(tv + 4)  = *(const f32x4*)(srcW + 4);
        *(f32x4*)(tv + 8)  = *(const f32x4*)(srcW + 8);
        *(f32x4*)(tv + 12) = *(const f32x4*)(srcW + 12);
      } else {
        *(f32x4*)(tv)      = *(const f32x4*)(srcW);
        *(f32x4*)(tv + 4)  = *(const f32x4*)(srcW + 4);
        *(f32x4*)(tv + 8)  = *(const f32x4*)(srcW + 8);
        tv[12] = tv[13] = tv[14] = tv[15] = 0.f;
      }
      #pragma unroll
      for (int j = 0; j < 16; ++j)
        buf[j][k] = (j < jmax) ? f2bf(tv[j]) : (ushort_t)0;
    } else {
      #pragma unroll
      for (int j = 0; j < 16; ++j) buf[j][k] = 0;
    }
  };

  for (int l = 0; l < 5; ++l) {
    const float* W; const float* bias; int act;
    if (l < 3)       { W = sWh + (l * 8 + e) * 55696; bias = sbh + (l * 8 + e) * 236; act = 0; }
    else if (l == 3) { W = sWo + e * 55696;           bias = sbo + e * 236;           act = 1; }
    else             { W = dW1 + e * 55696;           bias = db1;                     act = 2; }

    __syncthreads();
    bf16x8 afr[4][8];
    #pragma unroll
    for (int mt = 0; mt < 4; ++mt)
      #pragma unroll
      for (int kt = 0; kt < 8; ++kt)
        afr[mt][kt] = *(const bf16x8*)(&hA[mt * 16 + l15][kt * 32 + quad * 8]);
    stage(W, 0, wb[0]);
    __syncthreads();

    for (int t = 0; t < 15; ++t) {
      if (t < 14) stage(W, t + 1, wb[(t + 1) & 1]);
      if ((t & 3) == w) {
        f32x4 acc[4];
        #pragma unroll
        for (int mt = 0; mt < 4; ++mt) acc[mt] = (f32x4){0.f, 0.f, 0.f, 0.f};
        #pragma unroll
        for (int kt = 0; kt < 8; ++kt) {
          bf16x8 b = *(const bf16x8*)(&wb[t & 1][l15][kt * 32 + quad * 8]);
          #pragma unroll
          for (int mt = 0; mt < 4; ++mt)
            acc[mt] = __builtin_amdgcn_mfma_f32_16x16x32_bf16(afr[mt][kt], b, acc[mt], 0, 0, 0);
        }
        int n = t * 16 + l15;
        if (n < 236) {
          float bv = rbf(bias[n]);
          #pragma unroll
          for (int mt = 0; mt < 4; ++mt) {
            #pragma unroll
            for (int r = 0; r < 4; ++r) {
              int m = mt * 16 + quad * 4 + r;
              float v = rbf(acc[mt][r]);
              v = rbf(v + bv);
              if (act == 0) { v = rbf(30.f * v); v = sinf(v); }
              else if (act == 2) v = fmaxf(v, 0.f);
              hA[m][n] = f2bf(v);
            }
          }
        }
      }
      __syncthreads();
    }
  }

  for (int j = tid; j < 711; j += 256)
    wc[j] = (j < 708) ? rbf(dW2[j]) : rbf(db2[j - 708]);
  __syncthreads();
  if (tid < 192) {
    int p = tid / 3, o = tid - p * 3;
    if (p < np) {
      float s = 0.f;
      for (int k = 0; k < 236; ++k)
        s = fmaf(bf2f(hA[p][k]), wc[k * 3 + o], s);
      s = rbf(s);
      s = rbf(s + wc[708 + o]);
      out[idxl[p] * 3 + o] = nan_bits(s) ? 16.0f : fminf(fmaxf(s, -4.f), 4.f);
    }
  }
}

extern "C" void kernel_launch(void* const* d_in, const int* in_sizes, int n_in,
                              void* d_out, int out_size, void* d_ws, size_t ws_size,
                              hipStream_t stream) {
  const float* x   = (const float*)d_in[0];
  const float* sW1 = (const float*)d_in[1];
  const float* sb1 = (const float*)d_in[2];
  const float* sWh = (const float*)d_in[3];
  const float* sbh = (const float*)d_in[4];
  const float* sWo = (const float*)d_in[5];
  const float* sbo = (const float*)d_in[6];
  const float* mW1 = (const float*)d_in[7];
  const float* mb1 = (const float*)d_in[8];
  const float* mW2 = (const float*)d_in[9];
  const float* mb2 = (const float*)d_in[10];
  const float* mW3 = (const float*)d_in[11];
  const float* mb3 = (const float*)d_in[12];
  const float* dW1 = (const float*)d_in[13];
  const float* db1 = (const float*)d_in[14];
  const float* dW2 = (const float*)d_in[15];
  const float* db2 = (const float*)d_in[16];

  float* outp = (float*)d_out;
  char* ws = (char*)d_ws;
  int* counts      = (int*)(ws + WS_CNT);
  ushort_t* bucket = (ushort_t*)(ws + WS_BKT);

  if (ws_size >= (size_t)WS_FAST) {
    ushort_t* W2S = (ushort_t*)(ws + OFF_W2S);
    ushort_t* w3T = (ushort_t*)(ws + OFF_W3T);
    ushort_t* swt = (ushort_t*)(ws + OFF_SWT);
    ushort_t* d2f = (ushort_t*)(ws + OFF_D2F);
    k_prep_fast<<<dim3(2048), dim3(256), 0, stream>>>(sWh, sWo, dW1, mW2, mW3, dW2,
                                                      counts, W2S, w3T, swt, d2f, outp);
    k_gate_fast<<<dim3(1024), dim3(256), 0, stream>>>(x, mW1, mb1, mb2, mb3,
                                                      W2S, w3T, counts, bucket);
    k_sdec_fast<<<dim3(1032), dim3(256), 0, stream>>>(x, sW1, sb1, sbh, sbo,
                                                      db1, db2, swt, d2f,
                                                      counts, bucket, outp);
  } else if (ws_size >= (size_t)WS_SLOW) {
    k_prep_slow<<<dim3(1), dim3(64), 0, stream>>>(counts, outp);
    k_gate_slow<<<dim3(1024), dim3(256), 62976, stream>>>(x, mW1, mb1, mW2, mb2, mW3, mb3,
                                                          counts, bucket);
    k_sdec_slow<<<dim3(1024, 8), dim3(256), 0, stream>>>(x, sW1, sb1, sWh, sbh, sWo, sbo,
                                                         dW1, db1, dW2, db2, counts, bucket, outp);
  } else {
    k_sentinel<<<dim3(1), dim3(64), 0, stream>>>(outp);
  }
}